// Round 3
// baseline (1432.605 us; speedup 1.0000x reference)
//
#include <hip/hip_runtime.h>
#include <math.h>

#define NN 100000
#define NE 500000
#define NREL 3
#define F 128
#define SCAN_BLK 1024
#define NBLK ((NN + SCAN_BLK - 1) / SCAN_BLK)   // 98
#define CH 25000                                 // z-chunk rows (NN = 4*CH)
#define NCH 4

__device__ __forceinline__ float sigm(float x) { return 1.f / (1.f + __expf(-x)); }

// ---- degree counting ----
__global__ void count_deg(const int* __restrict__ src, const int* __restrict__ dst,
                          int* __restrict__ cnt_out, int* __restrict__ cnt_in) {
  int i = blockIdx.x * blockDim.x + threadIdx.x;
  if (i >= NREL * NE) return;
  int r = i / NE;
  atomicAdd(&cnt_out[r * NN + src[i]], 1);
  atomicAdd(&cnt_in[r * NN + dst[i]], 1);
}

__global__ void make_rs(const int* __restrict__ cnt_out, const int* __restrict__ cnt_in,
                        float* __restrict__ rs_out, float* __restrict__ rs_in3) {
  int i = blockIdx.x * blockDim.x + threadIdx.x;
  if (i >= NREL * NN) return;
  int c0 = cnt_out[i];
  rs_out[i] = rsqrtf((float)(c0 < 1 ? 1 : c0));
  int c1 = cnt_in[i];
  rs_in3[i] = rsqrtf((float)(c1 < 1 ? 1 : c1)) * (1.f / 3.f);
}

// ---- two-level exclusive scan of cnt_in -> row_ptr ----
__global__ __launch_bounds__(256) void scan1(const int* __restrict__ cnt,
                                             int* __restrict__ excl, int* __restrict__ bsums) {
  int rb = blockIdx.x;
  int r = rb / NBLK, blk = rb % NBLK;
  int tid = (int)threadIdx.x;
  int v[4]; int sum = 0;
#pragma unroll
  for (int i = 0; i < 4; ++i) {
    int idx = blk * SCAN_BLK + tid * 4 + i;
    int c = (idx < NN) ? cnt[r * NN + idx] : 0;
    v[i] = sum; sum += c;
  }
  __shared__ int ts[256];
  ts[tid] = sum;
  __syncthreads();
  for (int off = 1; off < 256; off <<= 1) {
    int t = (tid >= off) ? ts[tid - off] : 0;
    __syncthreads();
    ts[tid] += t;
    __syncthreads();
  }
  int texcl = tid ? ts[tid - 1] : 0;
#pragma unroll
  for (int i = 0; i < 4; ++i) {
    int idx = blk * SCAN_BLK + tid * 4 + i;
    if (idx < NN) excl[r * NN + idx] = texcl + v[i];
  }
  if (tid == 255) bsums[rb] = ts[255];
}

__global__ __launch_bounds__(128) void scan2(int* __restrict__ bsums) {
  int r = blockIdx.x;
  int tid = (int)threadIdx.x;
  __shared__ int ts[128];
  ts[tid] = (tid < NBLK) ? bsums[r * NBLK + tid] : 0;
  __syncthreads();
  for (int off = 1; off < 128; off <<= 1) {
    int t = (tid >= off) ? ts[tid - off] : 0;
    __syncthreads();
    ts[tid] += t;
    __syncthreads();
  }
  if (tid < NBLK) bsums[r * NBLK + tid] = tid ? ts[tid - 1] : 0;
}

__global__ void scan3(int* __restrict__ row_ptr, const int* __restrict__ bsums,
                      int* __restrict__ cursor) {
  int i = blockIdx.x * blockDim.x + threadIdx.x;
  if (i >= NREL * NN) return;
  int r = i / NN, idx = i - r * NN, blk = idx / SCAN_BLK;
  int val = row_ptr[i] + bsums[r * NBLK + blk];
  row_ptr[i] = val;
  cursor[i] = val;
}

// counting-sort edges by dst; store (src, rs_out[src]) pairs
__global__ void place_edges(const int* __restrict__ src, const int* __restrict__ dst,
                            const float* __restrict__ rs_out,
                            int* __restrict__ cursor, int2* __restrict__ ses) {
  int i = blockIdx.x * blockDim.x + threadIdx.x;
  if (i >= NREL * NE) return;
  int r = i / NE;
  int s = src[i];
  int pos = atomicAdd(&cursor[r * NN + dst[i]], 1);
  ses[(size_t)r * NE + pos] = make_int2(s, __float_as_int(rs_out[r * NN + s]));
}

// small prep: bbar1/bbar2 (mean bias over relations), bselw (lstm gate biases)
__global__ void prep_small(const float* __restrict__ b1, const float* __restrict__ b2,
                           const float* __restrict__ bif, const float* __restrict__ bhf,
                           const float* __restrict__ bib, const float* __restrict__ bhb,
                           float* __restrict__ bbar1, float* __restrict__ bbar2,
                           float* __restrict__ bselw) {
  int t = (int)threadIdx.x;
  if (t < 128) {
    bbar1[t] = (b1[t] + b1[128 + t] + b1[256 + t]) * (1.f / 3.f);
  } else if (t < 256) {
    int j = t - 128;
    bbar2[j] = (b2[j] + b2[128 + j] + b2[256 + j]) * (1.f / 3.f);
  } else if (t < 640) {
    int m = t - 256;                 // m = g*128 + j, j = dir*64 + jj
    int g = m >> 7, j = m & 127, dir = j >> 6, jj = j & 63;
    int grow = (g == 0) ? jj : (g == 1) ? (128 + jj) : (192 + jj);
    bselw[m] = dir ? (bib[grow] + bhb[grow]) : (bif[grow] + bhf[grow]);
  }
}

// pack lstm gate weights: Wpack[k][m] = Wd[grow][k], m = g*128 + dir*64 + jj
__global__ void pack_w(const float* __restrict__ Wf, const float* __restrict__ Wb,
                       float* __restrict__ Wpack) {
  int i = blockIdx.x * blockDim.x + threadIdx.x;
  if (i >= 128 * 384) return;
  int k = i / 384, m = i % 384;
  int g = m >> 7, j = m & 127, dir = j >> 6, jj = j & 63;
  int grow = (g == 0) ? jj : (g == 1) ? (128 + jj) : (192 + jj);
  const float* Wd = dir ? Wb : Wf;
  Wpack[i] = Wd[grow * 128 + k];
}

// fused 3-relation gather: z[n-n0][r*128+..] = rs_in3_r[n] * sum_e rs_out_r[s]*table[s][:]
__global__ __launch_bounds__(256) void gather3(
    const float* __restrict__ table, const int2* __restrict__ ses,
    const int* __restrict__ row_ptr, const int* __restrict__ cnt,
    const float* __restrict__ rs_in3, float* __restrict__ z, int n0) {
  int wid = (int)threadIdx.x >> 6, lane = (int)threadIdx.x & 63;
  int n = n0 + blockIdx.x * 4 + wid;
  if (n >= NN) return;
  const float2* xl = (const float2*)table + lane;  // row stride 64 float2
  float* zrow = z + (size_t)(n - n0) * 384;
  for (int r = 0; r < NREL; ++r) {
    int base = r * NN + n;
    int beg = row_ptr[base], c = cnt[base];
    float ax = 0.f, ay = 0.f;
    int p = 0;
    while (p < c) {
      int chunk = min(64, c - p);
      int2 es = make_int2(0, 0);
      if (lane < chunk) es = ses[(size_t)r * NE + beg + p + lane];
      int t = 0;
      for (; t + 8 <= chunk; t += 8) {
        float2 v[8]; float sc[8];
#pragma unroll
        for (int u = 0; u < 8; ++u) {
          int s = __shfl(es.x, t + u);
          sc[u] = __int_as_float(__shfl(es.y, t + u));
          v[u] = xl[(size_t)s * 64];
        }
#pragma unroll
        for (int u = 0; u < 8; ++u) {
          ax = fmaf(v[u].x, sc[u], ax);
          ay = fmaf(v[u].y, sc[u], ay);
        }
      }
      for (; t < chunk; ++t) {
        int s = __shfl(es.x, t);
        float scu = __int_as_float(__shfl(es.y, t));
        float2 v = xl[(size_t)s * 64];
        ax = fmaf(v.x, scu, ax);
        ay = fmaf(v.y, scu, ay);
      }
      p += chunk;
    }
    float ci = rs_in3[base];
    *((float2*)(zrow + r * 128) + lane) = make_float2(ax * ci, ay * ci);
  }
}

// H[n0+row] = (relu?) (Z[row,0:384] @ B[384,128] + bbar)
template <bool RELU>
__global__ __launch_bounds__(256, 4)
void gemm_zcat(const float* __restrict__ Z, const float* __restrict__ B,
               const float* __restrict__ bias, float* __restrict__ H, int n0) {
  __shared__ float As[128][33];
  __shared__ float Ws[32][132];
  const int row0 = blockIdx.x * 128;
  const int tid = (int)threadIdx.x;
  const int rg = tid >> 4;
  const int cg = tid & 15;
  float acc[8][8] = {};

  for (int kt = 0; kt < 12; ++kt) {
    __syncthreads();
#pragma unroll
    for (int it = 0; it < 4; ++it) {
      int lin = (it * 256 + tid) << 2;
      int r = lin >> 5, c = lin & 31;
      float4 v = make_float4(0.f, 0.f, 0.f, 0.f);
      if (row0 + r < CH)
        v = *(const float4*)(Z + (size_t)(row0 + r) * 384 + kt * 32 + c);
      As[r][c] = v.x; As[r][c + 1] = v.y; As[r][c + 2] = v.z; As[r][c + 3] = v.w;
    }
#pragma unroll
    for (int it = 0; it < 4; ++it) {
      int lin = (it * 256 + tid) << 2;
      int kk = lin >> 7, j = lin & 127;
      *(float4*)&Ws[kk][j] = *(const float4*)(B + (size_t)(kt * 32 + kk) * 128 + j);
    }
    __syncthreads();
#pragma unroll
    for (int kk = 0; kk < 32; ++kk) {
      float a[8];
#pragma unroll
      for (int i = 0; i < 8; ++i) a[i] = As[rg * 8 + i][kk];
      const float4 w0 = *(const float4*)&Ws[kk][cg * 4];
      const float4 w1 = *(const float4*)&Ws[kk][64 + cg * 4];
#pragma unroll
      for (int i = 0; i < 8; ++i) {
        acc[i][0] = fmaf(a[i], w0.x, acc[i][0]);
        acc[i][1] = fmaf(a[i], w0.y, acc[i][1]);
        acc[i][2] = fmaf(a[i], w0.z, acc[i][2]);
        acc[i][3] = fmaf(a[i], w0.w, acc[i][3]);
        acc[i][4] = fmaf(a[i], w1.x, acc[i][4]);
        acc[i][5] = fmaf(a[i], w1.y, acc[i][5]);
        acc[i][6] = fmaf(a[i], w1.z, acc[i][6]);
        acc[i][7] = fmaf(a[i], w1.w, acc[i][7]);
      }
    }
  }
  const float4 b0 = *(const float4*)(bias + cg * 4);
  const float4 b1v = *(const float4*)(bias + 64 + cg * 4);
#pragma unroll
  for (int i = 0; i < 8; ++i) {
    int lr = row0 + rg * 8 + i;
    if (lr < CH) {
      float4 o0, o1;
      o0.x = acc[i][0] + b0.x; o0.y = acc[i][1] + b0.y;
      o0.z = acc[i][2] + b0.z; o0.w = acc[i][3] + b0.w;
      o1.x = acc[i][4] + b1v.x; o1.y = acc[i][5] + b1v.y;
      o1.z = acc[i][6] + b1v.z; o1.w = acc[i][7] + b1v.w;
      if (RELU) {
        o0.x = fmaxf(o0.x, 0.f); o0.y = fmaxf(o0.y, 0.f);
        o0.z = fmaxf(o0.z, 0.f); o0.w = fmaxf(o0.w, 0.f);
        o1.x = fmaxf(o1.x, 0.f); o1.y = fmaxf(o1.y, 0.f);
        o1.z = fmaxf(o1.z, 0.f); o1.w = fmaxf(o1.w, 0.f);
      }
      *(float4*)(H + (size_t)(n0 + lr) * F + cg * 4) = o0;
      *(float4*)(H + (size_t)(n0 + lr) * F + 64 + cg * 4) = o1;
    }
  }
}

// fused BiLSTM step from packed gate weights; in-place safe (row-disjoint blocks)
__global__ __launch_bounds__(512, 2)
void lstm_fused2(const float* __restrict__ H, const float* __restrict__ Wpack,
                 const float* __restrict__ bselw, float* __restrict__ out) {
  __shared__ float As[64][33];
  __shared__ float Ws[32][392];
  const int row0 = blockIdx.x * 64;
  const int tid = (int)threadIdx.x;
  const int rg = tid >> 5;   // rows rg*4+i
  const int cg = tid & 31;   // cols cg*4+t

  float acc[3][4][4] = {};
  for (int kt = 0; kt < 4; ++kt) {
    __syncthreads();
    {
      int lin = tid << 2;
      int r = lin >> 5, c = lin & 31;
      int gr = row0 + r;
      float4 v = make_float4(0.f, 0.f, 0.f, 0.f);
      if (gr < NN) v = *(const float4*)(H + (size_t)gr * F + kt * 32 + c);
      As[r][c] = v.x; As[r][c + 1] = v.y; As[r][c + 2] = v.z; As[r][c + 3] = v.w;
    }
#pragma unroll
    for (int it = 0; it < 6; ++it) {
      int lin = it * 512 + tid;          // 0..3071 = 32 kk * 96 q
      int kk = lin / 96, q = lin % 96;
      *(float4*)&Ws[kk][q * 4] =
          *(const float4*)(Wpack + (size_t)(kt * 32 + kk) * 384 + q * 4);
    }
    __syncthreads();
#pragma unroll
    for (int kk = 0; kk < 32; ++kk) {
      float a[4];
#pragma unroll
      for (int i = 0; i < 4; ++i) a[i] = As[rg * 4 + i][kk];
      const float4 w0 = *(const float4*)&Ws[kk][cg * 4];
      const float4 w1 = *(const float4*)&Ws[kk][128 + cg * 4];
      const float4 w2 = *(const float4*)&Ws[kk][256 + cg * 4];
#pragma unroll
      for (int i = 0; i < 4; ++i) {
        acc[0][i][0] = fmaf(a[i], w0.x, acc[0][i][0]);
        acc[0][i][1] = fmaf(a[i], w0.y, acc[0][i][1]);
        acc[0][i][2] = fmaf(a[i], w0.z, acc[0][i][2]);
        acc[0][i][3] = fmaf(a[i], w0.w, acc[0][i][3]);
        acc[1][i][0] = fmaf(a[i], w1.x, acc[1][i][0]);
        acc[1][i][1] = fmaf(a[i], w1.y, acc[1][i][1]);
        acc[1][i][2] = fmaf(a[i], w1.z, acc[1][i][2]);
        acc[1][i][3] = fmaf(a[i], w1.w, acc[1][i][3]);
        acc[2][i][0] = fmaf(a[i], w2.x, acc[2][i][0]);
        acc[2][i][1] = fmaf(a[i], w2.y, acc[2][i][1]);
        acc[2][i][2] = fmaf(a[i], w2.z, acc[2][i][2]);
        acc[2][i][3] = fmaf(a[i], w2.w, acc[2][i][3]);
      }
    }
  }
  float bi[4], bg[4], bo[4];
#pragma unroll
  for (int t = 0; t < 4; ++t) {
    int j = cg * 4 + t;
    bi[t] = bselw[j];
    bg[t] = bselw[128 + j];
    bo[t] = bselw[256 + j];
  }
#pragma unroll
  for (int i = 0; i < 4; ++i) {
    int gr = row0 + rg * 4 + i;
    if (gr < NN) {
      float4 o;
#pragma unroll
      for (int t = 0; t < 4; ++t) {
        float iv = acc[0][i][t] + bi[t];
        float gv = acc[1][i][t] + bg[t];
        float ov = acc[2][i][t] + bo[t];
        float c = sigm(iv) * tanhf(gv);
        (&o.x)[t] = sigm(ov) * tanhf(c);
      }
      *(float4*)(out + (size_t)gr * F + cg * 4) = o;
    }
  }
}

extern "C" void kernel_launch(void* const* d_in, const int* in_sizes, int n_in,
                              void* d_out, int out_size, void* d_ws, size_t ws_size,
                              hipStream_t stream) {
  const float* x = (const float*)d_in[0];
  const int* src = (const int*)d_in[1];
  const int* dst = (const int*)d_in[2];
  const float* W1 = (const float*)d_in[3];   // [3][128][128] == Wcat1 [384][128]
  const float* b1 = (const float*)d_in[4];
  const float* W2 = (const float*)d_in[5];
  const float* b2 = (const float*)d_in[6];
  const float* Wih_f = (const float*)d_in[7];
  const float* bih_f = (const float*)d_in[9];
  const float* bhh_f = (const float*)d_in[10];
  const float* Wih_b = (const float*)d_in[11];
  const float* bih_b = (const float*)d_in[13];
  const float* bhh_b = (const float*)d_in[14];
  float* out = (float*)d_out;

  // workspace carve-up (~109 MB)
  float* rs_out = (float*)d_ws;                     // 3*NN f
  float* rs_in3 = rs_out + 3 * NN;                  // 3*NN f
  int* cnt_out = (int*)(rs_in3 + 3 * NN);           // 3*NN i
  int* cnt_in = cnt_out + 3 * NN;                   // 3*NN i
  int* row_ptr = cnt_in + 3 * NN;                   // 3*NN i
  int* cursor = row_ptr + 3 * NN;                   // 3*NN i
  int* bsums = cursor + 3 * NN;                     // 1024 i
  int2* ses = (int2*)(bsums + 1024);                // 3*NE int2
  float* Wpack = (float*)(ses + (size_t)3 * NE);    // 128*384 f
  float* bbar1 = Wpack + 128 * 384;                 // 128
  float* bbar2 = bbar1 + 128;                       // 128
  float* bselw = bbar2 + 128;                       // 384 (+pad to 640)
  float* z = bselw + 640;                           // CH*384 f
  float* h1 = z + (size_t)CH * 384;                 // NN*128 f

  // CSR + normalizers (shared by both layers)
  hipMemsetAsync(cnt_out, 0, (size_t)6 * NN * sizeof(int), stream);
  count_deg<<<(NREL * NE + 255) / 256, 256, 0, stream>>>(src, dst, cnt_out, cnt_in);
  make_rs<<<(NREL * NN + 255) / 256, 256, 0, stream>>>(cnt_out, cnt_in, rs_out, rs_in3);
  scan1<<<NREL * NBLK, 256, 0, stream>>>(cnt_in, row_ptr, bsums);
  scan2<<<NREL, 128, 0, stream>>>(bsums);
  scan3<<<(NREL * NN + 255) / 256, 256, 0, stream>>>(row_ptr, bsums, cursor);
  place_edges<<<(NREL * NE + 255) / 256, 256, 0, stream>>>(src, dst, rs_out, cursor, ses);
  prep_small<<<1, 640, 0, stream>>>(b1, b2, bih_f, bhh_f, bih_b, bhh_b, bbar1, bbar2, bselw);
  pack_w<<<(128 * 384 + 255) / 256, 256, 0, stream>>>(Wih_f, Wih_b, Wpack);

  // layer 1: x -> h1 (relu)
  for (int c = 0; c < NCH; ++c) {
    gather3<<<CH / 4, 256, 0, stream>>>(x, ses, row_ptr, cnt_in, rs_in3, z, c * CH);
    gemm_zcat<true><<<(CH + 127) / 128, 256, 0, stream>>>(z, W1, bbar1, h1, c * CH);
  }
  // layer 2: h1 -> d_out (h2)
  for (int c = 0; c < NCH; ++c) {
    gather3<<<CH / 4, 256, 0, stream>>>(h1, ses, row_ptr, cnt_in, rs_in3, z, c * CH);
    gemm_zcat<false><<<(CH + 127) / 128, 256, 0, stream>>>(z, W2, bbar2, out, c * CH);
  }
  // fused BiLSTM step, in place on d_out (row-disjoint blocks)
  lstm_fused2<<<(NN + 63) / 64, 512, 0, stream>>>(out, Wpack, bselw, out);
}

// Round 4
// 780.436 us; speedup vs baseline: 1.8356x; 1.8356x over previous
//
#include <hip/hip_runtime.h>
#include <math.h>

#define NN 100000
#define NE 500000
#define NREL 3
#define F 128
#define SCAN_BLK 1024
#define NBLK ((NN + SCAN_BLK - 1) / SCAN_BLK)   // 98
#define CH 25000
#define NCH 4

typedef __attribute__((ext_vector_type(8))) short bf16x8;
typedef __attribute__((ext_vector_type(4))) float f32x4;

__device__ __forceinline__ float sigm(float x) { return 1.f / (1.f + __expf(-x)); }

__device__ __forceinline__ unsigned bf16rne(float x) {
  unsigned u = __float_as_uint(x);
  return (u + 0x7FFFu + ((u >> 16) & 1u)) >> 16;
}
__device__ __forceinline__ void split1(float x, unsigned& h, unsigned& l) {
  h = bf16rne(x);
  float hf = __uint_as_float(h << 16);
  l = bf16rne(x - hf);
}

// ---- degree counting ----
__global__ void count_deg(const int* __restrict__ src, const int* __restrict__ dst,
                          int* __restrict__ cnt_out, int* __restrict__ cnt_in) {
  int i = blockIdx.x * blockDim.x + threadIdx.x;
  if (i >= NREL * NE) return;
  int r = i / NE;
  atomicAdd(&cnt_out[r * NN + src[i]], 1);
  atomicAdd(&cnt_in[r * NN + dst[i]], 1);
}

__global__ void make_rs(const int* __restrict__ cnt_out, const int* __restrict__ cnt_in,
                        float* __restrict__ rs_out, float* __restrict__ rs_in3) {
  int i = blockIdx.x * blockDim.x + threadIdx.x;
  if (i >= NREL * NN) return;
  int c0 = cnt_out[i];
  rs_out[i] = rsqrtf((float)(c0 < 1 ? 1 : c0));
  int c1 = cnt_in[i];
  rs_in3[i] = rsqrtf((float)(c1 < 1 ? 1 : c1)) * (1.f / 3.f);
}

// ---- two-level exclusive scan of cnt_in -> row_ptr ----
__global__ __launch_bounds__(256) void scan1(const int* __restrict__ cnt,
                                             int* __restrict__ excl, int* __restrict__ bsums) {
  int rb = blockIdx.x;
  int r = rb / NBLK, blk = rb % NBLK;
  int tid = (int)threadIdx.x;
  int v[4]; int sum = 0;
#pragma unroll
  for (int i = 0; i < 4; ++i) {
    int idx = blk * SCAN_BLK + tid * 4 + i;
    int c = (idx < NN) ? cnt[r * NN + idx] : 0;
    v[i] = sum; sum += c;
  }
  __shared__ int ts[256];
  ts[tid] = sum;
  __syncthreads();
  for (int off = 1; off < 256; off <<= 1) {
    int t = (tid >= off) ? ts[tid - off] : 0;
    __syncthreads();
    ts[tid] += t;
    __syncthreads();
  }
  int texcl = tid ? ts[tid - 1] : 0;
#pragma unroll
  for (int i = 0; i < 4; ++i) {
    int idx = blk * SCAN_BLK + tid * 4 + i;
    if (idx < NN) excl[r * NN + idx] = texcl + v[i];
  }
  if (tid == 255) bsums[rb] = ts[255];
}

__global__ __launch_bounds__(128) void scan2(int* __restrict__ bsums) {
  int r = blockIdx.x;
  int tid = (int)threadIdx.x;
  __shared__ int ts[128];
  ts[tid] = (tid < NBLK) ? bsums[r * NBLK + tid] : 0;
  __syncthreads();
  for (int off = 1; off < 128; off <<= 1) {
    int t = (tid >= off) ? ts[tid - off] : 0;
    __syncthreads();
    ts[tid] += t;
    __syncthreads();
  }
  if (tid < NBLK) bsums[r * NBLK + tid] = tid ? ts[tid - 1] : 0;
}

__global__ void scan3(int* __restrict__ row_ptr, const int* __restrict__ bsums,
                      int* __restrict__ cursor) {
  int i = blockIdx.x * blockDim.x + threadIdx.x;
  if (i >= NREL * NN) return;
  int r = i / NN, idx = i - r * NN, blk = idx / SCAN_BLK;
  int val = row_ptr[i] + bsums[r * NBLK + blk];
  row_ptr[i] = val;
  cursor[i] = val;
}

// counting-sort edges by dst; store (src, rs_out[src]) pairs
__global__ void place_edges(const int* __restrict__ src, const int* __restrict__ dst,
                            const float* __restrict__ rs_out,
                            int* __restrict__ cursor, int2* __restrict__ ses) {
  int i = blockIdx.x * blockDim.x + threadIdx.x;
  if (i >= NREL * NE) return;
  int r = i / NE;
  int s = src[i];
  int pos = atomicAdd(&cursor[r * NN + dst[i]], 1);
  ses[(size_t)r * NE + pos] = make_int2(s, __float_as_int(rs_out[r * NN + s]));
}

// biases: bbar1/bbar2 (mean over relations), bselw (lstm gate biases, m = g*128 + dir*64 + jj)
__global__ void prep_small(const float* __restrict__ b1, const float* __restrict__ b2,
                           const float* __restrict__ bif, const float* __restrict__ bhf,
                           const float* __restrict__ bib, const float* __restrict__ bhb,
                           float* __restrict__ bbar1, float* __restrict__ bbar2,
                           float* __restrict__ bselw) {
  int t = (int)threadIdx.x;
  if (t < 128) {
    bbar1[t] = (b1[t] + b1[128 + t] + b1[256 + t]) * (1.f / 3.f);
  } else if (t < 256) {
    int j = t - 128;
    bbar2[j] = (b2[j] + b2[128 + j] + b2[256 + j]) * (1.f / 3.f);
  } else if (t < 640) {
    int m = t - 256;
    int g = m >> 7, j = m & 127, dir = j >> 6, jj = j & 63;
    int grow = (g == 0) ? jj : (g == 1) ? (128 + jj) : (192 + jj);
    bselw[m] = dir ? (bib[grow] + bhb[grow]) : (bif[grow] + bhf[grow]);
  }
}

// W[384][128] (k-major) -> split-bf16 transposed planes WT[n][k], n-major k-contiguous
__global__ void wt_split(const float* __restrict__ W, ushort* __restrict__ th,
                         ushort* __restrict__ tl) {
  int i = blockIdx.x * blockDim.x + threadIdx.x;
  if (i >= 128 * 384) return;
  int n = i / 384, k = i % 384;
  float v = W[(size_t)k * 128 + n];
  unsigned h, l; split1(v, h, l);
  th[i] = (ushort)h; tl[i] = (ushort)l;
}

// lstm gate weights, packed+split: Wp[m][k], m = g*128 + dir*64 + jj
__global__ void pack_w_split(const float* __restrict__ Wf, const float* __restrict__ Wb,
                             ushort* __restrict__ ph, ushort* __restrict__ pl) {
  int i = blockIdx.x * blockDim.x + threadIdx.x;
  if (i >= 384 * 128) return;
  int m = i / 128, k = i % 128;
  int g = m >> 7, j = m & 127, dir = j >> 6, jj = j & 63;
  int grow = (g == 0) ? jj : (g == 1) ? (128 + jj) : (192 + jj);
  float v = (dir ? Wb : Wf)[(size_t)grow * 128 + k];
  unsigned h, l; split1(v, h, l);
  ph[i] = (ushort)h; pl[i] = (ushort)l;
}

// gather: one wave per (node, relation). 2 rows per load instr (float4/lane,
// halves own different edges), broadcast index loads, shfl_xor(32) reduce.
// writes z split-bf16 planes [CH][384].
__global__ __launch_bounds__(256) void gather3(
    const float* __restrict__ table, const int2* __restrict__ ses,
    const int* __restrict__ row_ptr, const int* __restrict__ cnt,
    const float* __restrict__ rs_in3, ushort* __restrict__ z_h,
    ushort* __restrict__ z_l, int n0) {
  int wid = (int)threadIdx.x >> 6, lane = (int)threadIdx.x & 63;
  int gw = blockIdx.x * 4 + wid;          // 0 .. 3*CH-1
  int r = gw / CH;
  int n = n0 + (gw - r * CH);
  int base = r * NN + n;
  int beg = row_ptr[base], c = cnt[base];
  const int2* el = ses + (size_t)r * NE + beg;
  int half = lane >> 5, cl = lane & 31;   // cols cl*4 .. cl*4+3
  const float4* x4 = (const float4*)table + cl;   // row stride 32 float4
  float4 acc = make_float4(0.f, 0.f, 0.f, 0.f);
  int p = 0;
  for (; p + 8 <= c; p += 8) {
    int2 e0 = el[p + 0], e1 = el[p + 1], e2 = el[p + 2], e3 = el[p + 3];
    int2 e4 = el[p + 4], e5 = el[p + 5], e6 = el[p + 6], e7 = el[p + 7];
    int s0 = half ? e1.x : e0.x; float c0 = __int_as_float(half ? e1.y : e0.y);
    int s1 = half ? e3.x : e2.x; float c1 = __int_as_float(half ? e3.y : e2.y);
    int s2 = half ? e5.x : e4.x; float c2 = __int_as_float(half ? e5.y : e4.y);
    int s3 = half ? e7.x : e6.x; float c3 = __int_as_float(half ? e7.y : e6.y);
    float4 v0 = x4[(size_t)s0 * 32];
    float4 v1 = x4[(size_t)s1 * 32];
    float4 v2 = x4[(size_t)s2 * 32];
    float4 v3 = x4[(size_t)s3 * 32];
    acc.x = fmaf(v0.x, c0, acc.x); acc.y = fmaf(v0.y, c0, acc.y);
    acc.z = fmaf(v0.z, c0, acc.z); acc.w = fmaf(v0.w, c0, acc.w);
    acc.x = fmaf(v1.x, c1, acc.x); acc.y = fmaf(v1.y, c1, acc.y);
    acc.z = fmaf(v1.z, c1, acc.z); acc.w = fmaf(v1.w, c1, acc.w);
    acc.x = fmaf(v2.x, c2, acc.x); acc.y = fmaf(v2.y, c2, acc.y);
    acc.z = fmaf(v2.z, c2, acc.z); acc.w = fmaf(v2.w, c2, acc.w);
    acc.x = fmaf(v3.x, c3, acc.x); acc.y = fmaf(v3.y, c3, acc.y);
    acc.z = fmaf(v3.z, c3, acc.z); acc.w = fmaf(v3.w, c3, acc.w);
  }
  for (; p < c; p += 2) {
    int2 ea = el[p];
    int2 eb = (p + 1 < c) ? el[p + 1] : make_int2(ea.x, 0);
    int s = half ? eb.x : ea.x; float sc = __int_as_float(half ? eb.y : ea.y);
    float4 v = x4[(size_t)s * 32];
    acc.x = fmaf(v.x, sc, acc.x); acc.y = fmaf(v.y, sc, acc.y);
    acc.z = fmaf(v.z, sc, acc.z); acc.w = fmaf(v.w, sc, acc.w);
  }
  acc.x += __shfl_xor(acc.x, 32);
  acc.y += __shfl_xor(acc.y, 32);
  acc.z += __shfl_xor(acc.z, 32);
  acc.w += __shfl_xor(acc.w, 32);
  float ci = rs_in3[base];
  unsigned h[4], l[4];
  split1(acc.x * ci, h[0], l[0]); split1(acc.y * ci, h[1], l[1]);
  split1(acc.z * ci, h[2], l[2]); split1(acc.w * ci, h[3], l[3]);
  size_t zo = (size_t)(n - n0) * 384 + r * 128 + cl * 4;
  if (half == 0) {
    *(ushort2*)(z_h + zo) = make_ushort2((ushort)h[0], (ushort)h[1]);
    *(ushort2*)(z_h + zo + 2) = make_ushort2((ushort)h[2], (ushort)h[3]);
  } else {
    *(ushort2*)(z_l + zo) = make_ushort2((ushort)l[0], (ushort)l[1]);
    *(ushort2*)(z_l + zo + 2) = make_ushort2((ushort)l[2], (ushort)l[3]);
  }
}

// LDS swizzle: 16B slot index xor'd by row bits -> 2-way max on ds_read_b128
__device__ __forceinline__ int swz(int row, int slot) {
  return row * 32 + ((slot ^ ((row >> 1) & 3)) << 3);   // ushort index
}

// H[n0+row][:] = (relu?)(Z[row,0:384] @ WT^T + bias), split-bf16 MFMA 16x16x32
// block: 256 thr = 4 waves, BM=64, BN=128 (wave = 64x32), BK=32, 12 ksteps.
template <bool RELU>
__global__ __launch_bounds__(256) void gemm_mfma(
    const ushort* __restrict__ zh, const ushort* __restrict__ zl,
    const ushort* __restrict__ wth, const ushort* __restrict__ wtl,
    const float* __restrict__ bias, float* __restrict__ H, int n0) {
  __shared__ ushort Ash[64 * 32], Asl[64 * 32], Bsh[128 * 32], Bsl[128 * 32];
  const int row0 = blockIdx.x * 64;
  const int t = (int)threadIdx.x;
  const int wn = t >> 6, l = t & 63, lr = l & 15, lk = l >> 4;
  f32x4 acc[4][2];
#pragma unroll
  for (int a = 0; a < 4; ++a)
#pragma unroll
    for (int b = 0; b < 2; ++b) acc[a][b] = (f32x4){0.f, 0.f, 0.f, 0.f};

  for (int kt = 0; kt < 12; ++kt) {
    __syncthreads();
    {   // stage A planes: 64 rows x 32 k
      int rr = t >> 2, slot = t & 3;
      size_t go = (size_t)(row0 + rr) * 384 + kt * 32 + slot * 8;
      uint4 vh = make_uint4(0, 0, 0, 0), vl = make_uint4(0, 0, 0, 0);
      if (row0 + rr < CH) { vh = *(const uint4*)(zh + go); vl = *(const uint4*)(zl + go); }
      *(uint4*)&Ash[swz(rr, slot)] = vh;
      *(uint4*)&Asl[swz(rr, slot)] = vl;
    }
#pragma unroll
    for (int i = 0; i < 2; ++i) {   // stage B planes: 128 n x 32 k
      int s = i * 256 + t;
      int nn_ = s >> 2, slot = s & 3;
      size_t go = (size_t)nn_ * 384 + kt * 32 + slot * 8;
      *(uint4*)&Bsh[swz(nn_, slot)] = *(const uint4*)(wth + go);
      *(uint4*)&Bsl[swz(nn_, slot)] = *(const uint4*)(wtl + go);
    }
    __syncthreads();
    bf16x8 ah[4], al[4], bh[2], bl[2];
#pragma unroll
    for (int mf = 0; mf < 4; ++mf) {
      int row = mf * 16 + lr;
      int off = swz(row, lk);
      ah[mf] = *(const bf16x8*)&Ash[off];
      al[mf] = *(const bf16x8*)&Asl[off];
    }
#pragma unroll
    for (int f = 0; f < 2; ++f) {
      int col = wn * 32 + f * 16 + lr;
      int off = swz(col, lk);
      bh[f] = *(const bf16x8*)&Bsh[off];
      bl[f] = *(const bf16x8*)&Bsl[off];
    }
#pragma unroll
    for (int mf = 0; mf < 4; ++mf)
#pragma unroll
      for (int f = 0; f < 2; ++f) {
        acc[mf][f] = __builtin_amdgcn_mfma_f32_16x16x32_bf16(ah[mf], bh[f], acc[mf][f], 0, 0, 0);
        acc[mf][f] = __builtin_amdgcn_mfma_f32_16x16x32_bf16(ah[mf], bl[f], acc[mf][f], 0, 0, 0);
        acc[mf][f] = __builtin_amdgcn_mfma_f32_16x16x32_bf16(al[mf], bh[f], acc[mf][f], 0, 0, 0);
      }
  }
#pragma unroll
  for (int mf = 0; mf < 4; ++mf)
#pragma unroll
    for (int f = 0; f < 2; ++f) {
      int col = wn * 32 + f * 16 + lr;
      float bv = bias[col];
#pragma unroll
      for (int reg = 0; reg < 4; ++reg) {
        int row = row0 + mf * 16 + lk * 4 + reg;
        if (row < CH) {
          float v = acc[mf][f][reg] + bv;
          if (RELU) v = fmaxf(v, 0.f);
          H[(size_t)(n0 + row) * 128 + col] = v;
        }
      }
    }
}

// BiLSTM step: out = act(H[NN,128] @ Wp^T[128,384] + b), gates i,g,o in-register.
// 512 thr = 8 waves (wm 0..1, wn 0..3); BM=128, BN=384; wave n-frags {wn+4t}.
__global__ __launch_bounds__(512) void lstm_mfma(
    const float* __restrict__ H, const ushort* __restrict__ wph,
    const ushort* __restrict__ wpl, const float* __restrict__ bselw,
    float* __restrict__ out) {
  __shared__ ushort Ash[128 * 32], Asl[128 * 32], Bsh[384 * 32], Bsl[384 * 32]; // 64 KB
  const int row0 = blockIdx.x * 128;
  const int t = (int)threadIdx.x;
  const int wid = t >> 6, wm = wid >> 2, wn = wid & 3;
  const int l = t & 63, lr = l & 15, lk = l >> 4;

  // bias regs for this thread's two output columns
  int j0 = wn * 16 + lr, j1 = (wn + 4) * 16 + lr;
  float bi0 = bselw[j0], bg0 = bselw[128 + j0], bo0 = bselw[256 + j0];
  float bi1 = bselw[j1], bg1 = bselw[128 + j1], bo1 = bselw[256 + j1];

  f32x4 acc[4][6];
#pragma unroll
  for (int a = 0; a < 4; ++a)
#pragma unroll
    for (int b = 0; b < 6; ++b) acc[a][b] = (f32x4){0.f, 0.f, 0.f, 0.f};

  for (int kt = 0; kt < 4; ++kt) {
    __syncthreads();
    {   // stage A: 128 rows x 32 k, split f32 -> bf16 hi/lo
      int rr = t >> 2, slot = t & 3;
      int grow = row0 + rr;
      float v[8];
      if (grow < NN) {
        float4 a0 = *(const float4*)(H + (size_t)grow * 128 + kt * 32 + slot * 8);
        float4 a1 = *(const float4*)(H + (size_t)grow * 128 + kt * 32 + slot * 8 + 4);
        v[0] = a0.x; v[1] = a0.y; v[2] = a0.z; v[3] = a0.w;
        v[4] = a1.x; v[5] = a1.y; v[6] = a1.z; v[7] = a1.w;
      } else {
#pragma unroll
        for (int q = 0; q < 8; ++q) v[q] = 0.f;
      }
      unsigned h[8], lo[8];
#pragma unroll
      for (int q = 0; q < 8; ++q) split1(v[q], h[q], lo[q]);
      uint4 hv = make_uint4(h[0] | (h[1] << 16), h[2] | (h[3] << 16),
                            h[4] | (h[5] << 16), h[6] | (h[7] << 16));
      uint4 lv = make_uint4(lo[0] | (lo[1] << 16), lo[2] | (lo[3] << 16),
                            lo[4] | (lo[5] << 16), lo[6] | (lo[7] << 16));
      *(uint4*)&Ash[swz(rr, slot)] = hv;
      *(uint4*)&Asl[swz(rr, slot)] = lv;
    }
#pragma unroll
    for (int i = 0; i < 3; ++i) {   // stage B: 384 m x 32 k
      int s = i * 512 + t;
      int nn_ = s >> 2, slot = s & 3;
      size_t go = (size_t)nn_ * 128 + kt * 32 + slot * 8;
      *(uint4*)&Bsh[swz(nn_, slot)] = *(const uint4*)(wph + go);
      *(uint4*)&Bsl[swz(nn_, slot)] = *(const uint4*)(wpl + go);
    }
    __syncthreads();
    bf16x8 ah[4], al[4];
#pragma unroll
    for (int mf = 0; mf < 4; ++mf) {
      int row = wm * 64 + mf * 16 + lr;
      int off = swz(row, lk);
      ah[mf] = *(const bf16x8*)&Ash[off];
      al[mf] = *(const bf16x8*)&Asl[off];
    }
#pragma unroll
    for (int tt = 0; tt < 6; ++tt) {
      int col = (wn + 4 * tt) * 16 + lr;
      int off = swz(col, lk);
      bf16x8 bh = *(const bf16x8*)&Bsh[off];
      bf16x8 bl = *(const bf16x8*)&Bsl[off];
#pragma unroll
      for (int mf = 0; mf < 4; ++mf) {
        acc[mf][tt] = __builtin_amdgcn_mfma_f32_16x16x32_bf16(ah[mf], bh, acc[mf][tt], 0, 0, 0);
        acc[mf][tt] = __builtin_amdgcn_mfma_f32_16x16x32_bf16(ah[mf], bl, acc[mf][tt], 0, 0, 0);
        acc[mf][tt] = __builtin_amdgcn_mfma_f32_16x16x32_bf16(al[mf], bh, acc[mf][tt], 0, 0, 0);
      }
    }
  }
#pragma unroll
  for (int mf = 0; mf < 4; ++mf)
#pragma unroll
    for (int reg = 0; reg < 4; ++reg) {
      int row = row0 + wm * 64 + mf * 16 + lk * 4 + reg;
      if (row < NN) {
        float iv0 = acc[mf][0][reg] + bi0, gv0 = acc[mf][2][reg] + bg0, ov0 = acc[mf][4][reg] + bo0;
        float cc0 = sigm(iv0) * tanhf(gv0);
        out[(size_t)row * 128 + j0] = sigm(ov0) * tanhf(cc0);
        float iv1 = acc[mf][1][reg] + bi1, gv1 = acc[mf][3][reg] + bg1, ov1 = acc[mf][5][reg] + bo1;
        float cc1 = sigm(iv1) * tanhf(gv1);
        out[(size_t)row * 128 + j1] = sigm(ov1) * tanhf(cc1);
      }
    }
}

extern "C" void kernel_launch(void* const* d_in, const int* in_sizes, int n_in,
                              void* d_out, int out_size, void* d_ws, size_t ws_size,
                              hipStream_t stream) {
  const float* x = (const float*)d_in[0];
  const int* src = (const int*)d_in[1];
  const int* dst = (const int*)d_in[2];
  const float* W1 = (const float*)d_in[3];   // [3][128][128] = Wcat [384][128]
  const float* b1 = (const float*)d_in[4];
  const float* W2 = (const float*)d_in[5];
  const float* b2 = (const float*)d_in[6];
  const float* Wih_f = (const float*)d_in[7];
  const float* bih_f = (const float*)d_in[9];
  const float* bhh_f = (const float*)d_in[10];
  const float* Wih_b = (const float*)d_in[11];
  const float* bih_b = (const float*)d_in[13];
  const float* bhh_b = (const float*)d_in[14];
  float* out = (float*)d_out;

  // workspace carve-up (~110 MB)
  char* wp = (char*)d_ws;
  float* rs_out = (float*)wp;          wp += (size_t)3 * NN * 4;
  float* rs_in3 = (float*)wp;          wp += (size_t)3 * NN * 4;
  int* cnt_out = (int*)wp;             wp += (size_t)3 * NN * 4;
  int* cnt_in = (int*)wp;              wp += (size_t)3 * NN * 4;
  int* row_ptr = (int*)wp;             wp += (size_t)3 * NN * 4;
  int* cursor = (int*)wp;              wp += (size_t)3 * NN * 4;
  int* bsums = (int*)wp;               wp += 4096;
  int2* ses = (int2*)wp;               wp += (size_t)3 * NE * 8;
  ushort* wt1h = (ushort*)wp;          wp += (size_t)128 * 384 * 2;
  ushort* wt1l = (ushort*)wp;          wp += (size_t)128 * 384 * 2;
  ushort* wt2h = (ushort*)wp;          wp += (size_t)128 * 384 * 2;
  ushort* wt2l = (ushort*)wp;          wp += (size_t)128 * 384 * 2;
  ushort* wph = (ushort*)wp;           wp += (size_t)384 * 128 * 2;
  ushort* wpl = (ushort*)wp;           wp += (size_t)384 * 128 * 2;
  float* bbar1 = (float*)wp;           wp += 512;
  float* bbar2 = (float*)wp;           wp += 512;
  float* bselw = (float*)wp;           wp += 2048;
  ushort* z_h = (ushort*)wp;           wp += (size_t)CH * 384 * 2;
  ushort* z_l = (ushort*)wp;           wp += (size_t)CH * 384 * 2;
  float* h1 = (float*)wp;              wp += (size_t)NN * 128 * 4;

  // CSR + normalizers + weight prep
  hipMemsetAsync(cnt_out, 0, (size_t)6 * NN * sizeof(int), stream);
  count_deg<<<(NREL * NE + 255) / 256, 256, 0, stream>>>(src, dst, cnt_out, cnt_in);
  make_rs<<<(NREL * NN + 255) / 256, 256, 0, stream>>>(cnt_out, cnt_in, rs_out, rs_in3);
  scan1<<<NREL * NBLK, 256, 0, stream>>>(cnt_in, row_ptr, bsums);
  scan2<<<NREL, 128, 0, stream>>>(bsums);
  scan3<<<(NREL * NN + 255) / 256, 256, 0, stream>>>(row_ptr, bsums, cursor);
  place_edges<<<(NREL * NE + 255) / 256, 256, 0, stream>>>(src, dst, rs_out, cursor, ses);
  prep_small<<<1, 640, 0, stream>>>(b1, b2, bih_f, bhh_f, bih_b, bhh_b, bbar1, bbar2, bselw);
  wt_split<<<192, 256, 0, stream>>>(W1, wt1h, wt1l);
  wt_split<<<192, 256, 0, stream>>>(W2, wt2h, wt2l);
  pack_w_split<<<192, 256, 0, stream>>>(Wih_f, Wih_b, wph, wpl);

  // layer 1: x -> h1 (relu)
  for (int c = 0; c < NCH; ++c) {
    gather3<<<3 * CH / 4, 256, 0, stream>>>(x, ses, row_ptr, cnt_in, rs_in3, z_h, z_l, c * CH);
    gemm_mfma<true><<<(CH + 63) / 64, 256, 0, stream>>>(z_h, z_l, wt1h, wt1l, bbar1, h1, c * CH);
  }
  // layer 2: h1 -> d_out
  for (int c = 0; c < NCH; ++c) {
    gather3<<<3 * CH / 4, 256, 0, stream>>>(h1, ses, row_ptr, cnt_in, rs_in3, z_h, z_l, c * CH);
    gemm_mfma<false><<<(CH + 63) / 64, 256, 0, stream>>>(z_h, z_l, wt2h, wt2l, bbar2, out, c * CH);
  }
  // BiLSTM step, in place on d_out (blocks read only their own rows)
  lstm_mfma<<<(NN + 127) / 128, 512, 0, stream>>>(out, wph, wpl, bselw, out);
}

// Round 5
// 771.968 us; speedup vs baseline: 1.8558x; 1.0110x over previous
//
#include <hip/hip_runtime.h>
#include <hip/hip_fp16.h>
#include <math.h>

#define NN 100000
#define NE 500000
#define NREL 3
#define F 128
#define SCAN_BLK 1024
#define NBLK ((NN + SCAN_BLK - 1) / SCAN_BLK)   // 98
#define CH 25000
#define NCH 4

typedef __attribute__((ext_vector_type(8))) short bf16x8;
typedef __attribute__((ext_vector_type(4))) float f32x4;

__device__ __forceinline__ float sigm(float x) { return 1.f / (1.f + __expf(-x)); }

__device__ __forceinline__ unsigned bf16rne(float x) {
  unsigned u = __float_as_uint(x);
  return (u + 0x7FFFu + ((u >> 16) & 1u)) >> 16;
}
__device__ __forceinline__ void split1(float x, unsigned& h, unsigned& l) {
  h = bf16rne(x);
  float hf = __uint_as_float(h << 16);
  l = bf16rne(x - hf);
}

// ---- degree counting ----
__global__ void count_deg(const int* __restrict__ src, const int* __restrict__ dst,
                          int* __restrict__ cnt_out, int* __restrict__ cnt_in) {
  int i = blockIdx.x * blockDim.x + threadIdx.x;
  if (i >= NREL * NE) return;
  int r = i / NE;
  atomicAdd(&cnt_out[r * NN + src[i]], 1);
  atomicAdd(&cnt_in[r * NN + dst[i]], 1);
}

__global__ void make_rs(const int* __restrict__ cnt_out, const int* __restrict__ cnt_in,
                        float* __restrict__ rs_out, float* __restrict__ rs_in3) {
  int i = blockIdx.x * blockDim.x + threadIdx.x;
  if (i >= NREL * NN) return;
  int c0 = cnt_out[i];
  rs_out[i] = rsqrtf((float)(c0 < 1 ? 1 : c0));
  int c1 = cnt_in[i];
  rs_in3[i] = rsqrtf((float)(c1 < 1 ? 1 : c1)) * (1.f / 3.f);
}

// ---- two-level exclusive scan of cnt_in -> row_ptr ----
__global__ __launch_bounds__(256) void scan1(const int* __restrict__ cnt,
                                             int* __restrict__ excl, int* __restrict__ bsums) {
  int rb = blockIdx.x;
  int r = rb / NBLK, blk = rb % NBLK;
  int tid = (int)threadIdx.x;
  int v[4]; int sum = 0;
#pragma unroll
  for (int i = 0; i < 4; ++i) {
    int idx = blk * SCAN_BLK + tid * 4 + i;
    int c = (idx < NN) ? cnt[r * NN + idx] : 0;
    v[i] = sum; sum += c;
  }
  __shared__ int ts[256];
  ts[tid] = sum;
  __syncthreads();
  for (int off = 1; off < 256; off <<= 1) {
    int t = (tid >= off) ? ts[tid - off] : 0;
    __syncthreads();
    ts[tid] += t;
    __syncthreads();
  }
  int texcl = tid ? ts[tid - 1] : 0;
#pragma unroll
  for (int i = 0; i < 4; ++i) {
    int idx = blk * SCAN_BLK + tid * 4 + i;
    if (idx < NN) excl[r * NN + idx] = texcl + v[i];
  }
  if (tid == 255) bsums[rb] = ts[255];
}

__global__ __launch_bounds__(128) void scan2(int* __restrict__ bsums) {
  int r = blockIdx.x;
  int tid = (int)threadIdx.x;
  __shared__ int ts[128];
  ts[tid] = (tid < NBLK) ? bsums[r * NBLK + tid] : 0;
  __syncthreads();
  for (int off = 1; off < 128; off <<= 1) {
    int t = (tid >= off) ? ts[tid - off] : 0;
    __syncthreads();
    ts[tid] += t;
    __syncthreads();
  }
  if (tid < NBLK) bsums[r * NBLK + tid] = tid ? ts[tid - 1] : 0;
}

__global__ void scan3(int* __restrict__ row_ptr, const int* __restrict__ bsums,
                      int* __restrict__ cursor) {
  int i = blockIdx.x * blockDim.x + threadIdx.x;
  if (i >= NREL * NN) return;
  int r = i / NN, idx = i - r * NN, blk = idx / SCAN_BLK;
  int val = row_ptr[i] + bsums[r * NBLK + blk];
  row_ptr[i] = val;
  cursor[i] = val;
}

// counting-sort edges by dst; store (src, rs_out[src]) pairs
__global__ void place_edges(const int* __restrict__ src, const int* __restrict__ dst,
                            const float* __restrict__ rs_out,
                            int* __restrict__ cursor, int2* __restrict__ ses) {
  int i = blockIdx.x * blockDim.x + threadIdx.x;
  if (i >= NREL * NE) return;
  int r = i / NE;
  int s = src[i];
  int pos = atomicAdd(&cursor[r * NN + dst[i]], 1);
  ses[(size_t)r * NE + pos] = make_int2(s, __float_as_int(rs_out[r * NN + s]));
}

// biases
__global__ void prep_small(const float* __restrict__ b1, const float* __restrict__ b2,
                           const float* __restrict__ bif, const float* __restrict__ bhf,
                           const float* __restrict__ bib, const float* __restrict__ bhb,
                           float* __restrict__ bbar1, float* __restrict__ bbar2,
                           float* __restrict__ bselw) {
  int t = (int)threadIdx.x;
  if (t < 128) {
    bbar1[t] = (b1[t] + b1[128 + t] + b1[256 + t]) * (1.f / 3.f);
  } else if (t < 256) {
    int j = t - 128;
    bbar2[j] = (b2[j] + b2[128 + j] + b2[256 + j]) * (1.f / 3.f);
  } else if (t < 640) {
    int m = t - 256;
    int g = m >> 7, j = m & 127, dir = j >> 6, jj = j & 63;
    int grow = (g == 0) ? jj : (g == 1) ? (128 + jj) : (192 + jj);
    bselw[m] = dir ? (bib[grow] + bhb[grow]) : (bif[grow] + bhf[grow]);
  }
}

// W[384][128] (k-major) -> split-bf16 transposed planes WT[n][k]
__global__ void wt_split(const float* __restrict__ W, ushort* __restrict__ th,
                         ushort* __restrict__ tl) {
  int i = blockIdx.x * blockDim.x + threadIdx.x;
  if (i >= 128 * 384) return;
  int n = i / 384, k = i % 384;
  float v = W[(size_t)k * 128 + n];
  unsigned h, l; split1(v, h, l);
  th[i] = (ushort)h; tl[i] = (ushort)l;
}

// lstm gate weights, packed+split: Wp[m][k], m = g*128 + dir*64 + jj
__global__ void pack_w_split(const float* __restrict__ Wf, const float* __restrict__ Wb,
                             ushort* __restrict__ ph, ushort* __restrict__ pl) {
  int i = blockIdx.x * blockDim.x + threadIdx.x;
  if (i >= 384 * 128) return;
  int m = i / 128, k = i % 128;
  int g = m >> 7, j = m & 127, dir = j >> 6, jj = j & 63;
  int grow = (g == 0) ? jj : (g == 1) ? (128 + jj) : (192 + jj);
  float v = (dir ? Wb : Wf)[(size_t)grow * 128 + k];
  unsigned h, l; split1(v, h, l);
  ph[i] = (ushort)h; pl[i] = (ushort)l;
}

// f32 [NN,128] -> f16 table
__global__ void cvt_f16(const float* __restrict__ in, ushort* __restrict__ o16) {
  int i = blockIdx.x * blockDim.x + threadIdx.x;
  if (i >= NN * (F / 4)) return;
  float4 v = ((const float4*)in)[i];
  __half2 a = __floats2half2_rn(v.x, v.y);
  __half2 b = __floats2half2_rn(v.z, v.w);
  ((uint2*)o16)[i] = make_uint2(*(unsigned*)&a, *(unsigned*)&b);
}

// gather from f16 table: one wave per (node, relation); 2 rows per load instr
// (uint2 = 4 f16 per lane, half-waves own alternate edges), shfl_xor(32) reduce.
// writes z split-bf16 planes [CH][384].
__global__ __launch_bounds__(256) void gather3(
    const ushort* __restrict__ table, const int2* __restrict__ ses,
    const int* __restrict__ row_ptr, const int* __restrict__ cnt,
    const float* __restrict__ rs_in3, ushort* __restrict__ z_h,
    ushort* __restrict__ z_l, int n0) {
  int wid = (int)threadIdx.x >> 6, lane = (int)threadIdx.x & 63;
  int gw = blockIdx.x * 4 + wid;          // 0 .. 3*CH-1
  int r = gw / CH;
  int n = n0 + (gw - r * CH);
  int base = r * NN + n;
  int beg = row_ptr[base], c = cnt[base];
  const int2* el = ses + (size_t)r * NE + beg;
  int half = lane >> 5, cl = lane & 31;   // cols cl*4 .. cl*4+3
  const uint2* x2 = (const uint2*)table + cl;   // row stride 32 uint2 (256 B)
  float4 acc = make_float4(0.f, 0.f, 0.f, 0.f);
  int p = 0;
  for (; p + 8 <= c; p += 8) {
    int2 e0 = el[p + 0], e1 = el[p + 1], e2 = el[p + 2], e3 = el[p + 3];
    int2 e4 = el[p + 4], e5 = el[p + 5], e6 = el[p + 6], e7 = el[p + 7];
    int s0 = half ? e1.x : e0.x; float c0 = __int_as_float(half ? e1.y : e0.y);
    int s1 = half ? e3.x : e2.x; float c1 = __int_as_float(half ? e3.y : e2.y);
    int s2 = half ? e5.x : e4.x; float c2 = __int_as_float(half ? e5.y : e4.y);
    int s3 = half ? e7.x : e6.x; float c3 = __int_as_float(half ? e7.y : e6.y);
    uint2 r0 = x2[(size_t)s0 * 32];
    uint2 r1 = x2[(size_t)s1 * 32];
    uint2 r2 = x2[(size_t)s2 * 32];
    uint2 r3 = x2[(size_t)s3 * 32];
#pragma unroll
    for (int u = 0; u < 4; ++u) {
      uint2 rw = (u == 0) ? r0 : (u == 1) ? r1 : (u == 2) ? r2 : r3;
      float sc = (u == 0) ? c0 : (u == 1) ? c1 : (u == 2) ? c2 : c3;
      float2 f0 = __half22float2(*(__half2*)&rw.x);
      float2 f1 = __half22float2(*(__half2*)&rw.y);
      acc.x = fmaf(f0.x, sc, acc.x); acc.y = fmaf(f0.y, sc, acc.y);
      acc.z = fmaf(f1.x, sc, acc.z); acc.w = fmaf(f1.y, sc, acc.w);
    }
  }
  for (; p < c; p += 2) {
    int2 ea = el[p];
    int2 eb = (p + 1 < c) ? el[p + 1] : make_int2(ea.x, 0);
    int s = half ? eb.x : ea.x; float sc = __int_as_float(half ? eb.y : ea.y);
    uint2 rw = x2[(size_t)s * 32];
    float2 f0 = __half22float2(*(__half2*)&rw.x);
    float2 f1 = __half22float2(*(__half2*)&rw.y);
    acc.x = fmaf(f0.x, sc, acc.x); acc.y = fmaf(f0.y, sc, acc.y);
    acc.z = fmaf(f1.x, sc, acc.z); acc.w = fmaf(f1.y, sc, acc.w);
  }
  acc.x += __shfl_xor(acc.x, 32);
  acc.y += __shfl_xor(acc.y, 32);
  acc.z += __shfl_xor(acc.z, 32);
  acc.w += __shfl_xor(acc.w, 32);
  float ci = rs_in3[base];
  unsigned h[4], l[4];
  split1(acc.x * ci, h[0], l[0]); split1(acc.y * ci, h[1], l[1]);
  split1(acc.z * ci, h[2], l[2]); split1(acc.w * ci, h[3], l[3]);
  size_t zo = (size_t)(n - n0) * 384 + r * 128 + cl * 4;
  if (half == 0) {
    *(ushort2*)(z_h + zo) = make_ushort2((ushort)h[0], (ushort)h[1]);
    *(ushort2*)(z_h + zo + 2) = make_ushort2((ushort)h[2], (ushort)h[3]);
  } else {
    *(ushort2*)(z_l + zo) = make_ushort2((ushort)l[0], (ushort)l[1]);
    *(ushort2*)(z_l + zo + 2) = make_ushort2((ushort)l[2], (ushort)l[3]);
  }
}

// LDS swizzle: 16B slot index xor'd by row bits -> 2-way max on ds_read_b128
__device__ __forceinline__ int swz(int row, int slot) {
  return row * 32 + ((slot ^ ((row >> 1) & 3)) << 3);   // ushort index
}

// H = (relu?)(Z[row,0:384] @ WT^T + bias); OUT16 -> write f16 table, else f32.
template <bool RELU, bool OUT16>
__global__ __launch_bounds__(256) void gemm_mfma(
    const ushort* __restrict__ zh, const ushort* __restrict__ zl,
    const ushort* __restrict__ wth, const ushort* __restrict__ wtl,
    const float* __restrict__ bias, void* __restrict__ Hout, int n0) {
  __shared__ ushort Ash[64 * 32], Asl[64 * 32], Bsh[128 * 32], Bsl[128 * 32];
  const int row0 = blockIdx.x * 64;
  const int t = (int)threadIdx.x;
  const int wn = t >> 6, l = t & 63, lr = l & 15, lk = l >> 4;
  f32x4 acc[4][2];
#pragma unroll
  for (int a = 0; a < 4; ++a)
#pragma unroll
    for (int b = 0; b < 2; ++b) acc[a][b] = (f32x4){0.f, 0.f, 0.f, 0.f};

  for (int kt = 0; kt < 12; ++kt) {
    __syncthreads();
    {   // stage A planes: 64 rows x 32 k
      int rr = t >> 2, slot = t & 3;
      size_t go = (size_t)(row0 + rr) * 384 + kt * 32 + slot * 8;
      uint4 vh = make_uint4(0, 0, 0, 0), vl = make_uint4(0, 0, 0, 0);
      if (row0 + rr < CH) { vh = *(const uint4*)(zh + go); vl = *(const uint4*)(zl + go); }
      *(uint4*)&Ash[swz(rr, slot)] = vh;
      *(uint4*)&Asl[swz(rr, slot)] = vl;
    }
#pragma unroll
    for (int i = 0; i < 2; ++i) {   // stage B planes: 128 n x 32 k
      int s = i * 256 + t;
      int nn_ = s >> 2, slot = s & 3;
      size_t go = (size_t)nn_ * 384 + kt * 32 + slot * 8;
      *(uint4*)&Bsh[swz(nn_, slot)] = *(const uint4*)(wth + go);
      *(uint4*)&Bsl[swz(nn_, slot)] = *(const uint4*)(wtl + go);
    }
    __syncthreads();
    bf16x8 ah[4], al[4], bh[2], bl[2];
#pragma unroll
    for (int mf = 0; mf < 4; ++mf) {
      int row = mf * 16 + lr;
      int off = swz(row, lk);
      ah[mf] = *(const bf16x8*)&Ash[off];
      al[mf] = *(const bf16x8*)&Asl[off];
    }
#pragma unroll
    for (int f = 0; f < 2; ++f) {
      int col = wn * 32 + f * 16 + lr;
      int off = swz(col, lk);
      bh[f] = *(const bf16x8*)&Bsh[off];
      bl[f] = *(const bf16x8*)&Bsl[off];
    }
#pragma unroll
    for (int mf = 0; mf < 4; ++mf)
#pragma unroll
      for (int f = 0; f < 2; ++f) {
        acc[mf][f] = __builtin_amdgcn_mfma_f32_16x16x32_bf16(ah[mf], bh[f], acc[mf][f], 0, 0, 0);
        acc[mf][f] = __builtin_amdgcn_mfma_f32_16x16x32_bf16(ah[mf], bl[f], acc[mf][f], 0, 0, 0);
        acc[mf][f] = __builtin_amdgcn_mfma_f32_16x16x32_bf16(al[mf], bh[f], acc[mf][f], 0, 0, 0);
      }
  }
#pragma unroll
  for (int mf = 0; mf < 4; ++mf)
#pragma unroll
    for (int f = 0; f < 2; ++f) {
      int col = wn * 32 + f * 16 + lr;
      float bv = bias[col];
#pragma unroll
      for (int reg = 0; reg < 4; ++reg) {
        int row = row0 + mf * 16 + lk * 4 + reg;
        if (row < CH) {
          float v = acc[mf][f][reg] + bv;
          if (RELU) v = fmaxf(v, 0.f);
          if (OUT16) {
            __half hv = __float2half_rn(v);
            ((ushort*)Hout)[(size_t)(n0 + row) * 128 + col] = *(ushort*)&hv;
          } else {
            ((float*)Hout)[(size_t)(n0 + row) * 128 + col] = v;
          }
        }
      }
    }
}

// BiLSTM step: out = act(H[NN,128] @ Wp^T[128,384] + b), gates i,g,o in-register.
__global__ __launch_bounds__(512) void lstm_mfma(
    const float* __restrict__ H, const ushort* __restrict__ wph,
    const ushort* __restrict__ wpl, const float* __restrict__ bselw,
    float* __restrict__ out) {
  __shared__ ushort Ash[128 * 32], Asl[128 * 32], Bsh[384 * 32], Bsl[384 * 32]; // 64 KB
  const int row0 = blockIdx.x * 128;
  const int t = (int)threadIdx.x;
  const int wid = t >> 6, wm = wid >> 2, wn = wid & 3;
  const int l = t & 63, lr = l & 15, lk = l >> 4;

  int j0 = wn * 16 + lr, j1 = (wn + 4) * 16 + lr;
  float bi0 = bselw[j0], bg0 = bselw[128 + j0], bo0 = bselw[256 + j0];
  float bi1 = bselw[j1], bg1 = bselw[128 + j1], bo1 = bselw[256 + j1];

  f32x4 acc[4][6];
#pragma unroll
  for (int a = 0; a < 4; ++a)
#pragma unroll
    for (int b = 0; b < 6; ++b) acc[a][b] = (f32x4){0.f, 0.f, 0.f, 0.f};

  for (int kt = 0; kt < 4; ++kt) {
    __syncthreads();
    {   // stage A: 128 rows x 32 k, split f32 -> bf16 hi/lo
      int rr = t >> 2, slot = t & 3;
      int grow = row0 + rr;
      float v[8];
      if (grow < NN) {
        float4 a0 = *(const float4*)(H + (size_t)grow * 128 + kt * 32 + slot * 8);
        float4 a1 = *(const float4*)(H + (size_t)grow * 128 + kt * 32 + slot * 8 + 4);
        v[0] = a0.x; v[1] = a0.y; v[2] = a0.z; v[3] = a0.w;
        v[4] = a1.x; v[5] = a1.y; v[6] = a1.z; v[7] = a1.w;
      } else {
#pragma unroll
        for (int q = 0; q < 8; ++q) v[q] = 0.f;
      }
      unsigned h[8], lo[8];
#pragma unroll
      for (int q = 0; q < 8; ++q) split1(v[q], h[q], lo[q]);
      uint4 hv = make_uint4(h[0] | (h[1] << 16), h[2] | (h[3] << 16),
                            h[4] | (h[5] << 16), h[6] | (h[7] << 16));
      uint4 lv = make_uint4(lo[0] | (lo[1] << 16), lo[2] | (lo[3] << 16),
                            lo[4] | (lo[5] << 16), lo[6] | (lo[7] << 16));
      *(uint4*)&Ash[swz(rr, slot)] = hv;
      *(uint4*)&Asl[swz(rr, slot)] = lv;
    }
#pragma unroll
    for (int i = 0; i < 3; ++i) {   // stage B: 384 m x 32 k
      int s = i * 512 + t;
      int nn_ = s >> 2, slot = s & 3;
      size_t go = (size_t)nn_ * 128 + kt * 32 + slot * 8;
      *(uint4*)&Bsh[swz(nn_, slot)] = *(const uint4*)(wph + go);
      *(uint4*)&Bsl[swz(nn_, slot)] = *(const uint4*)(wpl + go);
    }
    __syncthreads();
    bf16x8 ah[4], al[4];
#pragma unroll
    for (int mf = 0; mf < 4; ++mf) {
      int row = wm * 64 + mf * 16 + lr;
      int off = swz(row, lk);
      ah[mf] = *(const bf16x8*)&Ash[off];
      al[mf] = *(const bf16x8*)&Asl[off];
    }
#pragma unroll
    for (int tt = 0; tt < 6; ++tt) {
      int col = (wn + 4 * tt) * 16 + lr;
      int off = swz(col, lk);
      bf16x8 bh = *(const bf16x8*)&Bsh[off];
      bf16x8 bl = *(const bf16x8*)&Bsl[off];
#pragma unroll
      for (int mf = 0; mf < 4; ++mf) {
        acc[mf][tt] = __builtin_amdgcn_mfma_f32_16x16x32_bf16(ah[mf], bh, acc[mf][tt], 0, 0, 0);
        acc[mf][tt] = __builtin_amdgcn_mfma_f32_16x16x32_bf16(ah[mf], bl, acc[mf][tt], 0, 0, 0);
        acc[mf][tt] = __builtin_amdgcn_mfma_f32_16x16x32_bf16(al[mf], bh, acc[mf][tt], 0, 0, 0);
      }
    }
  }
#pragma unroll
  for (int mf = 0; mf < 4; ++mf)
#pragma unroll
    for (int reg = 0; reg < 4; ++reg) {
      int row = row0 + wm * 64 + mf * 16 + lk * 4 + reg;
      if (row < NN) {
        float iv0 = acc[mf][0][reg] + bi0, gv0 = acc[mf][2][reg] + bg0, ov0 = acc[mf][4][reg] + bo0;
        float cc0 = sigm(iv0) * tanhf(gv0);
        out[(size_t)row * 128 + j0] = sigm(ov0) * tanhf(cc0);
        float iv1 = acc[mf][1][reg] + bi1, gv1 = acc[mf][3][reg] + bg1, ov1 = acc[mf][5][reg] + bo1;
        float cc1 = sigm(iv1) * tanhf(gv1);
        out[(size_t)row * 128 + j1] = sigm(ov1) * tanhf(cc1);
      }
    }
}

extern "C" void kernel_launch(void* const* d_in, const int* in_sizes, int n_in,
                              void* d_out, int out_size, void* d_ws, size_t ws_size,
                              hipStream_t stream) {
  const float* x = (const float*)d_in[0];
  const int* src = (const int*)d_in[1];
  const int* dst = (const int*)d_in[2];
  const float* W1 = (const float*)d_in[3];   // [3][128][128] = Wcat [384][128]
  const float* b1 = (const float*)d_in[4];
  const float* W2 = (const float*)d_in[5];
  const float* b2 = (const float*)d_in[6];
  const float* Wih_f = (const float*)d_in[7];
  const float* bih_f = (const float*)d_in[9];
  const float* bhh_f = (const float*)d_in[10];
  const float* Wih_b = (const float*)d_in[11];
  const float* bih_b = (const float*)d_in[13];
  const float* bhh_b = (const float*)d_in[14];
  float* out = (float*)d_out;

  // workspace carve-up (~110 MB)
  char* wp = (char*)d_ws;
  float* rs_out = (float*)wp;          wp += (size_t)3 * NN * 4;
  float* rs_in3 = (float*)wp;          wp += (size_t)3 * NN * 4;
  int* cnt_out = (int*)wp;             wp += (size_t)3 * NN * 4;
  int* cnt_in = (int*)wp;              wp += (size_t)3 * NN * 4;
  int* row_ptr = (int*)wp;             wp += (size_t)3 * NN * 4;
  int* cursor = (int*)wp;              wp += (size_t)3 * NN * 4;
  int* bsums = (int*)wp;               wp += 4096;
  int2* ses = (int2*)wp;               wp += (size_t)3 * NE * 8;
  ushort* wt1h = (ushort*)wp;          wp += (size_t)128 * 384 * 2;
  ushort* wt1l = (ushort*)wp;          wp += (size_t)128 * 384 * 2;
  ushort* wt2h = (ushort*)wp;          wp += (size_t)128 * 384 * 2;
  ushort* wt2l = (ushort*)wp;          wp += (size_t)128 * 384 * 2;
  ushort* wph = (ushort*)wp;           wp += (size_t)384 * 128 * 2;
  ushort* wpl = (ushort*)wp;           wp += (size_t)384 * 128 * 2;
  float* bbar1 = (float*)wp;           wp += 512;
  float* bbar2 = (float*)wp;           wp += 512;
  float* bselw = (float*)wp;           wp += 2048;
  ushort* z_h = (ushort*)wp;           wp += (size_t)CH * 384 * 2;
  ushort* z_l = (ushort*)wp;           wp += (size_t)CH * 384 * 2;
  ushort* x16 = (ushort*)wp;           wp += (size_t)NN * F * 2;
  ushort* h116 = (ushort*)wp;          wp += (size_t)NN * F * 2;

  // CSR + normalizers + weight prep
  hipMemsetAsync(cnt_out, 0, (size_t)6 * NN * sizeof(int), stream);
  count_deg<<<(NREL * NE + 255) / 256, 256, 0, stream>>>(src, dst, cnt_out, cnt_in);
  make_rs<<<(NREL * NN + 255) / 256, 256, 0, stream>>>(cnt_out, cnt_in, rs_out, rs_in3);
  scan1<<<NREL * NBLK, 256, 0, stream>>>(cnt_in, row_ptr, bsums);
  scan2<<<NREL, 128, 0, stream>>>(bsums);
  scan3<<<(NREL * NN + 255) / 256, 256, 0, stream>>>(row_ptr, bsums, cursor);
  place_edges<<<(NREL * NE + 255) / 256, 256, 0, stream>>>(src, dst, rs_out, cursor, ses);
  prep_small<<<1, 640, 0, stream>>>(b1, b2, bih_f, bhh_f, bih_b, bhh_b, bbar1, bbar2, bselw);
  wt_split<<<192, 256, 0, stream>>>(W1, wt1h, wt1l);
  wt_split<<<192, 256, 0, stream>>>(W2, wt2h, wt2l);
  pack_w_split<<<192, 256, 0, stream>>>(Wih_f, Wih_b, wph, wpl);
  cvt_f16<<<(NN * 32 + 255) / 256, 256, 0, stream>>>(x, x16);

  // layer 1: x16 -> h1 (relu, f16 table)
  for (int c = 0; c < NCH; ++c) {
    gather3<<<3 * CH / 4, 256, 0, stream>>>(x16, ses, row_ptr, cnt_in, rs_in3, z_h, z_l, c * CH);
    gemm_mfma<true, true><<<(CH + 63) / 64, 256, 0, stream>>>(z_h, z_l, wt1h, wt1l, bbar1, h116, c * CH);
  }
  // layer 2: h116 -> d_out (f32)
  for (int c = 0; c < NCH; ++c) {
    gather3<<<3 * CH / 4, 256, 0, stream>>>(h116, ses, row_ptr, cnt_in, rs_in3, z_h, z_l, c * CH);
    gemm_mfma<false, false><<<(CH + 63) / 64, 256, 0, stream>>>(z_h, z_l, wt2h, wt2l, bbar2, out, c * CH);
  }
  // BiLSTM step, in place on d_out (blocks read only their own rows)
  lstm_mfma<<<(NN + 127) / 128, 512, 0, stream>>>(out, wph, wpl, bselw, out);
}

// Round 6
// 655.419 us; speedup vs baseline: 2.1858x; 1.1778x over previous
//
#include <hip/hip_runtime.h>
#include <hip/hip_fp16.h>
#include <math.h>

#define NN 100000
#define NE 500000
#define NREL 3
#define F 128
#define SCAN_BLK 1024
#define NBLK ((NN + SCAN_BLK - 1) / SCAN_BLK)   // 98
#define CH 25000
#define NCH 4

typedef __attribute__((ext_vector_type(8))) short bf16x8;
typedef __attribute__((ext_vector_type(4))) float f32x4;

__device__ __forceinline__ float sigm(float x) { return 1.f / (1.f + __expf(-x)); }

__device__ __forceinline__ unsigned bf16rne(float x) {
  unsigned u = __float_as_uint(x);
  return (u + 0x7FFFu + ((u >> 16) & 1u)) >> 16;
}
__device__ __forceinline__ void split1(float x, unsigned& h, unsigned& l) {
  h = bf16rne(x);
  float hf = __uint_as_float(h << 16);
  l = bf16rne(x - hf);
}

// ---- degree counting; in-degree atomic RETURNS the edge's bucket ordinal ----
__global__ void count_deg(const int* __restrict__ src, const int* __restrict__ dst,
                          int* __restrict__ cnt_out, int* __restrict__ cnt_in,
                          int* __restrict__ ord) {
  int i = blockIdx.x * blockDim.x + threadIdx.x;
  if (i >= NREL * NE) return;
  int r = i / NE;
  atomicAdd(&cnt_out[r * NN + src[i]], 1);
  ord[i] = atomicAdd(&cnt_in[r * NN + dst[i]], 1);
}

__global__ void make_rs(const int* __restrict__ cnt_out, const int* __restrict__ cnt_in,
                        float* __restrict__ rs_out, float* __restrict__ rs_in3) {
  int i = blockIdx.x * blockDim.x + threadIdx.x;
  if (i >= NREL * NN) return;
  int c0 = cnt_out[i];
  rs_out[i] = rsqrtf((float)(c0 < 1 ? 1 : c0));
  int c1 = cnt_in[i];
  rs_in3[i] = rsqrtf((float)(c1 < 1 ? 1 : c1)) * (1.f / 3.f);
}

// ---- two-level exclusive scan of cnt_in -> row_ptr ----
__global__ __launch_bounds__(256) void scan1(const int* __restrict__ cnt,
                                             int* __restrict__ excl, int* __restrict__ bsums) {
  int rb = blockIdx.x;
  int r = rb / NBLK, blk = rb % NBLK;
  int tid = (int)threadIdx.x;
  int v[4]; int sum = 0;
#pragma unroll
  for (int i = 0; i < 4; ++i) {
    int idx = blk * SCAN_BLK + tid * 4 + i;
    int c = (idx < NN) ? cnt[r * NN + idx] : 0;
    v[i] = sum; sum += c;
  }
  __shared__ int ts[256];
  ts[tid] = sum;
  __syncthreads();
  for (int off = 1; off < 256; off <<= 1) {
    int t = (tid >= off) ? ts[tid - off] : 0;
    __syncthreads();
    ts[tid] += t;
    __syncthreads();
  }
  int texcl = tid ? ts[tid - 1] : 0;
#pragma unroll
  for (int i = 0; i < 4; ++i) {
    int idx = blk * SCAN_BLK + tid * 4 + i;
    if (idx < NN) excl[r * NN + idx] = texcl + v[i];
  }
  if (tid == 255) bsums[rb] = ts[255];
}

__global__ __launch_bounds__(128) void scan2(int* __restrict__ bsums) {
  int r = blockIdx.x;
  int tid = (int)threadIdx.x;
  __shared__ int ts[128];
  ts[tid] = (tid < NBLK) ? bsums[r * NBLK + tid] : 0;
  __syncthreads();
  for (int off = 1; off < 128; off <<= 1) {
    int t = (tid >= off) ? ts[tid - off] : 0;
    __syncthreads();
    ts[tid] += t;
    __syncthreads();
  }
  if (tid < NBLK) bsums[r * NBLK + tid] = tid ? ts[tid - 1] : 0;
}

__global__ void scan3(int* __restrict__ row_ptr, const int* __restrict__ bsums) {
  int i = blockIdx.x * blockDim.x + threadIdx.x;
  if (i >= NREL * NN) return;
  int r = i / NN, idx = i - r * NN, blk = idx / SCAN_BLK;
  row_ptr[i] += bsums[r * NBLK + blk];
}

// atomic-free edge placement: pos = row_ptr[dst] + ord
__global__ void place_edges(const int* __restrict__ src, const int* __restrict__ dst,
                            const float* __restrict__ rs_out,
                            const int* __restrict__ row_ptr, const int* __restrict__ ord,
                            int2* __restrict__ ses) {
  int i = blockIdx.x * blockDim.x + threadIdx.x;
  if (i >= NREL * NE) return;
  int r = i / NE;
  int s = src[i];
  int pos = row_ptr[r * NN + dst[i]] + ord[i];
  ses[(size_t)r * NE + pos] = make_int2(s, __float_as_int(rs_out[r * NN + s]));
}

// biases
__global__ void prep_small(const float* __restrict__ b1, const float* __restrict__ b2,
                           const float* __restrict__ bif, const float* __restrict__ bhf,
                           const float* __restrict__ bib, const float* __restrict__ bhb,
                           float* __restrict__ bbar1, float* __restrict__ bbar2,
                           float* __restrict__ bselw) {
  int t = (int)threadIdx.x;
  if (t < 128) {
    bbar1[t] = (b1[t] + b1[128 + t] + b1[256 + t]) * (1.f / 3.f);
  } else if (t < 256) {
    int j = t - 128;
    bbar2[j] = (b2[j] + b2[128 + j] + b2[256 + j]) * (1.f / 3.f);
  } else if (t < 640) {
    int m = t - 256;
    int g = m >> 7, j = m & 127, dir = j >> 6, jj = j & 63;
    int grow = (g == 0) ? jj : (g == 1) ? (128 + jj) : (192 + jj);
    bselw[m] = dir ? (bib[grow] + bhb[grow]) : (bif[grow] + bhf[grow]);
  }
}

// W[384][128] (k-major) -> split-bf16 transposed planes WT[n][k]
__global__ void wt_split(const float* __restrict__ W, ushort* __restrict__ th,
                         ushort* __restrict__ tl) {
  int i = blockIdx.x * blockDim.x + threadIdx.x;
  if (i >= 128 * 384) return;
  int n = i / 384, k = i % 384;
  float v = W[(size_t)k * 128 + n];
  unsigned h, l; split1(v, h, l);
  th[i] = (ushort)h; tl[i] = (ushort)l;
}

// lstm gate weights, packed+split: Wp[m][k], m = g*128 + dir*64 + jj
__global__ void pack_w_split(const float* __restrict__ Wf, const float* __restrict__ Wb,
                             ushort* __restrict__ ph, ushort* __restrict__ pl) {
  int i = blockIdx.x * blockDim.x + threadIdx.x;
  if (i >= 384 * 128) return;
  int m = i / 128, k = i % 128;
  int g = m >> 7, j = m & 127, dir = j >> 6, jj = j & 63;
  int grow = (g == 0) ? jj : (g == 1) ? (128 + jj) : (192 + jj);
  float v = (dir ? Wb : Wf)[(size_t)grow * 128 + k];
  unsigned h, l; split1(v, h, l);
  ph[i] = (ushort)h; pl[i] = (ushort)l;
}

// f32 [NN,128] -> f16 table
__global__ void cvt_f16(const float* __restrict__ in, ushort* __restrict__ o16) {
  int i = blockIdx.x * blockDim.x + threadIdx.x;
  if (i >= NN * (F / 4)) return;
  float4 v = ((const float4*)in)[i];
  __half2 a = __floats2half2_rn(v.x, v.y);
  __half2 b = __floats2half2_rn(v.z, v.w);
  ((uint2*)o16)[i] = make_uint2(*(unsigned*)&a, *(unsigned*)&b);
}

// batched gather: one wave per (node, relation). Per 16-edge batch: one
// coalesced ses load (lanes 0-15), shfl broadcast, up to 8 paired-row loads
// issued back-to-back (uniform guards), then FMA phase. One latency exposure
// per batch instead of per edge-pair.
__global__ __launch_bounds__(256) void gather3(
    const ushort* __restrict__ table, const int2* __restrict__ ses,
    const int* __restrict__ row_ptr, const int* __restrict__ cnt,
    const float* __restrict__ rs_in3, ushort* __restrict__ z_h,
    ushort* __restrict__ z_l, int n0) {
  int wid = (int)threadIdx.x >> 6, lane = (int)threadIdx.x & 63;
  int gw = blockIdx.x * 4 + wid;          // 0 .. 3*CH-1
  int r = gw / CH;
  int n = n0 + (gw - r * CH);
  int base = r * NN + n;
  int beg = row_ptr[base], c = cnt[base];
  const int2* el = ses + (size_t)r * NE + beg;
  int half = lane >> 5, cl = lane & 31;
  const uint2* x2 = (const uint2*)table + cl;   // row stride 32 uint2 (256 B)
  float4 acc = make_float4(0.f, 0.f, 0.f, 0.f);

  int p = 0;
  while (p < c) {
    int rem = c - p; if (rem > 16) rem = 16;
    int2 es = make_int2(0, 0);
    if (lane < rem) es = el[p + lane];
    uint2 rw[8]; float scv[8];
#pragma unroll
    for (int j = 0; j < 8; ++j) {
      int e = 2 * j + half;
      int idx = (e < rem) ? e : 0;
      int s = __shfl(es.x, idx);
      float sc = __int_as_float(__shfl(es.y, idx));
      if (e >= rem) sc = 0.f;
      if (2 * j < rem) {          // wave-uniform guard; loads issue back-to-back
        rw[j] = x2[(size_t)s * 32];
        scv[j] = sc;
      }
    }
#pragma unroll
    for (int j = 0; j < 8; ++j) {
      if (2 * j < rem) {
        float2 f0 = __half22float2(*(__half2*)&rw[j].x);
        float2 f1 = __half22float2(*(__half2*)&rw[j].y);
        float sc = scv[j];
        acc.x = fmaf(f0.x, sc, acc.x); acc.y = fmaf(f0.y, sc, acc.y);
        acc.z = fmaf(f1.x, sc, acc.z); acc.w = fmaf(f1.y, sc, acc.w);
      }
    }
    p += rem;
  }

  acc.x += __shfl_xor(acc.x, 32);
  acc.y += __shfl_xor(acc.y, 32);
  acc.z += __shfl_xor(acc.z, 32);
  acc.w += __shfl_xor(acc.w, 32);
  float ci = rs_in3[base];
  unsigned h[4], l[4];
  split1(acc.x * ci, h[0], l[0]); split1(acc.y * ci, h[1], l[1]);
  split1(acc.z * ci, h[2], l[2]); split1(acc.w * ci, h[3], l[3]);
  size_t zo = (size_t)(n - n0) * 384 + r * 128 + cl * 4;
  if (half == 0) {
    *(ushort2*)(z_h + zo) = make_ushort2((ushort)h[0], (ushort)h[1]);
    *(ushort2*)(z_h + zo + 2) = make_ushort2((ushort)h[2], (ushort)h[3]);
  } else {
    *(ushort2*)(z_l + zo) = make_ushort2((ushort)l[0], (ushort)l[1]);
    *(ushort2*)(z_l + zo + 2) = make_ushort2((ushort)l[2], (ushort)l[3]);
  }
}

// LDS swizzle: 16B slot index xor'd by row bits -> 2-way max on ds_read_b128
__device__ __forceinline__ int swz(int row, int slot) {
  return row * 32 + ((slot ^ ((row >> 1) & 3)) << 3);   // ushort index
}

// H = (relu?)(Z[row,0:384] @ WT^T + bias); OUT16 -> write f16 table, else f32.
template <bool RELU, bool OUT16>
__global__ __launch_bounds__(256) void gemm_mfma(
    const ushort* __restrict__ zh, const ushort* __restrict__ zl,
    const ushort* __restrict__ wth, const ushort* __restrict__ wtl,
    const float* __restrict__ bias, void* __restrict__ Hout, int n0) {
  __shared__ ushort Ash[64 * 32], Asl[64 * 32], Bsh[128 * 32], Bsl[128 * 32];
  const int row0 = blockIdx.x * 64;
  const int t = (int)threadIdx.x;
  const int wn = t >> 6, l = t & 63, lr = l & 15, lk = l >> 4;
  f32x4 acc[4][2];
#pragma unroll
  for (int a = 0; a < 4; ++a)
#pragma unroll
    for (int b = 0; b < 2; ++b) acc[a][b] = (f32x4){0.f, 0.f, 0.f, 0.f};

  for (int kt = 0; kt < 12; ++kt) {
    __syncthreads();
    {   // stage A planes: 64 rows x 32 k
      int rr = t >> 2, slot = t & 3;
      size_t go = (size_t)(row0 + rr) * 384 + kt * 32 + slot * 8;
      uint4 vh = make_uint4(0, 0, 0, 0), vl = make_uint4(0, 0, 0, 0);
      if (row0 + rr < CH) { vh = *(const uint4*)(zh + go); vl = *(const uint4*)(zl + go); }
      *(uint4*)&Ash[swz(rr, slot)] = vh;
      *(uint4*)&Asl[swz(rr, slot)] = vl;
    }
#pragma unroll
    for (int i = 0; i < 2; ++i) {   // stage B planes: 128 n x 32 k
      int s = i * 256 + t;
      int nn_ = s >> 2, slot = s & 3;
      size_t go = (size_t)nn_ * 384 + kt * 32 + slot * 8;
      *(uint4*)&Bsh[swz(nn_, slot)] = *(const uint4*)(wth + go);
      *(uint4*)&Bsl[swz(nn_, slot)] = *(const uint4*)(wtl + go);
    }
    __syncthreads();
    bf16x8 ah[4], al[4], bh[2], bl[2];
#pragma unroll
    for (int mf = 0; mf < 4; ++mf) {
      int row = mf * 16 + lr;
      int off = swz(row, lk);
      ah[mf] = *(const bf16x8*)&Ash[off];
      al[mf] = *(const bf16x8*)&Asl[off];
    }
#pragma unroll
    for (int f = 0; f < 2; ++f) {
      int col = wn * 32 + f * 16 + lr;
      int off = swz(col, lk);
      bh[f] = *(const bf16x8*)&Bsh[off];
      bl[f] = *(const bf16x8*)&Bsl[off];
    }
#pragma unroll
    for (int mf = 0; mf < 4; ++mf)
#pragma unroll
      for (int f = 0; f < 2; ++f) {
        acc[mf][f] = __builtin_amdgcn_mfma_f32_16x16x32_bf16(ah[mf], bh[f], acc[mf][f], 0, 0, 0);
        acc[mf][f] = __builtin_amdgcn_mfma_f32_16x16x32_bf16(ah[mf], bl[f], acc[mf][f], 0, 0, 0);
        acc[mf][f] = __builtin_amdgcn_mfma_f32_16x16x32_bf16(al[mf], bh[f], acc[mf][f], 0, 0, 0);
      }
  }
#pragma unroll
  for (int mf = 0; mf < 4; ++mf)
#pragma unroll
    for (int f = 0; f < 2; ++f) {
      int col = wn * 32 + f * 16 + lr;
      float bv = bias[col];
#pragma unroll
      for (int reg = 0; reg < 4; ++reg) {
        int row = row0 + mf * 16 + lk * 4 + reg;
        if (row < CH) {
          float v = acc[mf][f][reg] + bv;
          if (RELU) v = fmaxf(v, 0.f);
          if (OUT16) {
            __half hv = __float2half_rn(v);
            ((ushort*)Hout)[(size_t)(n0 + row) * 128 + col] = *(ushort*)&hv;
          } else {
            ((float*)Hout)[(size_t)(n0 + row) * 128 + col] = v;
          }
        }
      }
    }
}

// BiLSTM step: out = act(H[NN,128] @ Wp^T[128,384] + b), gates i,g,o in-register.
__global__ __launch_bounds__(512) void lstm_mfma(
    const float* __restrict__ H, const ushort* __restrict__ wph,
    const ushort* __restrict__ wpl, const float* __restrict__ bselw,
    float* __restrict__ out) {
  __shared__ ushort Ash[128 * 32], Asl[128 * 32], Bsh[384 * 32], Bsl[384 * 32]; // 64 KB
  const int row0 = blockIdx.x * 128;
  const int t = (int)threadIdx.x;
  const int wid = t >> 6, wm = wid >> 2, wn = wid & 3;
  const int l = t & 63, lr = l & 15, lk = l >> 4;

  int j0 = wn * 16 + lr, j1 = (wn + 4) * 16 + lr;
  float bi0 = bselw[j0], bg0 = bselw[128 + j0], bo0 = bselw[256 + j0];
  float bi1 = bselw[j1], bg1 = bselw[128 + j1], bo1 = bselw[256 + j1];

  f32x4 acc[4][6];
#pragma unroll
  for (int a = 0; a < 4; ++a)
#pragma unroll
    for (int b = 0; b < 6; ++b) acc[a][b] = (f32x4){0.f, 0.f, 0.f, 0.f};

  for (int kt = 0; kt < 4; ++kt) {
    __syncthreads();
    {   // stage A: 128 rows x 32 k, split f32 -> bf16 hi/lo
      int rr = t >> 2, slot = t & 3;
      int grow = row0 + rr;
      float v[8];
      if (grow < NN) {
        float4 a0 = *(const float4*)(H + (size_t)grow * 128 + kt * 32 + slot * 8);
        float4 a1 = *(const float4*)(H + (size_t)grow * 128 + kt * 32 + slot * 8 + 4);
        v[0] = a0.x; v[1] = a0.y; v[2] = a0.z; v[3] = a0.w;
        v[4] = a1.x; v[5] = a1.y; v[6] = a1.z; v[7] = a1.w;
      } else {
#pragma unroll
        for (int q = 0; q < 8; ++q) v[q] = 0.f;
      }
      unsigned h[8], lo[8];
#pragma unroll
      for (int q = 0; q < 8; ++q) split1(v[q], h[q], lo[q]);
      uint4 hv = make_uint4(h[0] | (h[1] << 16), h[2] | (h[3] << 16),
                            h[4] | (h[5] << 16), h[6] | (h[7] << 16));
      uint4 lv = make_uint4(lo[0] | (lo[1] << 16), lo[2] | (lo[3] << 16),
                            lo[4] | (lo[5] << 16), lo[6] | (lo[7] << 16));
      *(uint4*)&Ash[swz(rr, slot)] = hv;
      *(uint4*)&Asl[swz(rr, slot)] = lv;
    }
#pragma unroll
    for (int i = 0; i < 3; ++i) {   // stage B: 384 m x 32 k
      int s = i * 512 + t;
      int nn_ = s >> 2, slot = s & 3;
      size_t go = (size_t)nn_ * 128 + kt * 32 + slot * 8;
      *(uint4*)&Bsh[swz(nn_, slot)] = *(const uint4*)(wph + go);
      *(uint4*)&Bsl[swz(nn_, slot)] = *(const uint4*)(wpl + go);
    }
    __syncthreads();
    bf16x8 ah[4], al[4];
#pragma unroll
    for (int mf = 0; mf < 4; ++mf) {
      int row = wm * 64 + mf * 16 + lr;
      int off = swz(row, lk);
      ah[mf] = *(const bf16x8*)&Ash[off];
      al[mf] = *(const bf16x8*)&Asl[off];
    }
#pragma unroll
    for (int tt = 0; tt < 6; ++tt) {
      int col = (wn + 4 * tt) * 16 + lr;
      int off = swz(col, lk);
      bf16x8 bh = *(const bf16x8*)&Bsh[off];
      bf16x8 bl = *(const bf16x8*)&Bsl[off];
#pragma unroll
      for (int mf = 0; mf < 4; ++mf) {
        acc[mf][tt] = __builtin_amdgcn_mfma_f32_16x16x32_bf16(ah[mf], bh, acc[mf][tt], 0, 0, 0);
        acc[mf][tt] = __builtin_amdgcn_mfma_f32_16x16x32_bf16(ah[mf], bl, acc[mf][tt], 0, 0, 0);
        acc[mf][tt] = __builtin_amdgcn_mfma_f32_16x16x32_bf16(al[mf], bh, acc[mf][tt], 0, 0, 0);
      }
    }
  }
#pragma unroll
  for (int mf = 0; mf < 4; ++mf)
#pragma unroll
    for (int reg = 0; reg < 4; ++reg) {
      int row = row0 + wm * 64 + mf * 16 + lk * 4 + reg;
      if (row < NN) {
        float iv0 = acc[mf][0][reg] + bi0, gv0 = acc[mf][2][reg] + bg0, ov0 = acc[mf][4][reg] + bo0;
        float cc0 = sigm(iv0) * tanhf(gv0);
        out[(size_t)row * 128 + j0] = sigm(ov0) * tanhf(cc0);
        float iv1 = acc[mf][1][reg] + bi1, gv1 = acc[mf][3][reg] + bg1, ov1 = acc[mf][5][reg] + bo1;
        float cc1 = sigm(iv1) * tanhf(gv1);
        out[(size_t)row * 128 + j1] = sigm(ov1) * tanhf(cc1);
      }
    }
}

extern "C" void kernel_launch(void* const* d_in, const int* in_sizes, int n_in,
                              void* d_out, int out_size, void* d_ws, size_t ws_size,
                              hipStream_t stream) {
  const float* x = (const float*)d_in[0];
  const int* src = (const int*)d_in[1];
  const int* dst = (const int*)d_in[2];
  const float* W1 = (const float*)d_in[3];   // [3][128][128] = Wcat [384][128]
  const float* b1 = (const float*)d_in[4];
  const float* W2 = (const float*)d_in[5];
  const float* b2 = (const float*)d_in[6];
  const float* Wih_f = (const float*)d_in[7];
  const float* bih_f = (const float*)d_in[9];
  const float* bhh_f = (const float*)d_in[10];
  const float* Wih_b = (const float*)d_in[11];
  const float* bih_b = (const float*)d_in[13];
  const float* bhh_b = (const float*)d_in[14];
  float* out = (float*)d_out;

  // workspace carve-up (~114 MB)
  char* wp = (char*)d_ws;
  float* rs_out = (float*)wp;          wp += (size_t)3 * NN * 4;
  float* rs_in3 = (float*)wp;          wp += (size_t)3 * NN * 4;
  int* cnt_out = (int*)wp;             wp += (size_t)3 * NN * 4;
  int* cnt_in = (int*)wp;              wp += (size_t)3 * NN * 4;
  int* row_ptr = (int*)wp;             wp += (size_t)3 * NN * 4;
  int* bsums = (int*)wp;               wp += 4096;
  int* ord = (int*)wp;                 wp += (size_t)3 * NE * 4;
  int2* ses = (int2*)wp;               wp += (size_t)3 * NE * 8;
  ushort* wt1h = (ushort*)wp;          wp += (size_t)128 * 384 * 2;
  ushort* wt1l = (ushort*)wp;          wp += (size_t)128 * 384 * 2;
  ushort* wt2h = (ushort*)wp;          wp += (size_t)128 * 384 * 2;
  ushort* wt2l = (ushort*)wp;          wp += (size_t)128 * 384 * 2;
  ushort* wph = (ushort*)wp;           wp += (size_t)384 * 128 * 2;
  ushort* wpl = (ushort*)wp;           wp += (size_t)384 * 128 * 2;
  float* bbar1 = (float*)wp;           wp += 512;
  float* bbar2 = (float*)wp;           wp += 512;
  float* bselw = (float*)wp;           wp += 2048;
  ushort* z_h = (ushort*)wp;           wp += (size_t)CH * 384 * 2;
  ushort* z_l = (ushort*)wp;           wp += (size_t)CH * 384 * 2;
  ushort* x16 = (ushort*)wp;           wp += (size_t)NN * F * 2;
  ushort* h116 = (ushort*)wp;          wp += (size_t)NN * F * 2;

  // CSR + normalizers + weight prep
  hipMemsetAsync(cnt_out, 0, (size_t)6 * NN * sizeof(int), stream);
  count_deg<<<(NREL * NE + 255) / 256, 256, 0, stream>>>(src, dst, cnt_out, cnt_in, ord);
  make_rs<<<(NREL * NN + 255) / 256, 256, 0, stream>>>(cnt_out, cnt_in, rs_out, rs_in3);
  scan1<<<NREL * NBLK, 256, 0, stream>>>(cnt_in, row_ptr, bsums);
  scan2<<<NREL, 128, 0, stream>>>(bsums);
  scan3<<<(NREL * NN + 255) / 256, 256, 0, stream>>>(row_ptr, bsums);
  place_edges<<<(NREL * NE + 255) / 256, 256, 0, stream>>>(src, dst, rs_out, row_ptr, ord, ses);
  prep_small<<<1, 640, 0, stream>>>(b1, b2, bih_f, bhh_f, bih_b, bhh_b, bbar1, bbar2, bselw);
  wt_split<<<192, 256, 0, stream>>>(W1, wt1h, wt1l);
  wt_split<<<192, 256, 0, stream>>>(W2, wt2h, wt2l);
  pack_w_split<<<192, 256, 0, stream>>>(Wih_f, Wih_b, wph, wpl);
  cvt_f16<<<(NN * 32 + 255) / 256, 256, 0, stream>>>(x, x16);

  // layer 1: x16 -> h1 (relu, f16 table)
  for (int c = 0; c < NCH; ++c) {
    gather3<<<3 * CH / 4, 256, 0, stream>>>(x16, ses, row_ptr, cnt_in, rs_in3, z_h, z_l, c * CH);
    gemm_mfma<true, true><<<(CH + 63) / 64, 256, 0, stream>>>(z_h, z_l, wt1h, wt1l, bbar1, h116, c * CH);
  }
  // layer 2: h116 -> d_out (f32)
  for (int c = 0; c < NCH; ++c) {
    gather3<<<3 * CH / 4, 256, 0, stream>>>(h116, ses, row_ptr, cnt_in, rs_in3, z_h, z_l, c * CH);
    gemm_mfma<false, false><<<(CH + 63) / 64, 256, 0, stream>>>(z_h, z_l, wt2h, wt2l, bbar2, out, c * CH);
  }
  // BiLSTM step, in place on d_out (blocks read only their own rows)
  lstm_mfma<<<(NN + 127) / 128, 512, 0, stream>>>(out, wph, wpl, bselw, out);
}

// Round 7
// 649.783 us; speedup vs baseline: 2.2047x; 1.0087x over previous
//
#include <hip/hip_runtime.h>
#include <hip/hip_fp16.h>
#include <math.h>

#define NN 100000
#define NE 500000
#define NREL 3
#define F 128
#define SCAN_BLK 1024
#define NBLK ((NN + SCAN_BLK - 1) / SCAN_BLK)   // 98
#define CH 25000
#define NCH 4

// CSR build partitioning
#define RANGE 16384
#define NRANGE 7            // 7*16384 = 114688 >= NN
#define NPAD (NRANGE * RANGE)
#define EC 8                // edge chunks
#define EPC (NE / EC)       // 62500

typedef __attribute__((ext_vector_type(8))) short bf16x8;
typedef __attribute__((ext_vector_type(4))) float f32x4;

__device__ __forceinline__ float sigm(float x) { return 1.f / (1.f + __expf(-x)); }

__device__ __forceinline__ unsigned bf16rne(float x) {
  unsigned u = __float_as_uint(x);
  return (u + 0x7FFFu + ((u >> 16) & 1u)) >> 16;
}
__device__ __forceinline__ void split1(float x, unsigned& h, unsigned& l) {
  h = bf16rne(x);
  float hf = __uint_as_float(h << 16);
  l = bf16rne(x - hf);
}

// ---- atomic-free histogram: one block owns (array, rel, chunk, range) ----
__global__ __launch_bounds__(256) void hist_part(const int* __restrict__ src,
                                                 const int* __restrict__ dst,
                                                 int* __restrict__ part) {
  int b = blockIdx.x;
  int g = b % NRANGE; b /= NRANGE;
  int c = b % EC;     b /= EC;
  int r = b % NREL;   b /= NREL;
  int a = b;          // 0=src, 1=dst
  __shared__ int h[RANGE];
  for (int i = threadIdx.x; i < RANGE; i += 256) h[i] = 0;
  __syncthreads();
  const int* idx = (a ? dst : src) + (size_t)r * NE + (size_t)c * EPC;
  const int4* v4 = (const int4*)idx;
  int lo = g * RANGE;
  for (int i = threadIdx.x; i < EPC / 4; i += 256) {
    int4 v = v4[i];
    int t;
    t = v.x - lo; if ((unsigned)t < RANGE) atomicAdd(&h[t], 1);
    t = v.y - lo; if ((unsigned)t < RANGE) atomicAdd(&h[t], 1);
    t = v.z - lo; if ((unsigned)t < RANGE) atomicAdd(&h[t], 1);
    t = v.w - lo; if ((unsigned)t < RANGE) atomicAdd(&h[t], 1);
  }
  __syncthreads();
  int* op = part + (((size_t)a * NREL + r) * EC + c) * NPAD + (size_t)g * RANGE;
  for (int i = threadIdx.x; i < RANGE; i += 256) op[i] = h[i];
}

// cnt[a][r][node] = sum over chunks
__global__ void reduce_part(const int* __restrict__ part, int* __restrict__ cnt_out,
                            int* __restrict__ cnt_in) {
  int i = blockIdx.x * blockDim.x + threadIdx.x;
  if (i >= 2 * NREL * NN) return;
  int a = i / (NREL * NN);
  int rn = i - a * (NREL * NN);
  const int* p = part + ((size_t)a * NREL + rn / NN) * EC * NPAD + (rn % NN);
  int s = 0;
#pragma unroll
  for (int c = 0; c < EC; ++c) s += p[(size_t)c * NPAD];
  (a ? cnt_in : cnt_out)[rn] = s;
}

__global__ void make_rs(const int* __restrict__ cnt_out, const int* __restrict__ cnt_in,
                        float* __restrict__ rs_out, float* __restrict__ rs_in3) {
  int i = blockIdx.x * blockDim.x + threadIdx.x;
  if (i >= NREL * NN) return;
  int c0 = cnt_out[i];
  rs_out[i] = rsqrtf((float)(c0 < 1 ? 1 : c0));
  int c1 = cnt_in[i];
  rs_in3[i] = rsqrtf((float)(c1 < 1 ? 1 : c1)) * (1.f / 3.f);
}

// ---- two-level exclusive scan of cnt_in -> row_ptr ----
__global__ __launch_bounds__(256) void scan1(const int* __restrict__ cnt,
                                             int* __restrict__ excl, int* __restrict__ bsums) {
  int rb = blockIdx.x;
  int r = rb / NBLK, blk = rb % NBLK;
  int tid = (int)threadIdx.x;
  int v[4]; int sum = 0;
#pragma unroll
  for (int i = 0; i < 4; ++i) {
    int idx = blk * SCAN_BLK + tid * 4 + i;
    int c = (idx < NN) ? cnt[r * NN + idx] : 0;
    v[i] = sum; sum += c;
  }
  __shared__ int ts[256];
  ts[tid] = sum;
  __syncthreads();
  for (int off = 1; off < 256; off <<= 1) {
    int t = (tid >= off) ? ts[tid - off] : 0;
    __syncthreads();
    ts[tid] += t;
    __syncthreads();
  }
  int texcl = tid ? ts[tid - 1] : 0;
#pragma unroll
  for (int i = 0; i < 4; ++i) {
    int idx = blk * SCAN_BLK + tid * 4 + i;
    if (idx < NN) excl[r * NN + idx] = texcl + v[i];
  }
  if (tid == 255) bsums[rb] = ts[255];
}

__global__ __launch_bounds__(128) void scan2(int* __restrict__ bsums) {
  int r = blockIdx.x;
  int tid = (int)threadIdx.x;
  __shared__ int ts[128];
  ts[tid] = (tid < NBLK) ? bsums[r * NBLK + tid] : 0;
  __syncthreads();
  for (int off = 1; off < 128; off <<= 1) {
    int t = (tid >= off) ? ts[tid - off] : 0;
    __syncthreads();
    ts[tid] += t;
    __syncthreads();
  }
  if (tid < NBLK) bsums[r * NBLK + tid] = tid ? ts[tid - 1] : 0;
}

__global__ void scan3(int* __restrict__ row_ptr, const int* __restrict__ bsums) {
  int i = blockIdx.x * blockDim.x + threadIdx.x;
  if (i >= NREL * NN) return;
  int r = i / NN, idx = i - r * NN, blk = idx / SCAN_BLK;
  row_ptr[i] += bsums[r * NBLK + blk];
}

// per-(rel,node): exclusive scan of the EC chunk counts, starting at row_ptr
__global__ void chunk_prefix(int* __restrict__ part_dst, const int* __restrict__ row_ptr) {
  int i = blockIdx.x * blockDim.x + threadIdx.x;
  if (i >= NREL * NN) return;
  int r = i / NN, node = i - r * NN;
  int* p = part_dst + (size_t)r * EC * NPAD + node;
  int run = row_ptr[i];
#pragma unroll
  for (int c = 0; c < EC; ++c) {
    int t = p[(size_t)c * NPAD];
    p[(size_t)c * NPAD] = run;
    run += t;
  }
}

// atomic-free placement: one block owns (rel, chunk, range); LDS cursors
__global__ __launch_bounds__(256) void place_part(const int* __restrict__ src,
                                                  const int* __restrict__ dst,
                                                  const float* __restrict__ rs_out,
                                                  const int* __restrict__ part_dst,
                                                  int2* __restrict__ ses) {
  int b = blockIdx.x;
  int g = b % NRANGE; b /= NRANGE;
  int c = b % EC;     b /= EC;
  int r = b;
  __shared__ int cur[RANGE];
  const int* pc = part_dst + ((size_t)r * EC + c) * NPAD + (size_t)g * RANGE;
  for (int i = threadIdx.x; i < RANGE; i += 256) cur[i] = pc[i];
  __syncthreads();
  int lo = g * RANGE;
  const int4* s4 = (const int4*)(src + (size_t)r * NE + (size_t)c * EPC);
  const int4* d4 = (const int4*)(dst + (size_t)r * NE + (size_t)c * EPC);
  int2* sesr = ses + (size_t)r * NE;
  const float* rso = rs_out + r * NN;
  for (int i = threadIdx.x; i < EPC / 4; i += 256) {
    int4 dv = d4[i]; int4 sv = s4[i];
    int t;
    t = dv.x - lo; if ((unsigned)t < RANGE) { int pos = atomicAdd(&cur[t], 1); sesr[pos] = make_int2(sv.x, __float_as_int(rso[sv.x])); }
    t = dv.y - lo; if ((unsigned)t < RANGE) { int pos = atomicAdd(&cur[t], 1); sesr[pos] = make_int2(sv.y, __float_as_int(rso[sv.y])); }
    t = dv.z - lo; if ((unsigned)t < RANGE) { int pos = atomicAdd(&cur[t], 1); sesr[pos] = make_int2(sv.z, __float_as_int(rso[sv.z])); }
    t = dv.w - lo; if ((unsigned)t < RANGE) { int pos = atomicAdd(&cur[t], 1); sesr[pos] = make_int2(sv.w, __float_as_int(rso[sv.w])); }
  }
}

// biases
__global__ void prep_small(const float* __restrict__ b1, const float* __restrict__ b2,
                           const float* __restrict__ bif, const float* __restrict__ bhf,
                           const float* __restrict__ bib, const float* __restrict__ bhb,
                           float* __restrict__ bbar1, float* __restrict__ bbar2,
                           float* __restrict__ bselw) {
  int t = (int)threadIdx.x;
  if (t < 128) {
    bbar1[t] = (b1[t] + b1[128 + t] + b1[256 + t]) * (1.f / 3.f);
  } else if (t < 256) {
    int j = t - 128;
    bbar2[j] = (b2[j] + b2[128 + j] + b2[256 + j]) * (1.f / 3.f);
  } else if (t < 640) {
    int m = t - 256;
    int g = m >> 7, j = m & 127, dir = j >> 6, jj = j & 63;
    int grow = (g == 0) ? jj : (g == 1) ? (128 + jj) : (192 + jj);
    bselw[m] = dir ? (bib[grow] + bhb[grow]) : (bif[grow] + bhf[grow]);
  }
}

// W[384][128] (k-major) -> split-bf16 transposed planes WT[n][k]
__global__ void wt_split(const float* __restrict__ W, ushort* __restrict__ th,
                         ushort* __restrict__ tl) {
  int i = blockIdx.x * blockDim.x + threadIdx.x;
  if (i >= 128 * 384) return;
  int n = i / 384, k = i % 384;
  float v = W[(size_t)k * 128 + n];
  unsigned h, l; split1(v, h, l);
  th[i] = (ushort)h; tl[i] = (ushort)l;
}

// lstm gate weights, packed+split: Wp[m][k], m = g*128 + dir*64 + jj
__global__ void pack_w_split(const float* __restrict__ Wf, const float* __restrict__ Wb,
                             ushort* __restrict__ ph, ushort* __restrict__ pl) {
  int i = blockIdx.x * blockDim.x + threadIdx.x;
  if (i >= 384 * 128) return;
  int m = i / 128, k = i % 128;
  int g = m >> 7, j = m & 127, dir = j >> 6, jj = j & 63;
  int grow = (g == 0) ? jj : (g == 1) ? (128 + jj) : (192 + jj);
  float v = (dir ? Wb : Wf)[(size_t)grow * 128 + k];
  unsigned h, l; split1(v, h, l);
  ph[i] = (ushort)h; pl[i] = (ushort)l;
}

// f32 [NN,128] -> f16 table
__global__ void cvt_f16(const float* __restrict__ in, ushort* __restrict__ o16) {
  int i = blockIdx.x * blockDim.x + threadIdx.x;
  if (i >= NN * (F / 4)) return;
  float4 v = ((const float4*)in)[i];
  __half2 a = __floats2half2_rn(v.x, v.y);
  __half2 b = __floats2half2_rn(v.z, v.w);
  ((uint2*)o16)[i] = make_uint2(*(unsigned*)&a, *(unsigned*)&b);
}

// batched gather: one wave per (node, relation); 16-edge batches.
__global__ __launch_bounds__(256) void gather3(
    const ushort* __restrict__ table, const int2* __restrict__ ses,
    const int* __restrict__ row_ptr, const int* __restrict__ cnt,
    const float* __restrict__ rs_in3, ushort* __restrict__ z_h,
    ushort* __restrict__ z_l, int n0) {
  int wid = (int)threadIdx.x >> 6, lane = (int)threadIdx.x & 63;
  int gw = blockIdx.x * 4 + wid;          // 0 .. 3*CH-1
  int r = gw / CH;
  int n = n0 + (gw - r * CH);
  int base = r * NN + n;
  int beg = row_ptr[base], c = cnt[base];
  const int2* el = ses + (size_t)r * NE + beg;
  int half = lane >> 5, cl = lane & 31;
  const uint2* x2 = (const uint2*)table + cl;   // row stride 32 uint2 (256 B)
  float4 acc = make_float4(0.f, 0.f, 0.f, 0.f);

  int p = 0;
  while (p < c) {
    int rem = c - p; if (rem > 16) rem = 16;
    int2 es = make_int2(0, 0);
    if (lane < rem) es = el[p + lane];
    uint2 rw[8]; float scv[8];
#pragma unroll
    for (int j = 0; j < 8; ++j) {
      int e = 2 * j + half;
      int idx = (e < rem) ? e : 0;
      int s = __shfl(es.x, idx);
      float sc = __int_as_float(__shfl(es.y, idx));
      if (e >= rem) sc = 0.f;
      if (2 * j < rem) {
        rw[j] = x2[(size_t)s * 32];
        scv[j] = sc;
      }
    }
#pragma unroll
    for (int j = 0; j < 8; ++j) {
      if (2 * j < rem) {
        float2 f0 = __half22float2(*(__half2*)&rw[j].x);
        float2 f1 = __half22float2(*(__half2*)&rw[j].y);
        float sc = scv[j];
        acc.x = fmaf(f0.x, sc, acc.x); acc.y = fmaf(f0.y, sc, acc.y);
        acc.z = fmaf(f1.x, sc, acc.z); acc.w = fmaf(f1.y, sc, acc.w);
      }
    }
    p += rem;
  }

  acc.x += __shfl_xor(acc.x, 32);
  acc.y += __shfl_xor(acc.y, 32);
  acc.z += __shfl_xor(acc.z, 32);
  acc.w += __shfl_xor(acc.w, 32);
  float ci = rs_in3[base];
  unsigned h[4], l[4];
  split1(acc.x * ci, h[0], l[0]); split1(acc.y * ci, h[1], l[1]);
  split1(acc.z * ci, h[2], l[2]); split1(acc.w * ci, h[3], l[3]);
  size_t zo = (size_t)(n - n0) * 384 + r * 128 + cl * 4;
  if (half == 0) {
    *(ushort2*)(z_h + zo) = make_ushort2((ushort)h[0], (ushort)h[1]);
    *(ushort2*)(z_h + zo + 2) = make_ushort2((ushort)h[2], (ushort)h[3]);
  } else {
    *(ushort2*)(z_l + zo) = make_ushort2((ushort)l[0], (ushort)l[1]);
    *(ushort2*)(z_l + zo + 2) = make_ushort2((ushort)l[2], (ushort)l[3]);
  }
}

// LDS swizzle: 16B slot index xor'd by row bits -> 2-way max on ds_read_b128
__device__ __forceinline__ int swz(int row, int slot) {
  return row * 32 + ((slot ^ ((row >> 1) & 3)) << 3);   // ushort index
}

// H = (relu?)(Z[row,0:384] @ WT^T + bias); OUT16 -> write f16 table, else f32.
template <bool RELU, bool OUT16>
__global__ __launch_bounds__(256) void gemm_mfma(
    const ushort* __restrict__ zh, const ushort* __restrict__ zl,
    const ushort* __restrict__ wth, const ushort* __restrict__ wtl,
    const float* __restrict__ bias, void* __restrict__ Hout, int n0) {
  __shared__ ushort Ash[64 * 32], Asl[64 * 32], Bsh[128 * 32], Bsl[128 * 32];
  const int row0 = blockIdx.x * 64;
  const int t = (int)threadIdx.x;
  const int wn = t >> 6, l = t & 63, lr = l & 15, lk = l >> 4;
  f32x4 acc[4][2];
#pragma unroll
  for (int a = 0; a < 4; ++a)
#pragma unroll
    for (int b = 0; b < 2; ++b) acc[a][b] = (f32x4){0.f, 0.f, 0.f, 0.f};

  for (int kt = 0; kt < 12; ++kt) {
    __syncthreads();
    {
      int rr = t >> 2, slot = t & 3;
      size_t go = (size_t)(row0 + rr) * 384 + kt * 32 + slot * 8;
      uint4 vh = make_uint4(0, 0, 0, 0), vl = make_uint4(0, 0, 0, 0);
      if (row0 + rr < CH) { vh = *(const uint4*)(zh + go); vl = *(const uint4*)(zl + go); }
      *(uint4*)&Ash[swz(rr, slot)] = vh;
      *(uint4*)&Asl[swz(rr, slot)] = vl;
    }
#pragma unroll
    for (int i = 0; i < 2; ++i) {
      int s = i * 256 + t;
      int nn_ = s >> 2, slot = s & 3;
      size_t go = (size_t)nn_ * 384 + kt * 32 + slot * 8;
      *(uint4*)&Bsh[swz(nn_, slot)] = *(const uint4*)(wth + go);
      *(uint4*)&Bsl[swz(nn_, slot)] = *(const uint4*)(wtl + go);
    }
    __syncthreads();
    bf16x8 ah[4], al[4], bh[2], bl[2];
#pragma unroll
    for (int mf = 0; mf < 4; ++mf) {
      int row = mf * 16 + lr;
      int off = swz(row, lk);
      ah[mf] = *(const bf16x8*)&Ash[off];
      al[mf] = *(const bf16x8*)&Asl[off];
    }
#pragma unroll
    for (int f = 0; f < 2; ++f) {
      int col = wn * 32 + f * 16 + lr;
      int off = swz(col, lk);
      bh[f] = *(const bf16x8*)&Bsh[off];
      bl[f] = *(const bf16x8*)&Bsl[off];
    }
#pragma unroll
    for (int mf = 0; mf < 4; ++mf)
#pragma unroll
      for (int f = 0; f < 2; ++f) {
        acc[mf][f] = __builtin_amdgcn_mfma_f32_16x16x32_bf16(ah[mf], bh[f], acc[mf][f], 0, 0, 0);
        acc[mf][f] = __builtin_amdgcn_mfma_f32_16x16x32_bf16(ah[mf], bl[f], acc[mf][f], 0, 0, 0);
        acc[mf][f] = __builtin_amdgcn_mfma_f32_16x16x32_bf16(al[mf], bh[f], acc[mf][f], 0, 0, 0);
      }
  }
#pragma unroll
  for (int mf = 0; mf < 4; ++mf)
#pragma unroll
    for (int f = 0; f < 2; ++f) {
      int col = wn * 32 + f * 16 + lr;
      float bv = bias[col];
#pragma unroll
      for (int reg = 0; reg < 4; ++reg) {
        int row = row0 + mf * 16 + lk * 4 + reg;
        if (row < CH) {
          float v = acc[mf][f][reg] + bv;
          if (RELU) v = fmaxf(v, 0.f);
          if (OUT16) {
            __half hv = __float2half_rn(v);
            ((ushort*)Hout)[(size_t)(n0 + row) * 128 + col] = *(ushort*)&hv;
          } else {
            ((float*)Hout)[(size_t)(n0 + row) * 128 + col] = v;
          }
        }
      }
    }
}

// BiLSTM step: out = act(H[NN,128] @ Wp^T[128,384] + b), gates i,g,o in-register.
__global__ __launch_bounds__(512) void lstm_mfma(
    const float* __restrict__ H, const ushort* __restrict__ wph,
    const ushort* __restrict__ wpl, const float* __restrict__ bselw,
    float* __restrict__ out) {
  __shared__ ushort Ash[128 * 32], Asl[128 * 32], Bsh[384 * 32], Bsl[384 * 32]; // 64 KB
  const int row0 = blockIdx.x * 128;
  const int t = (int)threadIdx.x;
  const int wid = t >> 6, wm = wid >> 2, wn = wid & 3;
  const int l = t & 63, lr = l & 15, lk = l >> 4;

  int j0 = wn * 16 + lr, j1 = (wn + 4) * 16 + lr;
  float bi0 = bselw[j0], bg0 = bselw[128 + j0], bo0 = bselw[256 + j0];
  float bi1 = bselw[j1], bg1 = bselw[128 + j1], bo1 = bselw[256 + j1];

  f32x4 acc[4][6];
#pragma unroll
  for (int a = 0; a < 4; ++a)
#pragma unroll
    for (int b = 0; b < 6; ++b) acc[a][b] = (f32x4){0.f, 0.f, 0.f, 0.f};

  for (int kt = 0; kt < 4; ++kt) {
    __syncthreads();
    {
      int rr = t >> 2, slot = t & 3;
      int grow = row0 + rr;
      float v[8];
      if (grow < NN) {
        float4 a0 = *(const float4*)(H + (size_t)grow * 128 + kt * 32 + slot * 8);
        float4 a1 = *(const float4*)(H + (size_t)grow * 128 + kt * 32 + slot * 8 + 4);
        v[0] = a0.x; v[1] = a0.y; v[2] = a0.z; v[3] = a0.w;
        v[4] = a1.x; v[5] = a1.y; v[6] = a1.z; v[7] = a1.w;
      } else {
#pragma unroll
        for (int q = 0; q < 8; ++q) v[q] = 0.f;
      }
      unsigned h[8], lo[8];
#pragma unroll
      for (int q = 0; q < 8; ++q) split1(v[q], h[q], lo[q]);
      uint4 hv = make_uint4(h[0] | (h[1] << 16), h[2] | (h[3] << 16),
                            h[4] | (h[5] << 16), h[6] | (h[7] << 16));
      uint4 lv = make_uint4(lo[0] | (lo[1] << 16), lo[2] | (lo[3] << 16),
                            lo[4] | (lo[5] << 16), lo[6] | (lo[7] << 16));
      *(uint4*)&Ash[swz(rr, slot)] = hv;
      *(uint4*)&Asl[swz(rr, slot)] = lv;
    }
#pragma unroll
    for (int i = 0; i < 3; ++i) {
      int s = i * 512 + t;
      int nn_ = s >> 2, slot = s & 3;
      size_t go = (size_t)nn_ * 128 + kt * 32 + slot * 8;
      *(uint4*)&Bsh[swz(nn_, slot)] = *(const uint4*)(wph + go);
      *(uint4*)&Bsl[swz(nn_, slot)] = *(const uint4*)(wpl + go);
    }
    __syncthreads();
    bf16x8 ah[4], al[4];
#pragma unroll
    for (int mf = 0; mf < 4; ++mf) {
      int row = wm * 64 + mf * 16 + lr;
      int off = swz(row, lk);
      ah[mf] = *(const bf16x8*)&Ash[off];
      al[mf] = *(const bf16x8*)&Asl[off];
    }
#pragma unroll
    for (int tt = 0; tt < 6; ++tt) {
      int col = (wn + 4 * tt) * 16 + lr;
      int off = swz(col, lk);
      bf16x8 bh = *(const bf16x8*)&Bsh[off];
      bf16x8 bl = *(const bf16x8*)&Bsl[off];
#pragma unroll
      for (int mf = 0; mf < 4; ++mf) {
        acc[mf][tt] = __builtin_amdgcn_mfma_f32_16x16x32_bf16(ah[mf], bh, acc[mf][tt], 0, 0, 0);
        acc[mf][tt] = __builtin_amdgcn_mfma_f32_16x16x32_bf16(ah[mf], bl, acc[mf][tt], 0, 0, 0);
        acc[mf][tt] = __builtin_amdgcn_mfma_f32_16x16x32_bf16(al[mf], bh, acc[mf][tt], 0, 0, 0);
      }
    }
  }
#pragma unroll
  for (int mf = 0; mf < 4; ++mf)
#pragma unroll
    for (int reg = 0; reg < 4; ++reg) {
      int row = row0 + wm * 64 + mf * 16 + lk * 4 + reg;
      if (row < NN) {
        float iv0 = acc[mf][0][reg] + bi0, gv0 = acc[mf][2][reg] + bg0, ov0 = acc[mf][4][reg] + bo0;
        float cc0 = sigm(iv0) * tanhf(gv0);
        out[(size_t)row * 128 + j0] = sigm(ov0) * tanhf(cc0);
        float iv1 = acc[mf][1][reg] + bi1, gv1 = acc[mf][3][reg] + bg1, ov1 = acc[mf][5][reg] + bo1;
        float cc1 = sigm(iv1) * tanhf(gv1);
        out[(size_t)row * 128 + j1] = sigm(ov1) * tanhf(cc1);
      }
    }
}

extern "C" void kernel_launch(void* const* d_in, const int* in_sizes, int n_in,
                              void* d_out, int out_size, void* d_ws, size_t ws_size,
                              hipStream_t stream) {
  const float* x = (const float*)d_in[0];
  const int* src = (const int*)d_in[1];
  const int* dst = (const int*)d_in[2];
  const float* W1 = (const float*)d_in[3];   // [3][128][128] = Wcat [384][128]
  const float* b1 = (const float*)d_in[4];
  const float* W2 = (const float*)d_in[5];
  const float* b2 = (const float*)d_in[6];
  const float* Wih_f = (const float*)d_in[7];
  const float* bih_f = (const float*)d_in[9];
  const float* bhh_f = (const float*)d_in[10];
  const float* Wih_b = (const float*)d_in[11];
  const float* bih_b = (const float*)d_in[13];
  const float* bhh_b = (const float*)d_in[14];
  float* out = (float*)d_out;

  // workspace carve-up (~110 MB)
  char* wp = (char*)d_ws;
  float* rs_out = (float*)wp;          wp += (size_t)3 * NN * 4;
  float* rs_in3 = (float*)wp;          wp += (size_t)3 * NN * 4;
  int* cnt_out = (int*)wp;             wp += (size_t)3 * NN * 4;
  int* cnt_in = (int*)wp;              wp += (size_t)3 * NN * 4;
  int* row_ptr = (int*)wp;             wp += (size_t)3 * NN * 4;
  int* bsums = (int*)wp;               wp += 4096;
  int2* ses = (int2*)wp;               wp += (size_t)3 * NE * 8;
  ushort* wt1h = (ushort*)wp;          wp += (size_t)128 * 384 * 2;
  ushort* wt1l = (ushort*)wp;          wp += (size_t)128 * 384 * 2;
  ushort* wt2h = (ushort*)wp;          wp += (size_t)128 * 384 * 2;
  ushort* wt2l = (ushort*)wp;          wp += (size_t)128 * 384 * 2;
  ushort* wph = (ushort*)wp;           wp += (size_t)384 * 128 * 2;
  ushort* wpl = (ushort*)wp;           wp += (size_t)384 * 128 * 2;
  float* bbar1 = (float*)wp;           wp += 512;
  float* bbar2 = (float*)wp;           wp += 512;
  float* bselw = (float*)wp;           wp += 2048;
  ushort* z_h = (ushort*)wp;           wp += (size_t)CH * 384 * 2;
  ushort* z_l = (ushort*)wp;           wp += (size_t)CH * 384 * 2;
  ushort* x16 = (ushort*)wp;           wp += (size_t)NN * F * 2;
  ushort* h116 = (ushort*)wp;          wp += (size_t)NN * F * 2;

  // partial histograms alias the z region (dead until first gather):
  // part[2][NREL][EC][NPAD] = 22 MB <= 38.4 MB of z_h+z_l
  int* part = (int*)z_h;
  int* part_dst = part + (size_t)NREL * EC * NPAD;   // a=1 slice

  // CSR build — zero global atomics
  hist_part<<<2 * NREL * EC * NRANGE, 256, 0, stream>>>(src, dst, part);
  reduce_part<<<(2 * NREL * NN + 255) / 256, 256, 0, stream>>>(part, cnt_out, cnt_in);
  make_rs<<<(NREL * NN + 255) / 256, 256, 0, stream>>>(cnt_out, cnt_in, rs_out, rs_in3);
  scan1<<<NREL * NBLK, 256, 0, stream>>>(cnt_in, row_ptr, bsums);
  scan2<<<NREL, 128, 0, stream>>>(bsums);
  scan3<<<(NREL * NN + 255) / 256, 256, 0, stream>>>(row_ptr, bsums);
  chunk_prefix<<<(NREL * NN + 255) / 256, 256, 0, stream>>>(part_dst, row_ptr);
  place_part<<<NREL * EC * NRANGE, 256, 0, stream>>>(src, dst, rs_out, part_dst, ses);

  // weight prep
  prep_small<<<1, 640, 0, stream>>>(b1, b2, bih_f, bhh_f, bih_b, bhh_b, bbar1, bbar2, bselw);
  wt_split<<<192, 256, 0, stream>>>(W1, wt1h, wt1l);
  wt_split<<<192, 256, 0, stream>>>(W2, wt2h, wt2l);
  pack_w_split<<<192, 256, 0, stream>>>(Wih_f, Wih_b, wph, wpl);
  cvt_f16<<<(NN * 32 + 255) / 256, 256, 0, stream>>>(x, x16);

  // layer 1: x16 -> h1 (relu, f16 table)
  for (int c = 0; c < NCH; ++c) {
    gather3<<<3 * CH / 4, 256, 0, stream>>>(x16, ses, row_ptr, cnt_in, rs_in3, z_h, z_l, c * CH);
    gemm_mfma<true, true><<<(CH + 63) / 64, 256, 0, stream>>>(z_h, z_l, wt1h, wt1l, bbar1, h116, c * CH);
  }
  // layer 2: h116 -> d_out (f32)
  for (int c = 0; c < NCH; ++c) {
    gather3<<<3 * CH / 4, 256, 0, stream>>>(h116, ses, row_ptr, cnt_in, rs_in3, z_h, z_l, c * CH);
    gemm_mfma<false, false><<<(CH + 63) / 64, 256, 0, stream>>>(z_h, z_l, wt2h, wt2l, bbar2, out, c * CH);
  }
  // BiLSTM step, in place on d_out (blocks read only their own rows)
  lstm_mfma<<<(NN + 127) / 128, 512, 0, stream>>>(out, wph, wpl, bselw, out);
}

// Round 8
// 570.283 us; speedup vs baseline: 2.5121x; 1.1394x over previous
//
#include <hip/hip_runtime.h>
#include <hip/hip_fp16.h>
#include <math.h>

#define NN 100000
#define NE 500000
#define NREL 3
#define F 128
#define SCAN_BLK 1024
#define NBLK ((NN + SCAN_BLK - 1) / SCAN_BLK)   // 98
#define CH 25000
#define NCH 4

// CSR build partitioning
#define RANGE 16384
#define NRANGE 7            // 7*16384 = 114688 >= NN
#define NPAD (NRANGE * RANGE)
#define EC 20               // edge chunks (EPC divisible by 4)
#define EPC (NE / EC)       // 25000

typedef __attribute__((ext_vector_type(8))) short bf16x8;
typedef __attribute__((ext_vector_type(4))) float f32x4;

__device__ __forceinline__ float sigm(float x) { return 1.f / (1.f + __expf(-x)); }

__device__ __forceinline__ unsigned bf16rne(float x) {
  unsigned u = __float_as_uint(x);
  return (u + 0x7FFFu + ((u >> 16) & 1u)) >> 16;
}
__device__ __forceinline__ void split1(float x, unsigned& h, unsigned& l) {
  h = bf16rne(x);
  float hf = __uint_as_float(h << 16);
  l = bf16rne(x - hf);
}

// ---- atomic-free histogram: one block owns (array, rel, chunk, range).
// XCD-grouped decode: all NRANGE blocks of one (a,r,c) share blockIdx%8
// -> same XCD -> chunk reads L2-hit on 6/7 passes.
__global__ __launch_bounds__(256) void hist_part(const int* __restrict__ src,
                                                 const int* __restrict__ dst,
                                                 int* __restrict__ part) {
  int x = blockIdx.x & 7, q = blockIdx.x >> 3;
  int g = q % NRANGE;
  int rc2 = x + 8 * (q / NRANGE);     // [0, 2*NREL*EC) exactly
  int a = rc2 / (NREL * EC);
  int rcl = rc2 % (NREL * EC);
  int r = rcl / EC, c = rcl % EC;
  __shared__ int h[RANGE];
  for (int i = threadIdx.x; i < RANGE; i += 256) h[i] = 0;
  __syncthreads();
  const int* idx = (a ? dst : src) + (size_t)r * NE + (size_t)c * EPC;
  const int4* v4 = (const int4*)idx;
  int lo = g * RANGE;
  for (int i = threadIdx.x; i < EPC / 4; i += 256) {
    int4 v = v4[i];
    int t;
    t = v.x - lo; if ((unsigned)t < RANGE) atomicAdd(&h[t], 1);
    t = v.y - lo; if ((unsigned)t < RANGE) atomicAdd(&h[t], 1);
    t = v.z - lo; if ((unsigned)t < RANGE) atomicAdd(&h[t], 1);
    t = v.w - lo; if ((unsigned)t < RANGE) atomicAdd(&h[t], 1);
  }
  __syncthreads();
  int* op = part + (((size_t)a * NREL + r) * EC + c) * NPAD + (size_t)g * RANGE;
  for (int i = threadIdx.x; i < RANGE; i += 256) op[i] = h[i];
}

// cnt[a][r][node] = sum over chunks
__global__ void reduce_part(const int* __restrict__ part, int* __restrict__ cnt_out,
                            int* __restrict__ cnt_in) {
  int i = blockIdx.x * blockDim.x + threadIdx.x;
  if (i >= 2 * NREL * NN) return;
  int a = i / (NREL * NN);
  int rn = i - a * (NREL * NN);
  const int* p = part + ((size_t)a * NREL + rn / NN) * EC * NPAD + (rn % NN);
  int s = 0;
#pragma unroll
  for (int c = 0; c < EC; ++c) s += p[(size_t)c * NPAD];
  (a ? cnt_in : cnt_out)[rn] = s;
}

__global__ void make_rs(const int* __restrict__ cnt_out, const int* __restrict__ cnt_in,
                        float* __restrict__ rs_out, float* __restrict__ rs_in3) {
  int i = blockIdx.x * blockDim.x + threadIdx.x;
  if (i >= NREL * NN) return;
  int c0 = cnt_out[i];
  rs_out[i] = rsqrtf((float)(c0 < 1 ? 1 : c0));
  int c1 = cnt_in[i];
  rs_in3[i] = rsqrtf((float)(c1 < 1 ? 1 : c1)) * (1.f / 3.f);
}

// ---- two-level exclusive scan of cnt_in -> row_ptr ----
__global__ __launch_bounds__(256) void scan1(const int* __restrict__ cnt,
                                             int* __restrict__ excl, int* __restrict__ bsums) {
  int rb = blockIdx.x;
  int r = rb / NBLK, blk = rb % NBLK;
  int tid = (int)threadIdx.x;
  int v[4]; int sum = 0;
#pragma unroll
  for (int i = 0; i < 4; ++i) {
    int idx = blk * SCAN_BLK + tid * 4 + i;
    int c = (idx < NN) ? cnt[r * NN + idx] : 0;
    v[i] = sum; sum += c;
  }
  __shared__ int ts[256];
  ts[tid] = sum;
  __syncthreads();
  for (int off = 1; off < 256; off <<= 1) {
    int t = (tid >= off) ? ts[tid - off] : 0;
    __syncthreads();
    ts[tid] += t;
    __syncthreads();
  }
  int texcl = tid ? ts[tid - 1] : 0;
#pragma unroll
  for (int i = 0; i < 4; ++i) {
    int idx = blk * SCAN_BLK + tid * 4 + i;
    if (idx < NN) excl[r * NN + idx] = texcl + v[i];
  }
  if (tid == 255) bsums[rb] = ts[255];
}

__global__ __launch_bounds__(128) void scan2(int* __restrict__ bsums) {
  int r = blockIdx.x;
  int tid = (int)threadIdx.x;
  __shared__ int ts[128];
  ts[tid] = (tid < NBLK) ? bsums[r * NBLK + tid] : 0;
  __syncthreads();
  for (int off = 1; off < 128; off <<= 1) {
    int t = (tid >= off) ? ts[tid - off] : 0;
    __syncthreads();
    ts[tid] += t;
    __syncthreads();
  }
  if (tid < NBLK) bsums[r * NBLK + tid] = tid ? ts[tid - 1] : 0;
}

__global__ void scan3(int* __restrict__ row_ptr, const int* __restrict__ bsums) {
  int i = blockIdx.x * blockDim.x + threadIdx.x;
  if (i >= NREL * NN) return;
  int r = i / NN, idx = i - r * NN, blk = idx / SCAN_BLK;
  row_ptr[i] += bsums[r * NBLK + blk];
}

// per-(rel,node): exclusive scan of the EC chunk counts, starting at row_ptr
__global__ void chunk_prefix(int* __restrict__ part_dst, const int* __restrict__ row_ptr) {
  int i = blockIdx.x * blockDim.x + threadIdx.x;
  if (i >= NREL * NN) return;
  int r = i / NN, node = i - r * NN;
  int* p = part_dst + (size_t)r * EC * NPAD + node;
  int run = row_ptr[i];
#pragma unroll
  for (int c = 0; c < EC; ++c) {
    int t = p[(size_t)c * NPAD];
    p[(size_t)c * NPAD] = run;
    run += t;
  }
}

// streaming edge payload: pay[i] = (src, rs_out[src] bits) — absorbs the
// random rs read with full-grid latency hiding.
__global__ void make_pay(const int* __restrict__ src, const float* __restrict__ rs_out,
                         int2* __restrict__ pay) {
  int i = blockIdx.x * blockDim.x + threadIdx.x;
  if (i >= NREL * NE) return;
  int r = i / NE;
  int s = src[i];
  pay[i] = make_int2(s, __float_as_int(rs_out[r * NN + s]));
}

// atomic-free placement: one block owns (rel, chunk, range); LDS cursors.
// XCD-grouped decode as in hist_part; streams dst + pay only.
__global__ __launch_bounds__(256) void place_part(const int* __restrict__ dst,
                                                  const int2* __restrict__ pay,
                                                  const int* __restrict__ part_dst,
                                                  int2* __restrict__ ses) {
  int x = blockIdx.x & 7, q = blockIdx.x >> 3;
  int g = q % NRANGE;
  int rc = x + 8 * (q / NRANGE);
  if (rc >= NREL * EC) return;            // grid padded to multiple of 8
  int r = rc / EC, c = rc % EC;
  __shared__ int cur[RANGE];
  const int* pc = part_dst + ((size_t)r * EC + c) * NPAD + (size_t)g * RANGE;
  for (int i = threadIdx.x; i < RANGE; i += 256) cur[i] = pc[i];
  __syncthreads();
  int lo = g * RANGE;
  const int4* d4 = (const int4*)(dst + (size_t)r * NE + (size_t)c * EPC);
  const int4* p4 = (const int4*)(pay + (size_t)r * NE + (size_t)c * EPC);
  int2* sesr = ses + (size_t)r * NE;
  for (int i = threadIdx.x; i < EPC / 4; i += 256) {
    int4 dv = d4[i];
    int4 pa = p4[2 * i], pb = p4[2 * i + 1];
    int t;
    t = dv.x - lo; if ((unsigned)t < RANGE) { int pos = atomicAdd(&cur[t], 1); sesr[pos] = make_int2(pa.x, pa.y); }
    t = dv.y - lo; if ((unsigned)t < RANGE) { int pos = atomicAdd(&cur[t], 1); sesr[pos] = make_int2(pa.z, pa.w); }
    t = dv.z - lo; if ((unsigned)t < RANGE) { int pos = atomicAdd(&cur[t], 1); sesr[pos] = make_int2(pb.x, pb.y); }
    t = dv.w - lo; if ((unsigned)t < RANGE) { int pos = atomicAdd(&cur[t], 1); sesr[pos] = make_int2(pb.z, pb.w); }
  }
}

// biases
__global__ void prep_small(const float* __restrict__ b1, const float* __restrict__ b2,
                           const float* __restrict__ bif, const float* __restrict__ bhf,
                           const float* __restrict__ bib, const float* __restrict__ bhb,
                           float* __restrict__ bbar1, float* __restrict__ bbar2,
                           float* __restrict__ bselw) {
  int t = (int)threadIdx.x;
  if (t < 128) {
    bbar1[t] = (b1[t] + b1[128 + t] + b1[256 + t]) * (1.f / 3.f);
  } else if (t < 256) {
    int j = t - 128;
    bbar2[j] = (b2[j] + b2[128 + j] + b2[256 + j]) * (1.f / 3.f);
  } else if (t < 640) {
    int m = t - 256;
    int g = m >> 7, j = m & 127, dir = j >> 6, jj = j & 63;
    int grow = (g == 0) ? jj : (g == 1) ? (128 + jj) : (192 + jj);
    bselw[m] = dir ? (bib[grow] + bhb[grow]) : (bif[grow] + bhf[grow]);
  }
}

// W[384][128] (k-major) -> split-bf16 transposed planes WT[n][k]
__global__ void wt_split(const float* __restrict__ W, ushort* __restrict__ th,
                         ushort* __restrict__ tl) {
  int i = blockIdx.x * blockDim.x + threadIdx.x;
  if (i >= 128 * 384) return;
  int n = i / 384, k = i % 384;
  float v = W[(size_t)k * 128 + n];
  unsigned h, l; split1(v, h, l);
  th[i] = (ushort)h; tl[i] = (ushort)l;
}

// lstm gate weights, packed+split: Wp[m][k], m = g*128 + dir*64 + jj
__global__ void pack_w_split(const float* __restrict__ Wf, const float* __restrict__ Wb,
                             ushort* __restrict__ ph, ushort* __restrict__ pl) {
  int i = blockIdx.x * blockDim.x + threadIdx.x;
  if (i >= 384 * 128) return;
  int m = i / 128, k = i % 128;
  int g = m >> 7, j = m & 127, dir = j >> 6, jj = j & 63;
  int grow = (g == 0) ? jj : (g == 1) ? (128 + jj) : (192 + jj);
  float v = (dir ? Wb : Wf)[(size_t)grow * 128 + k];
  unsigned h, l; split1(v, h, l);
  ph[i] = (ushort)h; pl[i] = (ushort)l;
}

// f32 [NN,128] -> f16 table
__global__ void cvt_f16(const float* __restrict__ in, ushort* __restrict__ o16) {
  int i = blockIdx.x * blockDim.x + threadIdx.x;
  if (i >= NN * (F / 4)) return;
  float4 v = ((const float4*)in)[i];
  __half2 a = __floats2half2_rn(v.x, v.y);
  __half2 b = __floats2half2_rn(v.z, v.w);
  ((uint2*)o16)[i] = make_uint2(*(unsigned*)&a, *(unsigned*)&b);
}

// batched gather: one wave per (node, relation); 16-edge batches.
__global__ __launch_bounds__(256) void gather3(
    const ushort* __restrict__ table, const int2* __restrict__ ses,
    const int* __restrict__ row_ptr, const int* __restrict__ cnt,
    const float* __restrict__ rs_in3, ushort* __restrict__ z_h,
    ushort* __restrict__ z_l, int n0) {
  int wid = (int)threadIdx.x >> 6, lane = (int)threadIdx.x & 63;
  int gw = blockIdx.x * 4 + wid;          // 0 .. 3*CH-1
  int r = gw / CH;
  int n = n0 + (gw - r * CH);
  int base = r * NN + n;
  int beg = row_ptr[base], c = cnt[base];
  const int2* el = ses + (size_t)r * NE + beg;
  int half = lane >> 5, cl = lane & 31;
  const uint2* x2 = (const uint2*)table + cl;   // row stride 32 uint2 (256 B)
  float4 acc = make_float4(0.f, 0.f, 0.f, 0.f);

  int p = 0;
  while (p < c) {
    int rem = c - p; if (rem > 16) rem = 16;
    int2 es = make_int2(0, 0);
    if (lane < rem) es = el[p + lane];
    uint2 rw[8]; float scv[8];
#pragma unroll
    for (int j = 0; j < 8; ++j) {
      int e = 2 * j + half;
      int idx = (e < rem) ? e : 0;
      int s = __shfl(es.x, idx);
      float sc = __int_as_float(__shfl(es.y, idx));
      if (e >= rem) sc = 0.f;
      if (2 * j < rem) {
        rw[j] = x2[(size_t)s * 32];
        scv[j] = sc;
      }
    }
#pragma unroll
    for (int j = 0; j < 8; ++j) {
      if (2 * j < rem) {
        float2 f0 = __half22float2(*(__half2*)&rw[j].x);
        float2 f1 = __half22float2(*(__half2*)&rw[j].y);
        float sc = scv[j];
        acc.x = fmaf(f0.x, sc, acc.x); acc.y = fmaf(f0.y, sc, acc.y);
        acc.z = fmaf(f1.x, sc, acc.z); acc.w = fmaf(f1.y, sc, acc.w);
      }
    }
    p += rem;
  }

  acc.x += __shfl_xor(acc.x, 32);
  acc.y += __shfl_xor(acc.y, 32);
  acc.z += __shfl_xor(acc.z, 32);
  acc.w += __shfl_xor(acc.w, 32);
  float ci = rs_in3[base];
  unsigned h[4], l[4];
  split1(acc.x * ci, h[0], l[0]); split1(acc.y * ci, h[1], l[1]);
  split1(acc.z * ci, h[2], l[2]); split1(acc.w * ci, h[3], l[3]);
  size_t zo = (size_t)(n - n0) * 384 + r * 128 + cl * 4;
  if (half == 0) {
    *(ushort2*)(z_h + zo) = make_ushort2((ushort)h[0], (ushort)h[1]);
    *(ushort2*)(z_h + zo + 2) = make_ushort2((ushort)h[2], (ushort)h[3]);
  } else {
    *(ushort2*)(z_l + zo) = make_ushort2((ushort)l[0], (ushort)l[1]);
    *(ushort2*)(z_l + zo + 2) = make_ushort2((ushort)l[2], (ushort)l[3]);
  }
}

// LDS swizzle: 16B slot index xor'd by row bits -> 2-way max on ds_read_b128
__device__ __forceinline__ int swz(int row, int slot) {
  return row * 32 + ((slot ^ ((row >> 1) & 3)) << 3);   // ushort index
}

// H = (relu?)(Z[row,0:384] @ WT^T + bias); OUT16 -> write f16 table, else f32.
template <bool RELU, bool OUT16>
__global__ __launch_bounds__(256) void gemm_mfma(
    const ushort* __restrict__ zh, const ushort* __restrict__ zl,
    const ushort* __restrict__ wth, const ushort* __restrict__ wtl,
    const float* __restrict__ bias, void* __restrict__ Hout, int n0) {
  __shared__ ushort Ash[64 * 32], Asl[64 * 32], Bsh[128 * 32], Bsl[128 * 32];
  const int row0 = blockIdx.x * 64;
  const int t = (int)threadIdx.x;
  const int wn = t >> 6, l = t & 63, lr = l & 15, lk = l >> 4;
  f32x4 acc[4][2];
#pragma unroll
  for (int a = 0; a < 4; ++a)
#pragma unroll
    for (int b = 0; b < 2; ++b) acc[a][b] = (f32x4){0.f, 0.f, 0.f, 0.f};

  for (int kt = 0; kt < 12; ++kt) {
    __syncthreads();
    {
      int rr = t >> 2, slot = t & 3;
      size_t go = (size_t)(row0 + rr) * 384 + kt * 32 + slot * 8;
      uint4 vh = make_uint4(0, 0, 0, 0), vl = make_uint4(0, 0, 0, 0);
      if (row0 + rr < CH) { vh = *(const uint4*)(zh + go); vl = *(const uint4*)(zl + go); }
      *(uint4*)&Ash[swz(rr, slot)] = vh;
      *(uint4*)&Asl[swz(rr, slot)] = vl;
    }
#pragma unroll
    for (int i = 0; i < 2; ++i) {
      int s = i * 256 + t;
      int nn_ = s >> 2, slot = s & 3;
      size_t go = (size_t)nn_ * 384 + kt * 32 + slot * 8;
      *(uint4*)&Bsh[swz(nn_, slot)] = *(const uint4*)(wth + go);
      *(uint4*)&Bsl[swz(nn_, slot)] = *(const uint4*)(wtl + go);
    }
    __syncthreads();
    bf16x8 ah[4], al[4], bh[2], bl[2];
#pragma unroll
    for (int mf = 0; mf < 4; ++mf) {
      int row = mf * 16 + lr;
      int off = swz(row, lk);
      ah[mf] = *(const bf16x8*)&Ash[off];
      al[mf] = *(const bf16x8*)&Asl[off];
    }
#pragma unroll
    for (int f = 0; f < 2; ++f) {
      int col = wn * 32 + f * 16 + lr;
      int off = swz(col, lk);
      bh[f] = *(const bf16x8*)&Bsh[off];
      bl[f] = *(const bf16x8*)&Bsl[off];
    }
#pragma unroll
    for (int mf = 0; mf < 4; ++mf)
#pragma unroll
      for (int f = 0; f < 2; ++f) {
        acc[mf][f] = __builtin_amdgcn_mfma_f32_16x16x32_bf16(ah[mf], bh[f], acc[mf][f], 0, 0, 0);
        acc[mf][f] = __builtin_amdgcn_mfma_f32_16x16x32_bf16(ah[mf], bl[f], acc[mf][f], 0, 0, 0);
        acc[mf][f] = __builtin_amdgcn_mfma_f32_16x16x32_bf16(al[mf], bh[f], acc[mf][f], 0, 0, 0);
      }
  }
#pragma unroll
  for (int mf = 0; mf < 4; ++mf)
#pragma unroll
    for (int f = 0; f < 2; ++f) {
      int col = wn * 32 + f * 16 + lr;
      float bv = bias[col];
#pragma unroll
      for (int reg = 0; reg < 4; ++reg) {
        int row = row0 + mf * 16 + lk * 4 + reg;
        if (row < CH) {
          float v = acc[mf][f][reg] + bv;
          if (RELU) v = fmaxf(v, 0.f);
          if (OUT16) {
            __half hv = __float2half_rn(v);
            ((ushort*)Hout)[(size_t)(n0 + row) * 128 + col] = *(ushort*)&hv;
          } else {
            ((float*)Hout)[(size_t)(n0 + row) * 128 + col] = v;
          }
        }
      }
    }
}

// BiLSTM step: out = act(H[NN,128] @ Wp^T[128,384] + b), gates i,g,o in-register.
__global__ __launch_bounds__(512) void lstm_mfma(
    const float* __restrict__ H, const ushort* __restrict__ wph,
    const ushort* __restrict__ wpl, const float* __restrict__ bselw,
    float* __restrict__ out) {
  __shared__ ushort Ash[128 * 32], Asl[128 * 32], Bsh[384 * 32], Bsl[384 * 32]; // 64 KB
  const int row0 = blockIdx.x * 128;
  const int t = (int)threadIdx.x;
  const int wid = t >> 6, wm = wid >> 2, wn = wid & 3;
  const int l = t & 63, lr = l & 15, lk = l >> 4;

  int j0 = wn * 16 + lr, j1 = (wn + 4) * 16 + lr;
  float bi0 = bselw[j0], bg0 = bselw[128 + j0], bo0 = bselw[256 + j0];
  float bi1 = bselw[j1], bg1 = bselw[128 + j1], bo1 = bselw[256 + j1];

  f32x4 acc[4][6];
#pragma unroll
  for (int a = 0; a < 4; ++a)
#pragma unroll
    for (int b = 0; b < 6; ++b) acc[a][b] = (f32x4){0.f, 0.f, 0.f, 0.f};

  for (int kt = 0; kt < 4; ++kt) {
    __syncthreads();
    {
      int rr = t >> 2, slot = t & 3;
      int grow = row0 + rr;
      float v[8];
      if (grow < NN) {
        float4 a0 = *(const float4*)(H + (size_t)grow * 128 + kt * 32 + slot * 8);
        float4 a1 = *(const float4*)(H + (size_t)grow * 128 + kt * 32 + slot * 8 + 4);
        v[0] = a0.x; v[1] = a0.y; v[2] = a0.z; v[3] = a0.w;
        v[4] = a1.x; v[5] = a1.y; v[6] = a1.z; v[7] = a1.w;
      } else {
#pragma unroll
        for (int q = 0; q < 8; ++q) v[q] = 0.f;
      }
      unsigned h[8], lo[8];
#pragma unroll
      for (int q = 0; q < 8; ++q) split1(v[q], h[q], lo[q]);
      uint4 hv = make_uint4(h[0] | (h[1] << 16), h[2] | (h[3] << 16),
                            h[4] | (h[5] << 16), h[6] | (h[7] << 16));
      uint4 lv = make_uint4(lo[0] | (lo[1] << 16), lo[2] | (lo[3] << 16),
                            lo[4] | (lo[5] << 16), lo[6] | (lo[7] << 16));
      *(uint4*)&Ash[swz(rr, slot)] = hv;
      *(uint4*)&Asl[swz(rr, slot)] = lv;
    }
#pragma unroll
    for (int i = 0; i < 3; ++i) {
      int s = i * 512 + t;
      int nn_ = s >> 2, slot = s & 3;
      size_t go = (size_t)nn_ * 128 + kt * 32 + slot * 8;
      *(uint4*)&Bsh[swz(nn_, slot)] = *(const uint4*)(wph + go);
      *(uint4*)&Bsl[swz(nn_, slot)] = *(const uint4*)(wpl + go);
    }
    __syncthreads();
    bf16x8 ah[4], al[4];
#pragma unroll
    for (int mf = 0; mf < 4; ++mf) {
      int row = wm * 64 + mf * 16 + lr;
      int off = swz(row, lk);
      ah[mf] = *(const bf16x8*)&Ash[off];
      al[mf] = *(const bf16x8*)&Asl[off];
    }
#pragma unroll
    for (int tt = 0; tt < 6; ++tt) {
      int col = (wn + 4 * tt) * 16 + lr;
      int off = swz(col, lk);
      bf16x8 bh = *(const bf16x8*)&Bsh[off];
      bf16x8 bl = *(const bf16x8*)&Bsl[off];
#pragma unroll
      for (int mf = 0; mf < 4; ++mf) {
        acc[mf][tt] = __builtin_amdgcn_mfma_f32_16x16x32_bf16(ah[mf], bh, acc[mf][tt], 0, 0, 0);
        acc[mf][tt] = __builtin_amdgcn_mfma_f32_16x16x32_bf16(ah[mf], bl, acc[mf][tt], 0, 0, 0);
        acc[mf][tt] = __builtin_amdgcn_mfma_f32_16x16x32_bf16(al[mf], bh, acc[mf][tt], 0, 0, 0);
      }
    }
  }
#pragma unroll
  for (int mf = 0; mf < 4; ++mf)
#pragma unroll
    for (int reg = 0; reg < 4; ++reg) {
      int row = row0 + wm * 64 + mf * 16 + lk * 4 + reg;
      if (row < NN) {
        float iv0 = acc[mf][0][reg] + bi0, gv0 = acc[mf][2][reg] + bg0, ov0 = acc[mf][4][reg] + bo0;
        float cc0 = sigm(iv0) * tanhf(gv0);
        out[(size_t)row * 128 + j0] = sigm(ov0) * tanhf(cc0);
        float iv1 = acc[mf][1][reg] + bi1, gv1 = acc[mf][3][reg] + bg1, ov1 = acc[mf][5][reg] + bo1;
        float cc1 = sigm(iv1) * tanhf(gv1);
        out[(size_t)row * 128 + j1] = sigm(ov1) * tanhf(cc1);
      }
    }
}

extern "C" void kernel_launch(void* const* d_in, const int* in_sizes, int n_in,
                              void* d_out, int out_size, void* d_ws, size_t ws_size,
                              hipStream_t stream) {
  const float* x = (const float*)d_in[0];
  const int* src = (const int*)d_in[1];
  const int* dst = (const int*)d_in[2];
  const float* W1 = (const float*)d_in[3];   // [3][128][128] = Wcat [384][128]
  const float* b1 = (const float*)d_in[4];
  const float* W2 = (const float*)d_in[5];
  const float* b2 = (const float*)d_in[6];
  const float* Wih_f = (const float*)d_in[7];
  const float* bih_f = (const float*)d_in[9];
  const float* bhh_f = (const float*)d_in[10];
  const float* Wih_b = (const float*)d_in[11];
  const float* bih_b = (const float*)d_in[13];
  const float* bhh_b = (const float*)d_in[14];
  float* out = (float*)d_out;

  // workspace carve-up (~110 MB)
  char* wp = (char*)d_ws;
  float* rs_out = (float*)wp;          wp += (size_t)3 * NN * 4;
  float* rs_in3 = (float*)wp;          wp += (size_t)3 * NN * 4;
  int* cnt_out = (int*)wp;             wp += (size_t)3 * NN * 4;
  int* cnt_in = (int*)wp;              wp += (size_t)3 * NN * 4;
  int* row_ptr = (int*)wp;             wp += (size_t)3 * NN * 4;
  int* bsums = (int*)wp;               wp += 4096;
  int2* ses = (int2*)wp;               wp += (size_t)3 * NE * 8;
  ushort* wt1h = (ushort*)wp;          wp += (size_t)128 * 384 * 2;
  ushort* wt1l = (ushort*)wp;          wp += (size_t)128 * 384 * 2;
  ushort* wt2h = (ushort*)wp;          wp += (size_t)128 * 384 * 2;
  ushort* wt2l = (ushort*)wp;          wp += (size_t)128 * 384 * 2;
  ushort* wph = (ushort*)wp;           wp += (size_t)384 * 128 * 2;
  ushort* wpl = (ushort*)wp;           wp += (size_t)384 * 128 * 2;
  float* bbar1 = (float*)wp;           wp += 512;
  float* bbar2 = (float*)wp;           wp += 512;
  float* bselw = (float*)wp;           wp += 2048;
  ushort* z_h = (ushort*)wp;           wp += (size_t)CH * 384 * 2;
  ushort* z_l = (ushort*)wp;           wp += (size_t)CH * 384 * 2;
  ushort* x16 = (ushort*)wp;           wp += (size_t)NN * F * 2;
  ushort* h116 = (ushort*)wp;          wp += (size_t)NN * F * 2;

  // aliases, live only during CSR build (before cvt_f16 / layer-1 gemm):
  // part[2][NREL][EC][NPAD] = 55 MB over z_h+z_l+x16 (64 MB)
  int* part = (int*)z_h;
  int* part_dst = part + (size_t)NREL * EC * NPAD;   // a=1 slice
  int2* pay = (int2*)h116;                           // 12 MB <= 25.6 MB

  // CSR build — zero global atomics, XCD-grouped L2 reuse
  hist_part<<<8 * ((2 * NREL * EC + 7) / 8) * NRANGE, 256, 0, stream>>>(src, dst, part);
  reduce_part<<<(2 * NREL * NN + 255) / 256, 256, 0, stream>>>(part, cnt_out, cnt_in);
  make_rs<<<(NREL * NN + 255) / 256, 256, 0, stream>>>(cnt_out, cnt_in, rs_out, rs_in3);
  scan1<<<NREL * NBLK, 256, 0, stream>>>(cnt_in, row_ptr, bsums);
  scan2<<<NREL, 128, 0, stream>>>(bsums);
  scan3<<<(NREL * NN + 255) / 256, 256, 0, stream>>>(row_ptr, bsums);
  chunk_prefix<<<(NREL * NN + 255) / 256, 256, 0, stream>>>(part_dst, row_ptr);
  make_pay<<<(NREL * NE + 255) / 256, 256, 0, stream>>>(src, rs_out, pay);
  place_part<<<8 * ((NREL * EC + 7) / 8) * NRANGE, 256, 0, stream>>>(dst, pay, part_dst, ses);

  // weight prep
  prep_small<<<1, 640, 0, stream>>>(b1, b2, bih_f, bhh_f, bih_b, bhh_b, bbar1, bbar2, bselw);
  wt_split<<<192, 256, 0, stream>>>(W1, wt1h, wt1l);
  wt_split<<<192, 256, 0, stream>>>(W2, wt2h, wt2l);
  pack_w_split<<<192, 256, 0, stream>>>(Wih_f, Wih_b, wph, wpl);
  cvt_f16<<<(NN * 32 + 255) / 256, 256, 0, stream>>>(x, x16);

  // layer 1: x16 -> h1 (relu, f16 table)
  for (int c = 0; c < NCH; ++c) {
    gather3<<<3 * CH / 4, 256, 0, stream>>>(x16, ses, row_ptr, cnt_in, rs_in3, z_h, z_l, c * CH);
    gemm_mfma<true, true><<<(CH + 63) / 64, 256, 0, stream>>>(z_h, z_l, wt1h, wt1l, bbar1, h116, c * CH);
  }
  // layer 2: h116 -> d_out (f32)
  for (int c = 0; c < NCH; ++c) {
    gather3<<<3 * CH / 4, 256, 0, stream>>>(h116, ses, row_ptr, cnt_in, rs_in3, z_h, z_l, c * CH);
    gemm_mfma<false, false><<<(CH + 63) / 64, 256, 0, stream>>>(z_h, z_l, wt2h, wt2l, bbar2, out, c * CH);
  }
  // BiLSTM step, in place on d_out (blocks read only their own rows)
  lstm_mfma<<<(NN + 127) / 128, 512, 0, stream>>>(out, wph, wpl, bselw, out);
}

// Round 9
// 519.975 us; speedup vs baseline: 2.7551x; 1.0968x over previous
//
#include <hip/hip_runtime.h>
#include <hip/hip_fp16.h>
#include <math.h>

#define NN 100000
#define NE 500000
#define NREL 3
#define F 128
#define SCAN_BLK 1024
#define NBLK ((NN + SCAN_BLK - 1) / SCAN_BLK)   // 98
#define CH 25000
#define NCH 4

// CSR build partitioning
#define RANGE 16384
#define NRANGE 7            // 7*16384 >= NN
#define NPAD (NRANGE * RANGE)
#define EC 20
#define EPC (NE / EC)       // 25000

typedef __attribute__((ext_vector_type(8))) short bf16x8;
typedef __attribute__((ext_vector_type(4))) float f32x4;

__device__ __forceinline__ float sigm(float x) { return 1.f / (1.f + __expf(-x)); }

__device__ __forceinline__ unsigned bf16rne(float x) {
  unsigned u = __float_as_uint(x);
  return (u + 0x7FFFu + ((u >> 16) & 1u)) >> 16;
}
__device__ __forceinline__ void split1(float x, unsigned& h, unsigned& l) {
  h = bf16rne(x);
  float hf = __uint_as_float(h << 16);
  l = bf16rne(x - hf);
}

// LDS swizzle (row stride 32 ushorts): 2-way max on ds_read_b128
__device__ __forceinline__ int swz(int row, int slot) {
  return row * 32 + ((slot ^ ((row >> 1) & 3)) << 3);
}

// ---- atomic-free histogram: one block owns (array, rel, chunk, range);
// XCD-grouped decode (all NRANGE blocks of one (a,r,c) share blockIdx%8).
__global__ __launch_bounds__(256) void hist_part(const int* __restrict__ src,
                                                 const int* __restrict__ dst,
                                                 int* __restrict__ part) {
  int x = blockIdx.x & 7, q = blockIdx.x >> 3;
  int g = q % NRANGE;
  int rc2 = x + 8 * (q / NRANGE);
  int a = rc2 / (NREL * EC);
  int rcl = rc2 % (NREL * EC);
  int r = rcl / EC, c = rcl % EC;
  __shared__ int h[RANGE];
  for (int i = threadIdx.x; i < RANGE; i += 256) h[i] = 0;
  __syncthreads();
  const int* idx = (a ? dst : src) + (size_t)r * NE + (size_t)c * EPC;
  const int4* v4 = (const int4*)idx;
  int lo = g * RANGE;
  for (int i = threadIdx.x; i < EPC / 4; i += 256) {
    int4 v = v4[i];
    int t;
    t = v.x - lo; if ((unsigned)t < RANGE) atomicAdd(&h[t], 1);
    t = v.y - lo; if ((unsigned)t < RANGE) atomicAdd(&h[t], 1);
    t = v.z - lo; if ((unsigned)t < RANGE) atomicAdd(&h[t], 1);
    t = v.w - lo; if ((unsigned)t < RANGE) atomicAdd(&h[t], 1);
  }
  __syncthreads();
  int* op = part + (((size_t)a * NREL + r) * EC + c) * NPAD + (size_t)g * RANGE;
  for (int i = threadIdx.x; i < RANGE; i += 256) op[i] = h[i];
}

__global__ void reduce_part(const int* __restrict__ part, int* __restrict__ cnt_out,
                            int* __restrict__ cnt_in) {
  int i = blockIdx.x * blockDim.x + threadIdx.x;
  if (i >= 2 * NREL * NN) return;
  int a = i / (NREL * NN);
  int rn = i - a * (NREL * NN);
  const int* p = part + ((size_t)a * NREL + rn / NN) * EC * NPAD + (rn % NN);
  int s = 0;
#pragma unroll
  for (int c = 0; c < EC; ++c) s += p[(size_t)c * NPAD];
  (a ? cnt_in : cnt_out)[rn] = s;
}

__global__ void make_rs(const int* __restrict__ cnt_out, const int* __restrict__ cnt_in,
                        float* __restrict__ rs_out, float* __restrict__ rs_in3) {
  int i = blockIdx.x * blockDim.x + threadIdx.x;
  if (i >= NREL * NN) return;
  int c0 = cnt_out[i];
  rs_out[i] = rsqrtf((float)(c0 < 1 ? 1 : c0));
  int c1 = cnt_in[i];
  rs_in3[i] = rsqrtf((float)(c1 < 1 ? 1 : c1)) * (1.f / 3.f);
}

// ---- two-level exclusive scan of cnt_in -> row_ptr ----
__global__ __launch_bounds__(256) void scan1(const int* __restrict__ cnt,
                                             int* __restrict__ excl, int* __restrict__ bsums) {
  int rb = blockIdx.x;
  int r = rb / NBLK, blk = rb % NBLK;
  int tid = (int)threadIdx.x;
  int v[4]; int sum = 0;
#pragma unroll
  for (int i = 0; i < 4; ++i) {
    int idx = blk * SCAN_BLK + tid * 4 + i;
    int c = (idx < NN) ? cnt[r * NN + idx] : 0;
    v[i] = sum; sum += c;
  }
  __shared__ int ts[256];
  ts[tid] = sum;
  __syncthreads();
  for (int off = 1; off < 256; off <<= 1) {
    int t = (tid >= off) ? ts[tid - off] : 0;
    __syncthreads();
    ts[tid] += t;
    __syncthreads();
  }
  int texcl = tid ? ts[tid - 1] : 0;
#pragma unroll
  for (int i = 0; i < 4; ++i) {
    int idx = blk * SCAN_BLK + tid * 4 + i;
    if (idx < NN) excl[r * NN + idx] = texcl + v[i];
  }
  if (tid == 255) bsums[rb] = ts[255];
}

__global__ __launch_bounds__(128) void scan2(int* __restrict__ bsums) {
  int r = blockIdx.x;
  int tid = (int)threadIdx.x;
  __shared__ int ts[128];
  ts[tid] = (tid < NBLK) ? bsums[r * NBLK + tid] : 0;
  __syncthreads();
  for (int off = 1; off < 128; off <<= 1) {
    int t = (tid >= off) ? ts[tid - off] : 0;
    __syncthreads();
    ts[tid] += t;
    __syncthreads();
  }
  if (tid < NBLK) bsums[r * NBLK + tid] = tid ? ts[tid - 1] : 0;
}

__global__ void scan3(int* __restrict__ row_ptr, const int* __restrict__ bsums) {
  int i = blockIdx.x * blockDim.x + threadIdx.x;
  if (i >= NREL * NN) return;
  int r = i / NN, idx = i - r * NN, blk = idx / SCAN_BLK;
  row_ptr[i] += bsums[r * NBLK + blk];
}

__global__ void chunk_prefix(int* __restrict__ part_dst, const int* __restrict__ row_ptr) {
  int i = blockIdx.x * blockDim.x + threadIdx.x;
  if (i >= NREL * NN) return;
  int r = i / NN, node = i - r * NN;
  int* p = part_dst + (size_t)r * EC * NPAD + node;
  int run = row_ptr[i];
#pragma unroll
  for (int c = 0; c < EC; ++c) {
    int t = p[(size_t)c * NPAD];
    p[(size_t)c * NPAD] = run;
    run += t;
  }
}

__global__ void make_pay(const int* __restrict__ src, const float* __restrict__ rs_out,
                         int2* __restrict__ pay) {
  int i = blockIdx.x * blockDim.x + threadIdx.x;
  if (i >= NREL * NE) return;
  int r = i / NE;
  int s = src[i];
  pay[i] = make_int2(s, __float_as_int(rs_out[r * NN + s]));
}

__global__ __launch_bounds__(256) void place_part(const int* __restrict__ dst,
                                                  const int2* __restrict__ pay,
                                                  const int* __restrict__ part_dst,
                                                  int2* __restrict__ ses) {
  int x = blockIdx.x & 7, q = blockIdx.x >> 3;
  int g = q % NRANGE;
  int rc = x + 8 * (q / NRANGE);
  if (rc >= NREL * EC) return;
  int r = rc / EC, c = rc % EC;
  __shared__ int cur[RANGE];
  const int* pc = part_dst + ((size_t)r * EC + c) * NPAD + (size_t)g * RANGE;
  for (int i = threadIdx.x; i < RANGE; i += 256) cur[i] = pc[i];
  __syncthreads();
  int lo = g * RANGE;
  const int4* d4 = (const int4*)(dst + (size_t)r * NE + (size_t)c * EPC);
  const int4* p4 = (const int4*)(pay + (size_t)r * NE + (size_t)c * EPC);
  int2* sesr = ses + (size_t)r * NE;
  for (int i = threadIdx.x; i < EPC / 4; i += 256) {
    int4 dv = d4[i];
    int4 pa = p4[2 * i], pb = p4[2 * i + 1];
    int t;
    t = dv.x - lo; if ((unsigned)t < RANGE) { int pos = atomicAdd(&cur[t], 1); sesr[pos] = make_int2(pa.x, pa.y); }
    t = dv.y - lo; if ((unsigned)t < RANGE) { int pos = atomicAdd(&cur[t], 1); sesr[pos] = make_int2(pa.z, pa.w); }
    t = dv.z - lo; if ((unsigned)t < RANGE) { int pos = atomicAdd(&cur[t], 1); sesr[pos] = make_int2(pb.x, pb.y); }
    t = dv.w - lo; if ((unsigned)t < RANGE) { int pos = atomicAdd(&cur[t], 1); sesr[pos] = make_int2(pb.z, pb.w); }
  }
}

// biases
__global__ void prep_small(const float* __restrict__ b1, const float* __restrict__ b2,
                           const float* __restrict__ bif, const float* __restrict__ bhf,
                           const float* __restrict__ bib, const float* __restrict__ bhb,
                           float* __restrict__ bbar1, float* __restrict__ bbar2,
                           float* __restrict__ bselw) {
  int t = (int)threadIdx.x;
  if (t < 128) {
    bbar1[t] = (b1[t] + b1[128 + t] + b1[256 + t]) * (1.f / 3.f);
  } else if (t < 256) {
    int j = t - 128;
    bbar2[j] = (b2[j] + b2[128 + j] + b2[256 + j]) * (1.f / 3.f);
  } else if (t < 640) {
    int m = t - 256;
    int g = m >> 7, j = m & 127, dir = j >> 6, jj = j & 63;
    int grow = (g == 0) ? jj : (g == 1) ? (128 + jj) : (192 + jj);
    bselw[m] = dir ? (bib[grow] + bhb[grow]) : (bif[grow] + bhf[grow]);
  }
}

// W[384][128] (k-major) -> split-bf16 transposed planes WT[n][k]
__global__ void wt_split(const float* __restrict__ W, ushort* __restrict__ th,
                         ushort* __restrict__ tl) {
  int i = blockIdx.x * blockDim.x + threadIdx.x;
  if (i >= 128 * 384) return;
  int n = i / 384, k = i % 384;
  float v = W[(size_t)k * 128 + n];
  unsigned h, l; split1(v, h, l);
  th[i] = (ushort)h; tl[i] = (ushort)l;
}

// lstm gate weights, packed+split: Wp[m][k], m = g*128 + dir*64 + jj
__global__ void pack_w_split(const float* __restrict__ Wf, const float* __restrict__ Wb,
                             ushort* __restrict__ ph, ushort* __restrict__ pl) {
  int i = blockIdx.x * blockDim.x + threadIdx.x;
  if (i >= 384 * 128) return;
  int m = i / 128, k = i % 128;
  int g = m >> 7, j = m & 127, dir = j >> 6, jj = j & 63;
  int grow = (g == 0) ? jj : (g == 1) ? (128 + jj) : (192 + jj);
  float v = (dir ? Wb : Wf)[(size_t)grow * 128 + k];
  unsigned h, l; split1(v, h, l);
  ph[i] = (ushort)h; pl[i] = (ushort)l;
}

// f32 [NN,128] -> f16 table
__global__ void cvt_f16(const float* __restrict__ in, ushort* __restrict__ o16) {
  int i = blockIdx.x * blockDim.x + threadIdx.x;
  if (i >= NN * (F / 4)) return;
  float4 v = ((const float4*)in)[i];
  __half2 a = __floats2half2_rn(v.x, v.y);
  __half2 b = __floats2half2_rn(v.z, v.w);
  ((uint2*)o16)[i] = make_uint2(*(unsigned*)&a, *(unsigned*)&b);
}

// batched gather: one wave per (node, relation); 16-edge batches; f16 z out.
__global__ __launch_bounds__(256) void gather3(
    const ushort* __restrict__ table, const int2* __restrict__ ses,
    const int* __restrict__ row_ptr, const int* __restrict__ cnt,
    const float* __restrict__ rs_in3, ushort* __restrict__ z16, int n0) {
  int wid = (int)threadIdx.x >> 6, lane = (int)threadIdx.x & 63;
  int gw = blockIdx.x * 4 + wid;
  int r = gw / CH;
  int n = n0 + (gw - r * CH);
  int base = r * NN + n;
  int beg = row_ptr[base], c = cnt[base];
  const int2* el = ses + (size_t)r * NE + beg;
  int half = lane >> 5, cl = lane & 31;
  const uint2* x2 = (const uint2*)table + cl;
  float4 acc = make_float4(0.f, 0.f, 0.f, 0.f);

  int p = 0;
  while (p < c) {
    int rem = c - p; if (rem > 16) rem = 16;
    int2 es = make_int2(0, 0);
    if (lane < rem) es = el[p + lane];
    uint2 rw[8]; float scv[8];
#pragma unroll
    for (int j = 0; j < 8; ++j) {
      int e = 2 * j + half;
      int idx = (e < rem) ? e : 0;
      int s = __shfl(es.x, idx);
      float sc = __int_as_float(__shfl(es.y, idx));
      if (e >= rem) sc = 0.f;
      if (2 * j < rem) {
        rw[j] = x2[(size_t)s * 32];
        scv[j] = sc;
      }
    }
#pragma unroll
    for (int j = 0; j < 8; ++j) {
      if (2 * j < rem) {
        float2 f0 = __half22float2(*(__half2*)&rw[j].x);
        float2 f1 = __half22float2(*(__half2*)&rw[j].y);
        float sc = scv[j];
        acc.x = fmaf(f0.x, sc, acc.x); acc.y = fmaf(f0.y, sc, acc.y);
        acc.z = fmaf(f1.x, sc, acc.z); acc.w = fmaf(f1.y, sc, acc.w);
      }
    }
    p += rem;
  }

  acc.x += __shfl_xor(acc.x, 32);
  acc.y += __shfl_xor(acc.y, 32);
  acc.z += __shfl_xor(acc.z, 32);
  acc.w += __shfl_xor(acc.w, 32);
  if (half == 0) {
    float ci = rs_in3[base];
    __half2 p0 = __floats2half2_rn(acc.x * ci, acc.y * ci);
    __half2 p1 = __floats2half2_rn(acc.z * ci, acc.w * ci);
    size_t zo = (size_t)(n - n0) * 384 + r * 128 + cl * 4;
    *(uint2*)(z16 + zo) = make_uint2(*(unsigned*)&p0, *(unsigned*)&p1);
  }
}

// f16x8 -> split bf16 hi/lo uint4s
__device__ __forceinline__ void cvt_split8(uint4 v, uint4& hv, uint4& lv) {
  float f[8];
  *(float2*)&f[0] = __half22float2(*(__half2*)&v.x);
  *(float2*)&f[2] = __half22float2(*(__half2*)&v.y);
  *(float2*)&f[4] = __half22float2(*(__half2*)&v.z);
  *(float2*)&f[6] = __half22float2(*(__half2*)&v.w);
  unsigned h[8], l[8];
#pragma unroll
  for (int q = 0; q < 8; ++q) split1(f[q], h[q], l[q]);
  hv = make_uint4(h[0] | (h[1] << 16), h[2] | (h[3] << 16),
                  h[4] | (h[5] << 16), h[6] | (h[7] << 16));
  lv = make_uint4(l[0] | (l[1] << 16), l[2] | (l[3] << 16),
                  l[4] | (l[5] << 16), l[6] | (l[7] << 16));
}

// layer-1 GEMM: h1 = relu(Z(f16)[row,0:384] @ WT^T + bias), f16 out. 256 thr.
__global__ __launch_bounds__(256) void gemm_mfma1(
    const ushort* __restrict__ z16,
    const ushort* __restrict__ wth, const ushort* __restrict__ wtl,
    const float* __restrict__ bias, ushort* __restrict__ Hout, int n0) {
  __shared__ ushort Ash[64 * 32], Asl[64 * 32], Bsh[128 * 32], Bsl[128 * 32];
  const int row0 = blockIdx.x * 64;
  const int t = (int)threadIdx.x;
  const int wn = t >> 6, l = t & 63, lr = l & 15, lk = l >> 4;
  f32x4 acc[4][2];
#pragma unroll
  for (int a = 0; a < 4; ++a)
#pragma unroll
    for (int b = 0; b < 2; ++b) acc[a][b] = (f32x4){0.f, 0.f, 0.f, 0.f};

  for (int kt = 0; kt < 12; ++kt) {
    __syncthreads();
    {   // A: 64x32 f16 -> split planes
      int rr = t >> 2, slot = t & 3;
      uint4 v = make_uint4(0, 0, 0, 0);
      if (row0 + rr < CH)
        v = *(const uint4*)(z16 + (size_t)(row0 + rr) * 384 + kt * 32 + slot * 8);
      uint4 hv, lv; cvt_split8(v, hv, lv);
      *(uint4*)&Ash[swz(rr, slot)] = hv;
      *(uint4*)&Asl[swz(rr, slot)] = lv;
    }
#pragma unroll
    for (int i = 0; i < 2; ++i) {
      int s = i * 256 + t;
      int nn_ = s >> 2, slot = s & 3;
      size_t go = (size_t)nn_ * 384 + kt * 32 + slot * 8;
      *(uint4*)&Bsh[swz(nn_, slot)] = *(const uint4*)(wth + go);
      *(uint4*)&Bsl[swz(nn_, slot)] = *(const uint4*)(wtl + go);
    }
    __syncthreads();
    bf16x8 ah[4], al[4], bh[2], bl[2];
#pragma unroll
    for (int mf = 0; mf < 4; ++mf) {
      int off = swz(mf * 16 + lr, lk);
      ah[mf] = *(const bf16x8*)&Ash[off];
      al[mf] = *(const bf16x8*)&Asl[off];
    }
#pragma unroll
    for (int f = 0; f < 2; ++f) {
      int off = swz(wn * 32 + f * 16 + lr, lk);
      bh[f] = *(const bf16x8*)&Bsh[off];
      bl[f] = *(const bf16x8*)&Bsl[off];
    }
#pragma unroll
    for (int mf = 0; mf < 4; ++mf)
#pragma unroll
      for (int f = 0; f < 2; ++f) {
        acc[mf][f] = __builtin_amdgcn_mfma_f32_16x16x32_bf16(ah[mf], bh[f], acc[mf][f], 0, 0, 0);
        acc[mf][f] = __builtin_amdgcn_mfma_f32_16x16x32_bf16(ah[mf], bl[f], acc[mf][f], 0, 0, 0);
        acc[mf][f] = __builtin_amdgcn_mfma_f32_16x16x32_bf16(al[mf], bh[f], acc[mf][f], 0, 0, 0);
      }
  }
#pragma unroll
  for (int mf = 0; mf < 4; ++mf)
#pragma unroll
    for (int f = 0; f < 2; ++f) {
      int col = wn * 32 + f * 16 + lr;
      float bv = bias[col];
#pragma unroll
      for (int reg = 0; reg < 4; ++reg) {
        int row = row0 + mf * 16 + lk * 4 + reg;
        if (row < CH) {
          float v = fmaxf(acc[mf][f][reg] + bv, 0.f);
          __half hv = __float2half_rn(v);
          Hout[(size_t)(n0 + row) * 128 + col] = *(ushort*)&hv;
        }
      }
    }
}

// fused layer-2 GEMM + BiLSTM. 512 thr, BM=64.
// phase1: h2 = z@W2T+b (regs). phase2: h2 -> LDS split planes (swizzled).
// phase3: gates = h2@WpT. epilogue: sigmoid/tanh -> out.
__global__ __launch_bounds__(512) void gemm2_lstm(
    const ushort* __restrict__ z16,
    const ushort* __restrict__ wth, const ushort* __restrict__ wtl,
    const ushort* __restrict__ wph, const ushort* __restrict__ wpl,
    const float* __restrict__ bbar2, const float* __restrict__ bselw,
    float* __restrict__ out, int n0) {
  __shared__ ushort lds[40960];   // 80 KB
  ushort* A1h = lds;              // [0,2048)
  ushort* A1l = lds + 2048;       // [2048,4096)
  ushort* B1h = lds + 4096;       // [4096,8192)
  ushort* B1l = lds + 8192;       // [8192,12288)
  ushort* A2h = lds;              // [0,8192)      phase 2/3
  ushort* A2l = lds + 8192;       // [8192,16384)
  ushort* B3h = lds + 16384;      // [16384,28672)
  ushort* B3l = lds + 28672;      // [28672,40960)

  const int row0 = blockIdx.x * 64;
  const int t = (int)threadIdx.x;
  const int wid = t >> 6, l = t & 63, lr = l & 15, lk = l >> 4;

  // ---- phase 1: 8 waves x 16 cols, 64 rows each ----
  f32x4 acc1[4];
#pragma unroll
  for (int a = 0; a < 4; ++a) acc1[a] = (f32x4){0.f, 0.f, 0.f, 0.f};

  for (int kt = 0; kt < 12; ++kt) {
    __syncthreads();
    if (t < 256) {   // A: 64x32 f16 -> split planes
      int rr = t >> 2, slot = t & 3;
      uint4 v = make_uint4(0, 0, 0, 0);
      if (row0 + rr < CH)
        v = *(const uint4*)(z16 + (size_t)(row0 + rr) * 384 + kt * 32 + slot * 8);
      uint4 hv, lv; cvt_split8(v, hv, lv);
      *(uint4*)&A1h[swz(rr, slot)] = hv;
      *(uint4*)&A1l[swz(rr, slot)] = lv;
    }
    {   // B: 128x32
      int nn_ = t >> 2, slot = t & 3;
      size_t go = (size_t)nn_ * 384 + kt * 32 + slot * 8;
      *(uint4*)&B1h[swz(nn_, slot)] = *(const uint4*)(wth + go);
      *(uint4*)&B1l[swz(nn_, slot)] = *(const uint4*)(wtl + go);
    }
    __syncthreads();
    bf16x8 ah[4], al[4];
#pragma unroll
    for (int mf = 0; mf < 4; ++mf) {
      int off = swz(mf * 16 + lr, lk);
      ah[mf] = *(const bf16x8*)&A1h[off];
      al[mf] = *(const bf16x8*)&A1l[off];
    }
    int offb = swz(wid * 16 + lr, lk);
    bf16x8 bh = *(const bf16x8*)&B1h[offb];
    bf16x8 bl = *(const bf16x8*)&B1l[offb];
#pragma unroll
    for (int mf = 0; mf < 4; ++mf) {
      acc1[mf] = __builtin_amdgcn_mfma_f32_16x16x32_bf16(ah[mf], bh, acc1[mf], 0, 0, 0);
      acc1[mf] = __builtin_amdgcn_mfma_f32_16x16x32_bf16(ah[mf], bl, acc1[mf], 0, 0, 0);
      acc1[mf] = __builtin_amdgcn_mfma_f32_16x16x32_bf16(al[mf], bh, acc1[mf], 0, 0, 0);
    }
  }

  // ---- phase 2: h2 tile -> LDS A2 split planes (swizzled [64][128]) ----
  __syncthreads();
  {
    int colc = wid * 16 + lr;
    float bb = bbar2[colc];
#pragma unroll
    for (int mf = 0; mf < 4; ++mf)
#pragma unroll
      for (int reg = 0; reg < 4; ++reg) {
        int rowc = mf * 16 + lk * 4 + reg;
        float v = acc1[mf][reg] + bb;
        unsigned h, lo2; split1(v, h, lo2);
        int sl2 = (colc >> 3) ^ (rowc & 7);
        int addr = rowc * 128 + (sl2 << 3) + (colc & 7);
        A2h[addr] = (ushort)h;
        A2l[addr] = (ushort)lo2;
      }
  }
  __syncthreads();

  // ---- phase 3: gates = h2 @ WpT, 8 waves: wm in {0,1} x wn3 in 0..3 ----
  const int wm = wid >> 2, wn3 = wid & 3;
  f32x4 acc3[2][6];
#pragma unroll
  for (int a = 0; a < 2; ++a)
#pragma unroll
    for (int b = 0; b < 6; ++b) acc3[a][b] = (f32x4){0.f, 0.f, 0.f, 0.f};

  for (int kt = 0; kt < 4; ++kt) {
    if (kt) __syncthreads();
#pragma unroll
    for (int i = 0; i < 3; ++i) {   // B3: 384x32 per plane
      int s = i * 512 + t;
      int m = s >> 2, slot = s & 3;
      size_t go = (size_t)m * 128 + kt * 32 + slot * 8;
      *(uint4*)&B3h[swz(m, slot)] = *(const uint4*)(wph + go);
      *(uint4*)&B3l[swz(m, slot)] = *(const uint4*)(wpl + go);
    }
    __syncthreads();
    bf16x8 ah2[2], al2[2];
#pragma unroll
    for (int mf = 0; mf < 2; ++mf) {
      int row = wm * 32 + mf * 16 + lr;
      int kslot = kt * 4 + lk;
      int sl2 = kslot ^ (row & 7);
      int addr = row * 128 + (sl2 << 3);
      ah2[mf] = *(const bf16x8*)&A2h[addr];
      al2[mf] = *(const bf16x8*)&A2l[addr];
    }
#pragma unroll
    for (int tt = 0; tt < 6; ++tt) {
      int m = (wn3 + 4 * tt) * 16 + lr;
      int off = swz(m, lk);
      bf16x8 bh = *(const bf16x8*)&B3h[off];
      bf16x8 bl = *(const bf16x8*)&B3l[off];
#pragma unroll
      for (int mf = 0; mf < 2; ++mf) {
        acc3[mf][tt] = __builtin_amdgcn_mfma_f32_16x16x32_bf16(ah2[mf], bh, acc3[mf][tt], 0, 0, 0);
        acc3[mf][tt] = __builtin_amdgcn_mfma_f32_16x16x32_bf16(ah2[mf], bl, acc3[mf][tt], 0, 0, 0);
        acc3[mf][tt] = __builtin_amdgcn_mfma_f32_16x16x32_bf16(al2[mf], bh, acc3[mf][tt], 0, 0, 0);
      }
    }
  }

  // ---- epilogue: LSTM activations ----
  int j0 = wn3 * 16 + lr, j1 = j0 + 64;
  float bi0 = bselw[j0], bg0 = bselw[128 + j0], bo0 = bselw[256 + j0];
  float bi1 = bselw[j1], bg1 = bselw[128 + j1], bo1 = bselw[256 + j1];
#pragma unroll
  for (int mf = 0; mf < 2; ++mf)
#pragma unroll
    for (int reg = 0; reg < 4; ++reg) {
      int grow = wm * 32 + mf * 16 + lk * 4 + reg;   // block-local row
      if (row0 + grow < CH) {
        size_t orow = (size_t)(n0 + row0 + grow) * 128;
        float iv0 = acc3[mf][0][reg] + bi0, gv0 = acc3[mf][2][reg] + bg0,
              ov0 = acc3[mf][4][reg] + bo0;
        float c0 = sigm(iv0) * tanhf(gv0);
        out[orow + j0] = sigm(ov0) * tanhf(c0);
        float iv1 = acc3[mf][1][reg] + bi1, gv1 = acc3[mf][3][reg] + bg1,
              ov1 = acc3[mf][5][reg] + bo1;
        float c1 = sigm(iv1) * tanhf(gv1);
        out[orow + j1] = sigm(ov1) * tanhf(c1);
      }
    }
}

extern "C" void kernel_launch(void* const* d_in, const int* in_sizes, int n_in,
                              void* d_out, int out_size, void* d_ws, size_t ws_size,
                              hipStream_t stream) {
  const float* x = (const float*)d_in[0];
  const int* src = (const int*)d_in[1];
  const int* dst = (const int*)d_in[2];
  const float* W1 = (const float*)d_in[3];
  const float* b1 = (const float*)d_in[4];
  const float* W2 = (const float*)d_in[5];
  const float* b2 = (const float*)d_in[6];
  const float* Wih_f = (const float*)d_in[7];
  const float* bih_f = (const float*)d_in[9];
  const float* bhh_f = (const float*)d_in[10];
  const float* Wih_b = (const float*)d_in[11];
  const float* bih_b = (const float*)d_in[13];
  const float* bhh_b = (const float*)d_in[14];
  float* out = (float*)d_out;

  // workspace carve-up (~90 MB)
  char* wp = (char*)d_ws;
  float* rs_out = (float*)wp;          wp += (size_t)3 * NN * 4;
  float* rs_in3 = (float*)wp;          wp += (size_t)3 * NN * 4;
  int* cnt_out = (int*)wp;             wp += (size_t)3 * NN * 4;
  int* cnt_in = (int*)wp;              wp += (size_t)3 * NN * 4;
  int* row_ptr = (int*)wp;             wp += (size_t)3 * NN * 4;
  int* bsums = (int*)wp;               wp += 4096;
  int2* ses = (int2*)wp;               wp += (size_t)3 * NE * 8;
  ushort* wt1h = (ushort*)wp;          wp += (size_t)128 * 384 * 2;
  ushort* wt1l = (ushort*)wp;          wp += (size_t)128 * 384 * 2;
  ushort* wt2h = (ushort*)wp;          wp += (size_t)128 * 384 * 2;
  ushort* wt2l = (ushort*)wp;          wp += (size_t)128 * 384 * 2;
  ushort* wph = (ushort*)wp;           wp += (size_t)384 * 128 * 2;
  ushort* wpl = (ushort*)wp;           wp += (size_t)384 * 128 * 2;
  float* bbar1 = (float*)wp;           wp += 512;
  float* bbar2 = (float*)wp;           wp += 512;
  float* bselw = (float*)wp;           wp += 2048;
  ushort* z16 = (ushort*)wp;           wp += (size_t)CH * 384 * 2;   // 19.2 MB
  ushort* x16 = (ushort*)wp;           wp += (size_t)NN * F * 2;     // 25.6 MB
  ushort* h116 = (ushort*)wp;          wp += (size_t)NN * F * 2;     // 25.6 MB

  // CSR-build aliases (dead before z16/x16/h116 first use):
  // part: 55.05 MB starting at z16 -> spans z16+x16 and 10.25 MB into h116.
  // pay: 12 MB at h116+12MB (disjoint from part's spill).
  int* part = (int*)z16;
  int* part_dst = part + (size_t)NREL * EC * NPAD;
  int2* pay = (int2*)((char*)h116 + ((size_t)12 << 20));

  // CSR build — zero global atomics, XCD-grouped L2 reuse
  hist_part<<<2 * NREL * EC * NRANGE, 256, 0, stream>>>(src, dst, part);
  reduce_part<<<(2 * NREL * NN + 255) / 256, 256, 0, stream>>>(part, cnt_out, cnt_in);
  make_rs<<<(NREL * NN + 255) / 256, 256, 0, stream>>>(cnt_out, cnt_in, rs_out, rs_in3);
  scan1<<<NREL * NBLK, 256, 0, stream>>>(cnt_in, row_ptr, bsums);
  scan2<<<NREL, 128, 0, stream>>>(bsums);
  scan3<<<(NREL * NN + 255) / 256, 256, 0, stream>>>(row_ptr, bsums);
  chunk_prefix<<<(NREL * NN + 255) / 256, 256, 0, stream>>>(part_dst, row_ptr);
  make_pay<<<(NREL * NE + 255) / 256, 256, 0, stream>>>(src, rs_out, pay);
  place_part<<<8 * ((NREL * EC + 7) / 8) * NRANGE, 256, 0, stream>>>(dst, pay, part_dst, ses);

  // weight prep
  prep_small<<<1, 640, 0, stream>>>(b1, b2, bih_f, bhh_f, bih_b, bhh_b, bbar1, bbar2, bselw);
  wt_split<<<192, 256, 0, stream>>>(W1, wt1h, wt1l);
  wt_split<<<192, 256, 0, stream>>>(W2, wt2h, wt2l);
  pack_w_split<<<192, 256, 0, stream>>>(Wih_f, Wih_b, wph, wpl);
  cvt_f16<<<(NN * 32 + 255) / 256, 256, 0, stream>>>(x, x16);

  // layer 1: x16 -> h116 (relu, f16)
  for (int c = 0; c < NCH; ++c) {
    gather3<<<3 * CH / 4, 256, 0, stream>>>(x16, ses, row_ptr, cnt_in, rs_in3, z16, c * CH);
    gemm_mfma1<<<(CH + 63) / 64, 256, 0, stream>>>(z16, wt1h, wt1l, bbar1, h116, c * CH);
  }
  // layer 2 + fused BiLSTM: h116 -> d_out
  for (int c = 0; c < NCH; ++c) {
    gather3<<<3 * CH / 4, 256, 0, stream>>>(h116, ses, row_ptr, cnt_in, rs_in3, z16, c * CH);
    gemm2_lstm<<<(CH + 63) / 64, 512, 0, stream>>>(z16, wt2h, wt2l, wph, wpl,
                                                   bbar2, bselw, out, c * CH);
  }
}

// Round 10
// 513.604 us; speedup vs baseline: 2.7893x; 1.0124x over previous
//
#include <hip/hip_runtime.h>
#include <hip/hip_fp16.h>
#include <math.h>

#define NN 100000
#define NE 500000
#define NREL 3
#define F 128
#define SCAN_BLK 1024
#define NBLK ((NN + SCAN_BLK - 1) / SCAN_BLK)   // 98
#define CH 25000
#define NCH 4

// CSR build partitioning
#define RANGE 16384
#define NRANGE 7            // 7*16384 >= NN
#define NPAD (NRANGE * RANGE)
#define EC 20
#define EPC (NE / EC)       // 25000

typedef __attribute__((ext_vector_type(8))) short bf16x8;
typedef __attribute__((ext_vector_type(4))) float f32x4;

__device__ __forceinline__ float sigm(float x) { return 1.f / (1.f + __expf(-x)); }

__device__ __forceinline__ unsigned bf16rne(float x) {
  unsigned u = __float_as_uint(x);
  return (u + 0x7FFFu + ((u >> 16) & 1u)) >> 16;
}
__device__ __forceinline__ void split1(float x, unsigned& h, unsigned& l) {
  h = bf16rne(x);
  float hf = __uint_as_float(h << 16);
  l = bf16rne(x - hf);
}

// LDS swizzle (row stride 32 ushorts): 2-way max on ds_read_b128
__device__ __forceinline__ int swz(int row, int slot) {
  return row * 32 + ((slot ^ ((row >> 1) & 3)) << 3);
}

// ---- atomic-free histogram (u16 partials): one block owns (array, rel, chunk, range);
// XCD-grouped decode (all NRANGE blocks of one (a,r,c) share blockIdx%8).
__global__ __launch_bounds__(256) void hist_part(const int* __restrict__ src,
                                                 const int* __restrict__ dst,
                                                 ushort* __restrict__ part) {
  int x = blockIdx.x & 7, q = blockIdx.x >> 3;
  int g = q % NRANGE;
  int rc2 = x + 8 * (q / NRANGE);
  int a = rc2 / (NREL * EC);
  int rcl = rc2 % (NREL * EC);
  int r = rcl / EC, c = rcl % EC;
  __shared__ int h[RANGE];
  for (int i = threadIdx.x; i < RANGE; i += 256) h[i] = 0;
  __syncthreads();
  const int* idx = (a ? dst : src) + (size_t)r * NE + (size_t)c * EPC;
  const int4* v4 = (const int4*)idx;
  int lo = g * RANGE;
  for (int i = threadIdx.x; i < EPC / 4; i += 256) {
    int4 v = v4[i];
    int t;
    t = v.x - lo; if ((unsigned)t < RANGE) atomicAdd(&h[t], 1);
    t = v.y - lo; if ((unsigned)t < RANGE) atomicAdd(&h[t], 1);
    t = v.z - lo; if ((unsigned)t < RANGE) atomicAdd(&h[t], 1);
    t = v.w - lo; if ((unsigned)t < RANGE) atomicAdd(&h[t], 1);
  }
  __syncthreads();
  ushort* op = part + (((size_t)a * NREL + r) * EC + c) * NPAD + (size_t)g * RANGE;
  for (int i = threadIdx.x; i < RANGE; i += 256) op[i] = (ushort)h[i];
}

// fused: cnt_in + both rsqrt normalizers from u16 partials
__global__ void reduce_rs(const ushort* __restrict__ part, int* __restrict__ cnt_in,
                          float* __restrict__ rs_out, float* __restrict__ rs_in3) {
  int i = blockIdx.x * blockDim.x + threadIdx.x;
  if (i >= NREL * NN) return;
  int r = i / NN, node = i - r * NN;
  const ushort* p0 = part + ((size_t)r * EC) * NPAD + node;                 // a=0 (src)
  const ushort* p1 = part + (((size_t)NREL + r) * EC) * NPAD + node;       // a=1 (dst)
  int s0 = 0, s1 = 0;
#pragma unroll
  for (int c = 0; c < EC; ++c) {
    s0 += p0[(size_t)c * NPAD];
    s1 += p1[(size_t)c * NPAD];
  }
  cnt_in[i] = s1;
  rs_out[i] = rsqrtf((float)(s0 < 1 ? 1 : s0));
  rs_in3[i] = rsqrtf((float)(s1 < 1 ? 1 : s1)) * (1.f / 3.f);
}

// ---- two-level exclusive scan of cnt_in -> row_ptr ----
__global__ __launch_bounds__(256) void scan1(const int* __restrict__ cnt,
                                             int* __restrict__ excl, int* __restrict__ bsums) {
  int rb = blockIdx.x;
  int r = rb / NBLK, blk = rb % NBLK;
  int tid = (int)threadIdx.x;
  int v[4]; int sum = 0;
#pragma unroll
  for (int i = 0; i < 4; ++i) {
    int idx = blk * SCAN_BLK + tid * 4 + i;
    int c = (idx < NN) ? cnt[r * NN + idx] : 0;
    v[i] = sum; sum += c;
  }
  __shared__ int ts[256];
  ts[tid] = sum;
  __syncthreads();
  for (int off = 1; off < 256; off <<= 1) {
    int t = (tid >= off) ? ts[tid - off] : 0;
    __syncthreads();
    ts[tid] += t;
    __syncthreads();
  }
  int texcl = tid ? ts[tid - 1] : 0;
#pragma unroll
  for (int i = 0; i < 4; ++i) {
    int idx = blk * SCAN_BLK + tid * 4 + i;
    if (idx < NN) excl[r * NN + idx] = texcl + v[i];
  }
  if (tid == 255) bsums[rb] = ts[255];
}

__global__ __launch_bounds__(128) void scan2(int* __restrict__ bsums) {
  int r = blockIdx.x;
  int tid = (int)threadIdx.x;
  __shared__ int ts[128];
  ts[tid] = (tid < NBLK) ? bsums[r * NBLK + tid] : 0;
  __syncthreads();
  for (int off = 1; off < 128; off <<= 1) {
    int t = (tid >= off) ? ts[tid - off] : 0;
    __syncthreads();
    ts[tid] += t;
    __syncthreads();
  }
  if (tid < NBLK) bsums[r * NBLK + tid] = tid ? ts[tid - 1] : 0;
}

// fused: finalize row_ptr (+bsums) and emit per-chunk int cursor bases cb
__global__ void scan3_chunk(int* __restrict__ row_ptr, const int* __restrict__ bsums,
                            const ushort* __restrict__ part, int* __restrict__ cb) {
  int i = blockIdx.x * blockDim.x + threadIdx.x;
  if (i >= NREL * NN) return;
  int r = i / NN, node = i - r * NN, blk = node / SCAN_BLK;
  int base = row_ptr[i] + bsums[r * NBLK + blk];
  row_ptr[i] = base;
  const ushort* p1 = part + (((size_t)NREL + r) * EC) * NPAD + node;   // dst slice
  int run = base;
#pragma unroll
  for (int c = 0; c < EC; ++c) {
    cb[((size_t)r * EC + c) * NPAD + node] = run;
    run += p1[(size_t)c * NPAD];
  }
}

__global__ void make_pay(const int* __restrict__ src, const float* __restrict__ rs_out,
                         int2* __restrict__ pay) {
  int i = blockIdx.x * blockDim.x + threadIdx.x;
  if (i >= NREL * NE) return;
  int r = i / NE;
  int s = src[i];
  pay[i] = make_int2(s, __float_as_int(rs_out[r * NN + s]));
}

__global__ __launch_bounds__(256) void place_part(const int* __restrict__ dst,
                                                  const int2* __restrict__ pay,
                                                  const int* __restrict__ cb,
                                                  int2* __restrict__ ses) {
  int x = blockIdx.x & 7, q = blockIdx.x >> 3;
  int g = q % NRANGE;
  int rc = x + 8 * (q / NRANGE);
  if (rc >= NREL * EC) return;
  int r = rc / EC, c = rc % EC;
  __shared__ int cur[RANGE];
  const int* pc = cb + ((size_t)r * EC + c) * NPAD + (size_t)g * RANGE;
  for (int i = threadIdx.x; i < RANGE; i += 256) cur[i] = pc[i];
  __syncthreads();
  int lo = g * RANGE;
  const int4* d4 = (const int4*)(dst + (size_t)r * NE + (size_t)c * EPC);
  const int4* p4 = (const int4*)(pay + (size_t)r * NE + (size_t)c * EPC);
  int2* sesr = ses + (size_t)r * NE;
  for (int i = threadIdx.x; i < EPC / 4; i += 256) {
    int4 dv = d4[i];
    int4 pa = p4[2 * i], pb = p4[2 * i + 1];
    int t;
    t = dv.x - lo; if ((unsigned)t < RANGE) { int pos = atomicAdd(&cur[t], 1); sesr[pos] = make_int2(pa.x, pa.y); }
    t = dv.y - lo; if ((unsigned)t < RANGE) { int pos = atomicAdd(&cur[t], 1); sesr[pos] = make_int2(pa.z, pa.w); }
    t = dv.z - lo; if ((unsigned)t < RANGE) { int pos = atomicAdd(&cur[t], 1); sesr[pos] = make_int2(pb.x, pb.y); }
    t = dv.w - lo; if ((unsigned)t < RANGE) { int pos = atomicAdd(&cur[t], 1); sesr[pos] = make_int2(pb.z, pb.w); }
  }
}

// biases
__global__ void prep_small(const float* __restrict__ b1, const float* __restrict__ b2,
                           const float* __restrict__ bif, const float* __restrict__ bhf,
                           const float* __restrict__ bib, const float* __restrict__ bhb,
                           float* __restrict__ bbar1, float* __restrict__ bbar2,
                           float* __restrict__ bselw) {
  int t = (int)threadIdx.x;
  if (t < 128) {
    bbar1[t] = (b1[t] + b1[128 + t] + b1[256 + t]) * (1.f / 3.f);
  } else if (t < 256) {
    int j = t - 128;
    bbar2[j] = (b2[j] + b2[128 + j] + b2[256 + j]) * (1.f / 3.f);
  } else if (t < 640) {
    int m = t - 256;
    int g = m >> 7, j = m & 127, dir = j >> 6, jj = j & 63;
    int grow = (g == 0) ? jj : (g == 1) ? (128 + jj) : (192 + jj);
    bselw[m] = dir ? (bib[grow] + bhb[grow]) : (bif[grow] + bhf[grow]);
  }
}

// W[384][128] (k-major) -> split-bf16 transposed planes WT[n][k]
__global__ void wt_split(const float* __restrict__ W, ushort* __restrict__ th,
                         ushort* __restrict__ tl) {
  int i = blockIdx.x * blockDim.x + threadIdx.x;
  if (i >= 128 * 384) return;
  int n = i / 384, k = i % 384;
  float v = W[(size_t)k * 128 + n];
  unsigned h, l; split1(v, h, l);
  th[i] = (ushort)h; tl[i] = (ushort)l;
}

// lstm gate weights, packed+split: Wp[m][k], m = g*128 + dir*64 + jj
__global__ void pack_w_split(const float* __restrict__ Wf, const float* __restrict__ Wb,
                             ushort* __restrict__ ph, ushort* __restrict__ pl) {
  int i = blockIdx.x * blockDim.x + threadIdx.x;
  if (i >= 384 * 128) return;
  int m = i / 128, k = i % 128;
  int g = m >> 7, j = m & 127, dir = j >> 6, jj = j & 63;
  int grow = (g == 0) ? jj : (g == 1) ? (128 + jj) : (192 + jj);
  float v = (dir ? Wb : Wf)[(size_t)grow * 128 + k];
  unsigned h, l; split1(v, h, l);
  ph[i] = (ushort)h; pl[i] = (ushort)l;
}

// f32 [NN,128] -> f16 table
__global__ void cvt_f16(const float* __restrict__ in, ushort* __restrict__ o16) {
  int i = blockIdx.x * blockDim.x + threadIdx.x;
  if (i >= NN * (F / 4)) return;
  float4 v = ((const float4*)in)[i];
  __half2 a = __floats2half2_rn(v.x, v.y);
  __half2 b = __floats2half2_rn(v.z, v.w);
  ((uint2*)o16)[i] = make_uint2(*(unsigned*)&a, *(unsigned*)&b);
}

// quad-row gather: one wave per (node, relation); 16-edge batches; per load
// instruction QUARTER-waves own 4 different edges (uint4 = 16 B/lane, 4 rows
// x 256 B per instr) -> half the vmem instructions of the pair scheme.
// Padding lanes re-read the batch's row 0 (cache-hot) with scale 0.
__global__ __launch_bounds__(256) void gather3(
    const ushort* __restrict__ table, const int2* __restrict__ ses,
    const int* __restrict__ row_ptr, const int* __restrict__ cnt,
    const float* __restrict__ rs_in3, ushort* __restrict__ z16, int n0) {
  int wid = (int)threadIdx.x >> 6, lane = (int)threadIdx.x & 63;
  int gw = blockIdx.x * 4 + wid;
  int r = gw / CH;
  int n = n0 + (gw - r * CH);
  int base = r * NN + n;
  int beg = row_ptr[base], c = cnt[base];
  const int2* el = ses + (size_t)r * NE + beg;
  int qw = lane >> 4, cl = lane & 15;          // cl owns cols cl*8 .. cl*8+7
  const uint4* x4 = (const uint4*)table + cl;  // row stride = 16 uint4 (256 B)
  float acc[8] = {};

  int p = 0;
  while (p < c) {
    int rem = c - p; if (rem > 16) rem = 16;
    int2 es = make_int2(0, 0);
    if (lane < rem) es = el[p + lane];
    uint4 rw[4]; float scv[4];
#pragma unroll
    for (int j = 0; j < 4; ++j) {
      int e = 4 * j + qw;
      int idx = (e < rem) ? e : 0;
      int s = __shfl(es.x, idx);
      float sc = __int_as_float(__shfl(es.y, idx));
      if (e >= rem) sc = 0.f;
      if (4 * j < rem) {            // wave-uniform guard
        rw[j] = x4[(size_t)s * 16];
        scv[j] = sc;
      }
    }
#pragma unroll
    for (int j = 0; j < 4; ++j) {
      if (4 * j < rem) {
        float sc = scv[j];
        float2 f0 = __half22float2(*(__half2*)&rw[j].x);
        float2 f1 = __half22float2(*(__half2*)&rw[j].y);
        float2 f2 = __half22float2(*(__half2*)&rw[j].z);
        float2 f3 = __half22float2(*(__half2*)&rw[j].w);
        acc[0] = fmaf(f0.x, sc, acc[0]); acc[1] = fmaf(f0.y, sc, acc[1]);
        acc[2] = fmaf(f1.x, sc, acc[2]); acc[3] = fmaf(f1.y, sc, acc[3]);
        acc[4] = fmaf(f2.x, sc, acc[4]); acc[5] = fmaf(f2.y, sc, acc[5]);
        acc[6] = fmaf(f3.x, sc, acc[6]); acc[7] = fmaf(f3.y, sc, acc[7]);
      }
    }
    p += rem;
  }

#pragma unroll
  for (int q = 0; q < 8; ++q) {
    acc[q] += __shfl_xor(acc[q], 16);
    acc[q] += __shfl_xor(acc[q], 32);
  }
  if (qw == 0) {
    float ci = rs_in3[base];
    __half2 p0 = __floats2half2_rn(acc[0] * ci, acc[1] * ci);
    __half2 p1 = __floats2half2_rn(acc[2] * ci, acc[3] * ci);
    __half2 p2 = __floats2half2_rn(acc[4] * ci, acc[5] * ci);
    __half2 p3 = __floats2half2_rn(acc[6] * ci, acc[7] * ci);
    size_t zo = (size_t)(n - n0) * 384 + r * 128 + cl * 8;
    *(uint4*)(z16 + zo) = make_uint4(*(unsigned*)&p0, *(unsigned*)&p1,
                                     *(unsigned*)&p2, *(unsigned*)&p3);
  }
}

// f16x8 -> split bf16 hi/lo uint4s
__device__ __forceinline__ void cvt_split8(uint4 v, uint4& hv, uint4& lv) {
  float f[8];
  *(float2*)&f[0] = __half22float2(*(__half2*)&v.x);
  *(float2*)&f[2] = __half22float2(*(__half2*)&v.y);
  *(float2*)&f[4] = __half22float2(*(__half2*)&v.z);
  *(float2*)&f[6] = __half22float2(*(__half2*)&v.w);
  unsigned h[8], l[8];
#pragma unroll
  for (int q = 0; q < 8; ++q) split1(f[q], h[q], l[q]);
  hv = make_uint4(h[0] | (h[1] << 16), h[2] | (h[3] << 16),
                  h[4] | (h[5] << 16), h[6] | (h[7] << 16));
  lv = make_uint4(l[0] | (l[1] << 16), l[2] | (l[3] << 16),
                  l[4] | (l[5] << 16), l[6] | (l[7] << 16));
}

// layer-1 GEMM: h1 = relu(Z(f16)[row,0:384] @ WT^T + bias), f16 out. 256 thr.
__global__ __launch_bounds__(256) void gemm_mfma1(
    const ushort* __restrict__ z16,
    const ushort* __restrict__ wth, const ushort* __restrict__ wtl,
    const float* __restrict__ bias, ushort* __restrict__ Hout, int n0) {
  __shared__ ushort Ash[64 * 32], Asl[64 * 32], Bsh[128 * 32], Bsl[128 * 32];
  const int row0 = blockIdx.x * 64;
  const int t = (int)threadIdx.x;
  const int wn = t >> 6, l = t & 63, lr = l & 15, lk = l >> 4;
  f32x4 acc[4][2];
#pragma unroll
  for (int a = 0; a < 4; ++a)
#pragma unroll
    for (int b = 0; b < 2; ++b) acc[a][b] = (f32x4){0.f, 0.f, 0.f, 0.f};

  for (int kt = 0; kt < 12; ++kt) {
    __syncthreads();
    {
      int rr = t >> 2, slot = t & 3;
      uint4 v = make_uint4(0, 0, 0, 0);
      if (row0 + rr < CH)
        v = *(const uint4*)(z16 + (size_t)(row0 + rr) * 384 + kt * 32 + slot * 8);
      uint4 hv, lv; cvt_split8(v, hv, lv);
      *(uint4*)&Ash[swz(rr, slot)] = hv;
      *(uint4*)&Asl[swz(rr, slot)] = lv;
    }
#pragma unroll
    for (int i = 0; i < 2; ++i) {
      int s = i * 256 + t;
      int nn_ = s >> 2, slot = s & 3;
      size_t go = (size_t)nn_ * 384 + kt * 32 + slot * 8;
      *(uint4*)&Bsh[swz(nn_, slot)] = *(const uint4*)(wth + go);
      *(uint4*)&Bsl[swz(nn_, slot)] = *(const uint4*)(wtl + go);
    }
    __syncthreads();
    bf16x8 ah[4], al[4], bh[2], bl[2];
#pragma unroll
    for (int mf = 0; mf < 4; ++mf) {
      int off = swz(mf * 16 + lr, lk);
      ah[mf] = *(const bf16x8*)&Ash[off];
      al[mf] = *(const bf16x8*)&Asl[off];
    }
#pragma unroll
    for (int f = 0; f < 2; ++f) {
      int off = swz(wn * 32 + f * 16 + lr, lk);
      bh[f] = *(const bf16x8*)&Bsh[off];
      bl[f] = *(const bf16x8*)&Bsl[off];
    }
#pragma unroll
    for (int mf = 0; mf < 4; ++mf)
#pragma unroll
      for (int f = 0; f < 2; ++f) {
        acc[mf][f] = __builtin_amdgcn_mfma_f32_16x16x32_bf16(ah[mf], bh[f], acc[mf][f], 0, 0, 0);
        acc[mf][f] = __builtin_amdgcn_mfma_f32_16x16x32_bf16(ah[mf], bl[f], acc[mf][f], 0, 0, 0);
        acc[mf][f] = __builtin_amdgcn_mfma_f32_16x16x32_bf16(al[mf], bh[f], acc[mf][f], 0, 0, 0);
      }
  }
#pragma unroll
  for (int mf = 0; mf < 4; ++mf)
#pragma unroll
    for (int f = 0; f < 2; ++f) {
      int col = wn * 32 + f * 16 + lr;
      float bv = bias[col];
#pragma unroll
      for (int reg = 0; reg < 4; ++reg) {
        int row = row0 + mf * 16 + lk * 4 + reg;
        if (row < CH) {
          float v = fmaxf(acc[mf][f][reg] + bv, 0.f);
          __half hv = __float2half_rn(v);
          Hout[(size_t)(n0 + row) * 128 + col] = *(ushort*)&hv;
        }
      }
    }
}

// fused layer-2 GEMM + BiLSTM. 512 thr, BM=64.
__global__ __launch_bounds__(512) void gemm2_lstm(
    const ushort* __restrict__ z16,
    const ushort* __restrict__ wth, const ushort* __restrict__ wtl,
    const ushort* __restrict__ wph, const ushort* __restrict__ wpl,
    const float* __restrict__ bbar2, const float* __restrict__ bselw,
    float* __restrict__ out, int n0) {
  __shared__ ushort lds[40960];   // 80 KB
  ushort* A1h = lds;
  ushort* A1l = lds + 2048;
  ushort* B1h = lds + 4096;
  ushort* B1l = lds + 8192;
  ushort* A2h = lds;
  ushort* A2l = lds + 8192;
  ushort* B3h = lds + 16384;
  ushort* B3l = lds + 28672;

  const int row0 = blockIdx.x * 64;
  const int t = (int)threadIdx.x;
  const int wid = t >> 6, l = t & 63, lr = l & 15, lk = l >> 4;

  f32x4 acc1[4];
#pragma unroll
  for (int a = 0; a < 4; ++a) acc1[a] = (f32x4){0.f, 0.f, 0.f, 0.f};

  for (int kt = 0; kt < 12; ++kt) {
    __syncthreads();
    if (t < 256) {
      int rr = t >> 2, slot = t & 3;
      uint4 v = make_uint4(0, 0, 0, 0);
      if (row0 + rr < CH)
        v = *(const uint4*)(z16 + (size_t)(row0 + rr) * 384 + kt * 32 + slot * 8);
      uint4 hv, lv; cvt_split8(v, hv, lv);
      *(uint4*)&A1h[swz(rr, slot)] = hv;
      *(uint4*)&A1l[swz(rr, slot)] = lv;
    }
    {
      int nn_ = t >> 2, slot = t & 3;
      size_t go = (size_t)nn_ * 384 + kt * 32 + slot * 8;
      *(uint4*)&B1h[swz(nn_, slot)] = *(const uint4*)(wth + go);
      *(uint4*)&B1l[swz(nn_, slot)] = *(const uint4*)(wtl + go);
    }
    __syncthreads();
    bf16x8 ah[4], al[4];
#pragma unroll
    for (int mf = 0; mf < 4; ++mf) {
      int off = swz(mf * 16 + lr, lk);
      ah[mf] = *(const bf16x8*)&A1h[off];
      al[mf] = *(const bf16x8*)&A1l[off];
    }
    int offb = swz(wid * 16 + lr, lk);
    bf16x8 bh = *(const bf16x8*)&B1h[offb];
    bf16x8 bl = *(const bf16x8*)&B1l[offb];
#pragma unroll
    for (int mf = 0; mf < 4; ++mf) {
      acc1[mf] = __builtin_amdgcn_mfma_f32_16x16x32_bf16(ah[mf], bh, acc1[mf], 0, 0, 0);
      acc1[mf] = __builtin_amdgcn_mfma_f32_16x16x32_bf16(ah[mf], bl, acc1[mf], 0, 0, 0);
      acc1[mf] = __builtin_amdgcn_mfma_f32_16x16x32_bf16(al[mf], bh, acc1[mf], 0, 0, 0);
    }
  }

  __syncthreads();
  {
    int colc = wid * 16 + lr;
    float bb = bbar2[colc];
#pragma unroll
    for (int mf = 0; mf < 4; ++mf)
#pragma unroll
      for (int reg = 0; reg < 4; ++reg) {
        int rowc = mf * 16 + lk * 4 + reg;
        float v = acc1[mf][reg] + bb;
        unsigned h, lo2; split1(v, h, lo2);
        int sl2 = (colc >> 3) ^ (rowc & 7);
        int addr = rowc * 128 + (sl2 << 3) + (colc & 7);
        A2h[addr] = (ushort)h;
        A2l[addr] = (ushort)lo2;
      }
  }
  __syncthreads();

  const int wm = wid >> 2, wn3 = wid & 3;
  f32x4 acc3[2][6];
#pragma unroll
  for (int a = 0; a < 2; ++a)
#pragma unroll
    for (int b = 0; b < 6; ++b) acc3[a][b] = (f32x4){0.f, 0.f, 0.f, 0.f};

  for (int kt = 0; kt < 4; ++kt) {
    if (kt) __syncthreads();
#pragma unroll
    for (int i = 0; i < 3; ++i) {
      int s = i * 512 + t;
      int m = s >> 2, slot = s & 3;
      size_t go = (size_t)m * 128 + kt * 32 + slot * 8;
      *(uint4*)&B3h[swz(m, slot)] = *(const uint4*)(wph + go);
      *(uint4*)&B3l[swz(m, slot)] = *(const uint4*)(wpl + go);
    }
    __syncthreads();
    bf16x8 ah2[2], al2[2];
#pragma unroll
    for (int mf = 0; mf < 2; ++mf) {
      int row = wm * 32 + mf * 16 + lr;
      int kslot = kt * 4 + lk;
      int sl2 = kslot ^ (row & 7);
      int addr = row * 128 + (sl2 << 3);
      ah2[mf] = *(const bf16x8*)&A2h[addr];
      al2[mf] = *(const bf16x8*)&A2l[addr];
    }
#pragma unroll
    for (int tt = 0; tt < 6; ++tt) {
      int m = (wn3 + 4 * tt) * 16 + lr;
      int off = swz(m, lk);
      bf16x8 bh = *(const bf16x8*)&B3h[off];
      bf16x8 bl = *(const bf16x8*)&B3l[off];
#pragma unroll
      for (int mf = 0; mf < 2; ++mf) {
        acc3[mf][tt] = __builtin_amdgcn_mfma_f32_16x16x32_bf16(ah2[mf], bh, acc3[mf][tt], 0, 0, 0);
        acc3[mf][tt] = __builtin_amdgcn_mfma_f32_16x16x32_bf16(ah2[mf], bl, acc3[mf][tt], 0, 0, 0);
        acc3[mf][tt] = __builtin_amdgcn_mfma_f32_16x16x32_bf16(al2[mf], bh, acc3[mf][tt], 0, 0, 0);
      }
    }
  }

  int j0 = wn3 * 16 + lr, j1 = j0 + 64;
  float bi0 = bselw[j0], bg0 = bselw[128 + j0], bo0 = bselw[256 + j0];
  float bi1 = bselw[j1], bg1 = bselw[128 + j1], bo1 = bselw[256 + j1];
#pragma unroll
  for (int mf = 0; mf < 2; ++mf)
#pragma unroll
    for (int reg = 0; reg < 4; ++reg) {
      int grow = wm * 32 + mf * 16 + lk * 4 + reg;
      if (row0 + grow < CH) {
        size_t orow = (size_t)(n0 + row0 + grow) * 128;
        float iv0 = acc3[mf][0][reg] + bi0, gv0 = acc3[mf][2][reg] + bg0,
              ov0 = acc3[mf][4][reg] + bo0;
        float c0 = sigm(iv0) * tanhf(gv0);
        out[orow + j0] = sigm(ov0) * tanhf(c0);
        float iv1 = acc3[mf][1][reg] + bi1, gv1 = acc3[mf][3][reg] + bg1,
              ov1 = acc3[mf][5][reg] + bo1;
        float c1 = sigm(iv1) * tanhf(gv1);
        out[orow + j1] = sigm(ov1) * tanhf(c1);
      }
    }
}

extern "C" void kernel_launch(void* const* d_in, const int* in_sizes, int n_in,
                              void* d_out, int out_size, void* d_ws, size_t ws_size,
                              hipStream_t stream) {
  const float* x = (const float*)d_in[0];
  const int* src = (const int*)d_in[1];
  const int* dst = (const int*)d_in[2];
  const float* W1 = (const float*)d_in[3];
  const float* b1 = (const float*)d_in[4];
  const float* W2 = (const float*)d_in[5];
  const float* b2 = (const float*)d_in[6];
  const float* Wih_f = (const float*)d_in[7];
  const float* bih_f = (const float*)d_in[9];
  const float* bhh_f = (const float*)d_in[10];
  const float* Wih_b = (const float*)d_in[11];
  const float* bih_b = (const float*)d_in[13];
  const float* bhh_b = (const float*)d_in[14];
  float* out = (float*)d_out;

  // workspace carve-up (~90 MB)
  char* wp = (char*)d_ws;
  float* rs_out = (float*)wp;          wp += (size_t)3 * NN * 4;
  float* rs_in3 = (float*)wp;          wp += (size_t)3 * NN * 4;
  int* cnt_in = (int*)wp;              wp += (size_t)3 * NN * 4;
  int* row_ptr = (int*)wp;             wp += (size_t)3 * NN * 4;
  int* bsums = (int*)wp;               wp += 4096;
  int2* ses = (int2*)wp;               wp += (size_t)3 * NE * 8;
  ushort* wt1h = (ushort*)wp;          wp += (size_t)128 * 384 * 2;
  ushort* wt1l = (ushort*)wp;          wp += (size_t)128 * 384 * 2;
  ushort* wt2h = (ushort*)wp;          wp += (size_t)128 * 384 * 2;
  ushort* wt2l = (ushort*)wp;          wp += (size_t)128 * 384 * 2;
  ushort* wph = (ushort*)wp;           wp += (size_t)384 * 128 * 2;
  ushort* wpl = (ushort*)wp;           wp += (size_t)384 * 128 * 2;
  float* bbar1 = (float*)wp;           wp += 512;
  float* bbar2 = (float*)wp;           wp += 512;
  float* bselw = (float*)wp;           wp += 2048;
  ushort* z16 = (ushort*)wp;           wp += (size_t)CH * 384 * 2;   // 19.2 MB
  ushort* x16 = (ushort*)wp;           wp += (size_t)NN * F * 2;     // 25.6 MB
  ushort* h116 = (ushort*)wp;          wp += (size_t)NN * F * 2;     // 25.6 MB

  // CSR-build aliases over the z16/x16/h116 region (70.4 MB), dead before use:
  // part (u16): 27.52 MB @ z16;  cb (int): 27.52 MB @ z16+28MB;
  // pay: 12 MB @ h116+12MB (region offset 56.8 MB, disjoint from cb's end 55.5 MB).
  ushort* part = (ushort*)z16;
  int* cb = (int*)((char*)z16 + ((size_t)28 << 20));
  int2* pay = (int2*)((char*)h116 + ((size_t)12 << 20));

  // CSR build — zero global atomics, XCD-grouped L2 reuse, u16 partials
  hist_part<<<2 * NREL * EC * NRANGE, 256, 0, stream>>>(src, dst, part);
  reduce_rs<<<(NREL * NN + 255) / 256, 256, 0, stream>>>(part, cnt_in, rs_out, rs_in3);
  scan1<<<NREL * NBLK, 256, 0, stream>>>(cnt_in, row_ptr, bsums);
  scan2<<<NREL, 128, 0, stream>>>(bsums);
  scan3_chunk<<<(NREL * NN + 255) / 256, 256, 0, stream>>>(row_ptr, bsums, part, cb);
  make_pay<<<(NREL * NE + 255) / 256, 256, 0, stream>>>(src, rs_out, pay);
  place_part<<<8 * ((NREL * EC + 7) / 8) * NRANGE, 256, 0, stream>>>(dst, pay, cb, ses);

  // weight prep
  prep_small<<<1, 640, 0, stream>>>(b1, b2, bih_f, bhh_f, bih_b, bhh_b, bbar1, bbar2, bselw);
  wt_split<<<192, 256, 0, stream>>>(W1, wt1h, wt1l);
  wt_split<<<192, 256, 0, stream>>>(W2, wt2h, wt2l);
  pack_w_split<<<192, 256, 0, stream>>>(Wih_f, Wih_b, wph, wpl);
  cvt_f16<<<(NN * 32 + 255) / 256, 256, 0, stream>>>(x, x16);

  // layer 1: x16 -> h116 (relu, f16)
  for (int c = 0; c < NCH; ++c) {
    gather3<<<3 * CH / 4, 256, 0, stream>>>(x16, ses, row_ptr, cnt_in, rs_in3, z16, c * CH);
    gemm_mfma1<<<(CH + 63) / 64, 256, 0, stream>>>(z16, wt1h, wt1l, bbar1, h116, c * CH);
  }
  // layer 2 + fused BiLSTM: h116 -> d_out
  for (int c = 0; c < NCH; ++c) {
    gather3<<<3 * CH / 4, 256, 0, stream>>>(h116, ses, row_ptr, cnt_in, rs_in3, z16, c * CH);
    gemm2_lstm<<<(CH + 63) / 64, 512, 0, stream>>>(z16, wt2h, wt2l, wph, wpl,
                                                   bbar2, bselw, out, c * CH);
  }
}

// Round 12
// 459.498 us; speedup vs baseline: 3.1178x; 1.1177x over previous
//
#include <hip/hip_runtime.h>
#include <hip/hip_fp16.h>
#include <math.h>

#define NN 100000
#define NE 500000
#define NREL 3
#define F 128
#define SCAN_BLK 1024
#define NBLK ((NN + SCAN_BLK - 1) / SCAN_BLK)   // 98
#define CH 50000
#define NCH 2

// CSR build partitioning
#define RANGE 16384
#define NRANGE 7            // 7*16384 >= NN
#define NPAD (NRANGE * RANGE)
#define EC 20
#define EPC (NE / EC)       // 25000

typedef __attribute__((ext_vector_type(8))) short bf16x8;
typedef __attribute__((ext_vector_type(4))) float f32x4;

__device__ __forceinline__ float sigm(float x) { return 1.f / (1.f + __expf(-x)); }

__device__ __forceinline__ unsigned bf16rne(float x) {
  unsigned u = __float_as_uint(x);
  return (u + 0x7FFFu + ((u >> 16) & 1u)) >> 16;
}
__device__ __forceinline__ void split1(float x, unsigned& h, unsigned& l) {
  h = bf16rne(x);
  float hf = __uint_as_float(h << 16);
  l = bf16rne(x - hf);
}

// LDS swizzle (row stride 32 ushorts): 2-way max on ds_read_b128
__device__ __forceinline__ int swz(int row, int slot) {
  return row * 32 + ((slot ^ ((row >> 1) & 3)) << 3);
}

// ---- atomic-free histogram, u16-PACKED LDS (32 KB -> ~2x occupancy).
// one block owns (array, rel, chunk, range); XCD-grouped decode.
// per-chunk per-node count <= EPC=25000 < 65536 -> low half never carries.
__global__ __launch_bounds__(256) void hist_part(const int* __restrict__ src,
                                                 const int* __restrict__ dst,
                                                 ushort* __restrict__ part) {
  int x = blockIdx.x & 7, q = blockIdx.x >> 3;
  int g = q % NRANGE;
  int rc2 = x + 8 * (q / NRANGE);
  int a = rc2 / (NREL * EC);
  int rcl = rc2 % (NREL * EC);
  int r = rcl / EC, c = rcl % EC;
  __shared__ unsigned h32[RANGE / 2];   // 32 KB
  for (int i = threadIdx.x; i < RANGE / 2; i += 256) h32[i] = 0;
  __syncthreads();
  const int* idx = (a ? dst : src) + (size_t)r * NE + (size_t)c * EPC;
  const int4* v4 = (const int4*)idx;
  int lo = g * RANGE;
  for (int i = threadIdx.x; i < EPC / 4; i += 256) {
    int4 v = v4[i];
    int t;
    t = v.x - lo; if ((unsigned)t < RANGE) atomicAdd(&h32[t >> 1], 1u << ((t & 1) * 16));
    t = v.y - lo; if ((unsigned)t < RANGE) atomicAdd(&h32[t >> 1], 1u << ((t & 1) * 16));
    t = v.z - lo; if ((unsigned)t < RANGE) atomicAdd(&h32[t >> 1], 1u << ((t & 1) * 16));
    t = v.w - lo; if ((unsigned)t < RANGE) atomicAdd(&h32[t >> 1], 1u << ((t & 1) * 16));
  }
  __syncthreads();
  // packed u32 layout == two consecutive u16 counts: copy directly
  unsigned* op = (unsigned*)(part + (((size_t)a * NREL + r) * EC + c) * NPAD + (size_t)g * RANGE);
  for (int i = threadIdx.x; i < RANGE / 2; i += 256) op[i] = h32[i];
}

// fused: cnt_in + both rsqrt normalizers from u16 partials
__global__ void reduce_rs(const ushort* __restrict__ part, int* __restrict__ cnt_in,
                          float* __restrict__ rs_out, float* __restrict__ rs_in3) {
  int i = blockIdx.x * blockDim.x + threadIdx.x;
  if (i >= NREL * NN) return;
  int r = i / NN, node = i - r * NN;
  const ushort* p0 = part + ((size_t)r * EC) * NPAD + node;
  const ushort* p1 = part + (((size_t)NREL + r) * EC) * NPAD + node;
  int s0 = 0, s1 = 0;
#pragma unroll
  for (int c = 0; c < EC; ++c) {
    s0 += p0[(size_t)c * NPAD];
    s1 += p1[(size_t)c * NPAD];
  }
  cnt_in[i] = s1;
  rs_out[i] = rsqrtf((float)(s0 < 1 ? 1 : s0));
  rs_in3[i] = rsqrtf((float)(s1 < 1 ? 1 : s1)) * (1.f / 3.f);
}

// ---- two-level exclusive scan of cnt_in -> row_ptr ----
__global__ __launch_bounds__(256) void scan1(const int* __restrict__ cnt,
                                             int* __restrict__ excl, int* __restrict__ bsums) {
  int rb = blockIdx.x;
  int r = rb / NBLK, blk = rb % NBLK;
  int tid = (int)threadIdx.x;
  int v[4]; int sum = 0;
#pragma unroll
  for (int i = 0; i < 4; ++i) {
    int idx = blk * SCAN_BLK + tid * 4 + i;
    int c = (idx < NN) ? cnt[r * NN + idx] : 0;
    v[i] = sum; sum += c;
  }
  __shared__ int ts[256];
  ts[tid] = sum;
  __syncthreads();
  for (int off = 1; off < 256; off <<= 1) {
    int t = (tid >= off) ? ts[tid - off] : 0;
    __syncthreads();
    ts[tid] += t;
    __syncthreads();
  }
  int texcl = tid ? ts[tid - 1] : 0;
#pragma unroll
  for (int i = 0; i < 4; ++i) {
    int idx = blk * SCAN_BLK + tid * 4 + i;
    if (idx < NN) excl[r * NN + idx] = texcl + v[i];
  }
  if (tid == 255) bsums[rb] = ts[255];
}

__global__ __launch_bounds__(128) void scan2(int* __restrict__ bsums) {
  int r = blockIdx.x;
  int tid = (int)threadIdx.x;
  __shared__ int ts[128];
  ts[tid] = (tid < NBLK) ? bsums[r * NBLK + tid] : 0;
  __syncthreads();
  for (int off = 1; off < 128; off <<= 1) {
    int t = (tid >= off) ? ts[tid - off] : 0;
    __syncthreads();
    ts[tid] += t;
    __syncthreads();
  }
  if (tid < NBLK) bsums[r * NBLK + tid] = tid ? ts[tid - 1] : 0;
}

// fused: finalize row_ptr and emit per-chunk int cursor bases cb
__global__ void scan3_chunk(int* __restrict__ row_ptr, const int* __restrict__ bsums,
                            const ushort* __restrict__ part, int* __restrict__ cb) {
  int i = blockIdx.x * blockDim.x + threadIdx.x;
  if (i >= NREL * NN) return;
  int r = i / NN, node = i - r * NN, blk = node / SCAN_BLK;
  int base = row_ptr[i] + bsums[r * NBLK + blk];
  row_ptr[i] = base;
  const ushort* p1 = part + (((size_t)NREL + r) * EC) * NPAD + node;
  int run = base;
#pragma unroll
  for (int c = 0; c < EC; ++c) {
    cb[((size_t)r * EC + c) * NPAD + node] = run;
    run += p1[(size_t)c * NPAD];
  }
}

__global__ void make_pay(const int* __restrict__ src, const float* __restrict__ rs_out,
                         int2* __restrict__ pay) {
  int i = blockIdx.x * blockDim.x + threadIdx.x;
  if (i >= NREL * NE) return;
  int r = i / NE;
  int s = src[i];
  pay[i] = make_int2(s, __float_as_int(rs_out[r * NN + s]));
}

__global__ __launch_bounds__(256) void place_part(const int* __restrict__ dst,
                                                  const int2* __restrict__ pay,
                                                  const int* __restrict__ cb,
                                                  int2* __restrict__ ses) {
  int x = blockIdx.x & 7, q = blockIdx.x >> 3;
  int g = q % NRANGE;
  int rc = x + 8 * (q / NRANGE);
  if (rc >= NREL * EC) return;
  int r = rc / EC, c = rc % EC;
  __shared__ int cur[RANGE];
  const int* pc = cb + ((size_t)r * EC + c) * NPAD + (size_t)g * RANGE;
  for (int i = threadIdx.x; i < RANGE; i += 256) cur[i] = pc[i];
  __syncthreads();
  int lo = g * RANGE;
  const int4* d4 = (const int4*)(dst + (size_t)r * NE + (size_t)c * EPC);
  const int4* p4 = (const int4*)(pay + (size_t)r * NE + (size_t)c * EPC);
  int2* sesr = ses + (size_t)r * NE;
  for (int i = threadIdx.x; i < EPC / 4; i += 256) {
    int4 dv = d4[i];
    int4 pa = p4[2 * i], pb = p4[2 * i + 1];
    int t;
    t = dv.x - lo; if ((unsigned)t < RANGE) { int pos = atomicAdd(&cur[t], 1); sesr[pos] = make_int2(pa.x, pa.y); }
    t = dv.y - lo; if ((unsigned)t < RANGE) { int pos = atomicAdd(&cur[t], 1); sesr[pos] = make_int2(pa.z, pa.w); }
    t = dv.z - lo; if ((unsigned)t < RANGE) { int pos = atomicAdd(&cur[t], 1); sesr[pos] = make_int2(pb.x, pb.y); }
    t = dv.w - lo; if ((unsigned)t < RANGE) { int pos = atomicAdd(&cur[t], 1); sesr[pos] = make_int2(pb.z, pb.w); }
  }
}

// biases
__global__ void prep_small(const float* __restrict__ b1, const float* __restrict__ b2,
                           const float* __restrict__ bif, const float* __restrict__ bhf,
                           const float* __restrict__ bib, const float* __restrict__ bhb,
                           float* __restrict__ bbar1, float* __restrict__ bbar2,
                           float* __restrict__ bselw) {
  int t = (int)threadIdx.x;
  if (t < 128) {
    bbar1[t] = (b1[t] + b1[128 + t] + b1[256 + t]) * (1.f / 3.f);
  } else if (t < 256) {
    int j = t - 128;
    bbar2[j] = (b2[j] + b2[128 + j] + b2[256 + j]) * (1.f / 3.f);
  } else if (t < 640) {
    int m = t - 256;
    int g = m >> 7, j = m & 127, dir = j >> 6, jj = j & 63;
    int grow = (g == 0) ? jj : (g == 1) ? (128 + jj) : (192 + jj);
    bselw[m] = dir ? (bib[grow] + bhb[grow]) : (bif[grow] + bhf[grow]);
  }
}

// W[384][128] (k-major) -> split-bf16 transposed planes WT[n][k]
__global__ void wt_split(const float* __restrict__ W, ushort* __restrict__ th,
                         ushort* __restrict__ tl) {
  int i = blockIdx.x * blockDim.x + threadIdx.x;
  if (i >= 128 * 384) return;
  int n = i / 384, k = i % 384;
  float v = W[(size_t)k * 128 + n];
  unsigned h, l; split1(v, h, l);
  th[i] = (ushort)h; tl[i] = (ushort)l;
}

// lstm gate weights, packed+split: Wp[m][k], m = g*128 + dir*64 + jj
__global__ void pack_w_split(const float* __restrict__ Wf, const float* __restrict__ Wb,
                             ushort* __restrict__ ph, ushort* __restrict__ pl) {
  int i = blockIdx.x * blockDim.x + threadIdx.x;
  if (i >= 384 * 128) return;
  int m = i / 128, k = i % 128;
  int g = m >> 7, j = m & 127, dir = j >> 6, jj = j & 63;
  int grow = (g == 0) ? jj : (g == 1) ? (128 + jj) : (192 + jj);
  float v = (dir ? Wb : Wf)[(size_t)grow * 128 + k];
  unsigned h, l; split1(v, h, l);
  ph[i] = (ushort)h; pl[i] = (ushort)l;
}

// f32 [NN,128] -> f16 table
__global__ void cvt_f16(const float* __restrict__ in, ushort* __restrict__ o16) {
  int i = blockIdx.x * blockDim.x + threadIdx.x;
  if (i >= NN * (F / 4)) return;
  float4 v = ((const float4*)in)[i];
  __half2 a = __floats2half2_rn(v.x, v.y);
  __half2 b = __floats2half2_rn(v.z, v.w);
  ((uint2*)o16)[i] = make_uint2(*(unsigned*)&a, *(unsigned*)&b);
}

// quad-row gather: one wave per (node, relation); 16-edge batches; per load
// instruction QUARTER-waves own 4 different edges (uint4 = 16 B/lane).
__global__ __launch_bounds__(256) void gather3(
    const ushort* __restrict__ table, const int2* __restrict__ ses,
    const int* __restrict__ row_ptr, const int* __restrict__ cnt,
    const float* __restrict__ rs_in3, ushort* __restrict__ z16, int n0) {
  int wid = (int)threadIdx.x >> 6, lane = (int)threadIdx.x & 63;
  int gw = blockIdx.x * 4 + wid;
  int r = gw / CH;
  int n = n0 + (gw - r * CH);
  int base = r * NN + n;
  int beg = row_ptr[base], c = cnt[base];
  const int2* el = ses + (size_t)r * NE + beg;
  int qw = lane >> 4, cl = lane & 15;          // cl owns cols cl*8 .. cl*8+7
  const uint4* x4 = (const uint4*)table + cl;  // row stride = 16 uint4 (256 B)
  float acc[8] = {};

  int p = 0;
  while (p < c) {
    int rem = c - p; if (rem > 16) rem = 16;
    int2 es = make_int2(0, 0);
    if (lane < rem) es = el[p + lane];
    uint4 rw[4]; float scv[4];
#pragma unroll
    for (int j = 0; j < 4; ++j) {
      int e = 4 * j + qw;
      int idx = (e < rem) ? e : 0;
      int s = __shfl(es.x, idx);
      float sc = __int_as_float(__shfl(es.y, idx));
      if (e >= rem) sc = 0.f;
      if (4 * j < rem) {            // wave-uniform guard
        rw[j] = x4[(size_t)s * 16];
        scv[j] = sc;
      }
    }
#pragma unroll
    for (int j = 0; j < 4; ++j) {
      if (4 * j < rem) {
        float sc = scv[j];
        float2 f0 = __half22float2(*(__half2*)&rw[j].x);
        float2 f1 = __half22float2(*(__half2*)&rw[j].y);
        float2 f2 = __half22float2(*(__half2*)&rw[j].z);
        float2 f3 = __half22float2(*(__half2*)&rw[j].w);
        acc[0] = fmaf(f0.x, sc, acc[0]); acc[1] = fmaf(f0.y, sc, acc[1]);
        acc[2] = fmaf(f1.x, sc, acc[2]); acc[3] = fmaf(f1.y, sc, acc[3]);
        acc[4] = fmaf(f2.x, sc, acc[4]); acc[5] = fmaf(f2.y, sc, acc[5]);
        acc[6] = fmaf(f3.x, sc, acc[6]); acc[7] = fmaf(f3.y, sc, acc[7]);
      }
    }
    p += rem;
  }

#pragma unroll
  for (int q = 0; q < 8; ++q) {
    acc[q] += __shfl_xor(acc[q], 16);
    acc[q] += __shfl_xor(acc[q], 32);
  }
  if (qw == 0) {
    float ci = rs_in3[base];
    __half2 p0 = __floats2half2_rn(acc[0] * ci, acc[1] * ci);
    __half2 p1 = __floats2half2_rn(acc[2] * ci, acc[3] * ci);
    __half2 p2 = __floats2half2_rn(acc[4] * ci, acc[5] * ci);
    __half2 p3 = __floats2half2_rn(acc[6] * ci, acc[7] * ci);
    size_t zo = (size_t)(n - n0) * 384 + r * 128 + cl * 8;
    *(uint4*)(z16 + zo) = make_uint4(*(unsigned*)&p0, *(unsigned*)&p1,
                                     *(unsigned*)&p2, *(unsigned*)&p3);
  }
}

// f16x8 -> split bf16 hi/lo uint4s
__device__ __forceinline__ void cvt_split8(uint4 v, uint4& hv, uint4& lv) {
  float f[8];
  *(float2*)&f[0] = __half22float2(*(__half2*)&v.x);
  *(float2*)&f[2] = __half22float2(*(__half2*)&v.y);
  *(float2*)&f[4] = __half22float2(*(__half2*)&v.z);
  *(float2*)&f[6] = __half22float2(*(__half2*)&v.w);
  unsigned h[8], l[8];
#pragma unroll
  for (int q = 0; q < 8; ++q) split1(f[q], h[q], l[q]);
  hv = make_uint4(h[0] | (h[1] << 16), h[2] | (h[3] << 16),
                  h[4] | (h[5] << 16), h[6] | (h[7] << 16));
  lv = make_uint4(l[0] | (l[1] << 16), l[2] | (l[3] << 16),
                  l[4] | (l[5] << 16), l[6] | (l[7] << 16));
}

// layer-1 GEMM: h1 = relu(Z(f16)[row,0:384] @ WT^T + bias), f16 out. 256 thr.
__global__ __launch_bounds__(256) void gemm_mfma1(
    const ushort* __restrict__ z16,
    const ushort* __restrict__ wth, const ushort* __restrict__ wtl,
    const float* __restrict__ bias, ushort* __restrict__ Hout, int n0) {
  __shared__ ushort Ash[64 * 32], Asl[64 * 32], Bsh[128 * 32], Bsl[128 * 32];
  const int row0 = blockIdx.x * 64;
  const int t = (int)threadIdx.x;
  const int wn = t >> 6, l = t & 63, lr = l & 15, lk = l >> 4;
  f32x4 acc[4][2];
#pragma unroll
  for (int a = 0; a < 4; ++a)
#pragma unroll
    for (int b = 0; b < 2; ++b) acc[a][b] = (f32x4){0.f, 0.f, 0.f, 0.f};

  for (int kt = 0; kt < 12; ++kt) {
    __syncthreads();
    {
      int rr = t >> 2, slot = t & 3;
      uint4 v = make_uint4(0, 0, 0, 0);
      if (row0 + rr < CH)
        v = *(const uint4*)(z16 + (size_t)(row0 + rr) * 384 + kt * 32 + slot * 8);
      uint4 hv, lv; cvt_split8(v, hv, lv);
      *(uint4*)&Ash[swz(rr, slot)] = hv;
      *(uint4*)&Asl[swz(rr, slot)] = lv;
    }
#pragma unroll
    for (int i = 0; i < 2; ++i) {
      int s = i * 256 + t;
      int nn_ = s >> 2, slot = s & 3;
      size_t go = (size_t)nn_ * 384 + kt * 32 + slot * 8;
      *(uint4*)&Bsh[swz(nn_, slot)] = *(const uint4*)(wth + go);
      *(uint4*)&Bsl[swz(nn_, slot)] = *(const uint4*)(wtl + go);
    }
    __syncthreads();
    bf16x8 ah[4], al[4], bh[2], bl[2];
#pragma unroll
    for (int mf = 0; mf < 4; ++mf) {
      int off = swz(mf * 16 + lr, lk);
      ah[mf] = *(const bf16x8*)&Ash[off];
      al[mf] = *(const bf16x8*)&Asl[off];
    }
#pragma unroll
    for (int f = 0; f < 2; ++f) {
      int off = swz(wn * 32 + f * 16 + lr, lk);
      bh[f] = *(const bf16x8*)&Bsh[off];
      bl[f] = *(const bf16x8*)&Bsl[off];
    }
#pragma unroll
    for (int mf = 0; mf < 4; ++mf)
#pragma unroll
      for (int f = 0; f < 2; ++f) {
        acc[mf][f] = __builtin_amdgcn_mfma_f32_16x16x32_bf16(ah[mf], bh[f], acc[mf][f], 0, 0, 0);
        acc[mf][f] = __builtin_amdgcn_mfma_f32_16x16x32_bf16(ah[mf], bl[f], acc[mf][f], 0, 0, 0);
        acc[mf][f] = __builtin_amdgcn_mfma_f32_16x16x32_bf16(al[mf], bh[f], acc[mf][f], 0, 0, 0);
      }
  }
#pragma unroll
  for (int mf = 0; mf < 4; ++mf)
#pragma unroll
    for (int f = 0; f < 2; ++f) {
      int col = wn * 32 + f * 16 + lr;
      float bv = bias[col];
#pragma unroll
      for (int reg = 0; reg < 4; ++reg) {
        int row = row0 + mf * 16 + lk * 4 + reg;
        if (row < CH) {
          float v = fmaxf(acc[mf][f][reg] + bv, 0.f);
          __half hv = __float2half_rn(v);
          Hout[(size_t)(n0 + row) * 128 + col] = *(ushort*)&hv;
        }
      }
    }
}

// fused layer-2 GEMM + BiLSTM. 512 thr, BM=64.
__global__ __launch_bounds__(512) void gemm2_lstm(
    const ushort* __restrict__ z16,
    const ushort* __restrict__ wth, const ushort* __restrict__ wtl,
    const ushort* __restrict__ wph, const ushort* __restrict__ wpl,
    const float* __restrict__ bbar2, const float* __restrict__ bselw,
    float* __restrict__ out, int n0) {
  __shared__ ushort lds[40960];   // 80 KB
  ushort* A1h = lds;
  ushort* A1l = lds + 2048;
  ushort* B1h = lds + 4096;
  ushort* B1l = lds + 8192;
  ushort* A2h = lds;
  ushort* A2l = lds + 8192;
  ushort* B3h = lds + 16384;
  ushort* B3l = lds + 28672;

  const int row0 = blockIdx.x * 64;
  const int t = (int)threadIdx.x;
  const int wid = t >> 6, l = t & 63, lr = l & 15, lk = l >> 4;

  f32x4 acc1[4];
#pragma unroll
  for (int a = 0; a < 4; ++a) acc1[a] = (f32x4){0.f, 0.f, 0.f, 0.f};

  for (int kt = 0; kt < 12; ++kt) {
    __syncthreads();
    if (t < 256) {
      int rr = t >> 2, slot = t & 3;
      uint4 v = make_uint4(0, 0, 0, 0);
      if (row0 + rr < CH)
        v = *(const uint4*)(z16 + (size_t)(row0 + rr) * 384 + kt * 32 + slot * 8);
      uint4 hv, lv; cvt_split8(v, hv, lv);
      *(uint4*)&A1h[swz(rr, slot)] = hv;
      *(uint4*)&A1l[swz(rr, slot)] = lv;
    }
    {
      int nn_ = t >> 2, slot = t & 3;
      size_t go = (size_t)nn_ * 384 + kt * 32 + slot * 8;
      *(uint4*)&B1h[swz(nn_, slot)] = *(const uint4*)(wth + go);
      *(uint4*)&B1l[swz(nn_, slot)] = *(const uint4*)(wtl + go);
    }
    __syncthreads();
    bf16x8 ah[4], al[4];
#pragma unroll
    for (int mf = 0; mf < 4; ++mf) {
      int off = swz(mf * 16 + lr, lk);
      ah[mf] = *(const bf16x8*)&A1h[off];
      al[mf] = *(const bf16x8*)&A1l[off];
    }
    int offb = swz(wid * 16 + lr, lk);
    bf16x8 bh = *(const bf16x8*)&B1h[offb];
    bf16x8 bl = *(const bf16x8*)&B1l[offb];
#pragma unroll
    for (int mf = 0; mf < 4; ++mf) {
      acc1[mf] = __builtin_amdgcn_mfma_f32_16x16x32_bf16(ah[mf], bh, acc1[mf], 0, 0, 0);
      acc1[mf] = __builtin_amdgcn_mfma_f32_16x16x32_bf16(ah[mf], bl, acc1[mf], 0, 0, 0);
      acc1[mf] = __builtin_amdgcn_mfma_f32_16x16x32_bf16(al[mf], bh, acc1[mf], 0, 0, 0);
    }
  }

  __syncthreads();
  {
    int colc = wid * 16 + lr;
    float bb = bbar2[colc];
#pragma unroll
    for (int mf = 0; mf < 4; ++mf)
#pragma unroll
      for (int reg = 0; reg < 4; ++reg) {
        int rowc = mf * 16 + lk * 4 + reg;
        float v = acc1[mf][reg] + bb;
        unsigned h, lo2; split1(v, h, lo2);
        int sl2 = (colc >> 3) ^ (rowc & 7);
        int addr = rowc * 128 + (sl2 << 3) + (colc & 7);
        A2h[addr] = (ushort)h;
        A2l[addr] = (ushort)lo2;
      }
  }
  __syncthreads();

  const int wm = wid >> 2, wn3 = wid & 3;
  f32x4 acc3[2][6];
#pragma unroll
  for (int a = 0; a < 2; ++a)
#pragma unroll
    for (int b = 0; b < 6; ++b) acc3[a][b] = (f32x4){0.f, 0.f, 0.f, 0.f};

  for (int kt = 0; kt < 4; ++kt) {
    if (kt) __syncthreads();
#pragma unroll
    for (int i = 0; i < 3; ++i) {
      int s = i * 512 + t;
      int m = s >> 2, slot = s & 3;
      size_t go = (size_t)m * 128 + kt * 32 + slot * 8;
      *(uint4*)&B3h[swz(m, slot)] = *(const uint4*)(wph + go);
      *(uint4*)&B3l[swz(m, slot)] = *(const uint4*)(wpl + go);
    }
    __syncthreads();
    bf16x8 ah2[2], al2[2];
#pragma unroll
    for (int mf = 0; mf < 2; ++mf) {
      int row = wm * 32 + mf * 16 + lr;
      int kslot = kt * 4 + lk;
      int sl2 = kslot ^ (row & 7);
      int addr = row * 128 + (sl2 << 3);
      ah2[mf] = *(const bf16x8*)&A2h[addr];
      al2[mf] = *(const bf16x8*)&A2l[addr];
    }
#pragma unroll
    for (int tt = 0; tt < 6; ++tt) {
      int m = (wn3 + 4 * tt) * 16 + lr;
      int off = swz(m, lk);
      bf16x8 bh = *(const bf16x8*)&B3h[off];
      bf16x8 bl = *(const bf16x8*)&B3l[off];
#pragma unroll
      for (int mf = 0; mf < 2; ++mf) {
        acc3[mf][tt] = __builtin_amdgcn_mfma_f32_16x16x32_bf16(ah2[mf], bh, acc3[mf][tt], 0, 0, 0);
        acc3[mf][tt] = __builtin_amdgcn_mfma_f32_16x16x32_bf16(ah2[mf], bl, acc3[mf][tt], 0, 0, 0);
        acc3[mf][tt] = __builtin_amdgcn_mfma_f32_16x16x32_bf16(al2[mf], bh, acc3[mf][tt], 0, 0, 0);
      }
    }
  }

  int j0 = wn3 * 16 + lr, j1 = j0 + 64;
  float bi0 = bselw[j0], bg0 = bselw[128 + j0], bo0 = bselw[256 + j0];
  float bi1 = bselw[j1], bg1 = bselw[128 + j1], bo1 = bselw[256 + j1];
#pragma unroll
  for (int mf = 0; mf < 2; ++mf)
#pragma unroll
    for (int reg = 0; reg < 4; ++reg) {
      int grow = wm * 32 + mf * 16 + lk * 4 + reg;
      if (row0 + grow < CH) {
        size_t orow = (size_t)(n0 + row0 + grow) * 128;
        float iv0 = acc3[mf][0][reg] + bi0, gv0 = acc3[mf][2][reg] + bg0,
              ov0 = acc3[mf][4][reg] + bo0;
        float c0 = sigm(iv0) * tanhf(gv0);
        out[orow + j0] = sigm(ov0) * tanhf(c0);
        float iv1 = acc3[mf][1][reg] + bi1, gv1 = acc3[mf][3][reg] + bg1,
              ov1 = acc3[mf][5][reg] + bo1;
        float c1 = sigm(iv1) * tanhf(gv1);
        out[orow + j1] = sigm(ov1) * tanhf(c1);
      }
    }
}

extern "C" void kernel_launch(void* const* d_in, const int* in_sizes, int n_in,
                              void* d_out, int out_size, void* d_ws, size_t ws_size,
                              hipStream_t stream) {
  const float* x = (const float*)d_in[0];
  const int* src = (const int*)d_in[1];
  const int* dst = (const int*)d_in[2];
  const float* W1 = (const float*)d_in[3];
  const float* b1 = (const float*)d_in[4];
  const float* W2 = (const float*)d_in[5];
  const float* b2 = (const float*)d_in[6];
  const float* Wih_f = (const float*)d_in[7];
  const float* bih_f = (const float*)d_in[9];
  const float* bhh_f = (const float*)d_in[10];
  const float* Wih_b = (const float*)d_in[11];
  const float* bih_b = (const float*)d_in[13];
  const float* bhh_b = (const float*)d_in[14];
  float* out = (float*)d_out;

  // workspace carve-up (~107 MB)
  char* wp = (char*)d_ws;
  float* rs_out = (float*)wp;          wp += (size_t)3 * NN * 4;
  float* rs_in3 = (float*)wp;          wp += (size_t)3 * NN * 4;
  int* cnt_in = (int*)wp;              wp += (size_t)3 * NN * 4;
  int* row_ptr = (int*)wp;             wp += (size_t)3 * NN * 4;
  int* bsums = (int*)wp;               wp += 4096;
  int2* ses = (int2*)wp;               wp += (size_t)3 * NE * 8;
  ushort* wt1h = (ushort*)wp;          wp += (size_t)128 * 384 * 2;
  ushort* wt1l = (ushort*)wp;          wp += (size_t)128 * 384 * 2;
  ushort* wt2h = (ushort*)wp;          wp += (size_t)128 * 384 * 2;
  ushort* wt2l = (ushort*)wp;          wp += (size_t)128 * 384 * 2;
  ushort* wph = (ushort*)wp;           wp += (size_t)384 * 128 * 2;
  ushort* wpl = (ushort*)wp;           wp += (size_t)384 * 128 * 2;
  float* bbar1 = (float*)wp;           wp += 512;
  float* bbar2 = (float*)wp;           wp += 512;
  float* bselw = (float*)wp;           wp += 2048;
  ushort* z16 = (ushort*)wp;           wp += (size_t)CH * 384 * 2;   // 38.4 MB
  ushort* x16 = (ushort*)wp;           wp += (size_t)NN * F * 2;     // 25.6 MB
  ushort* h116 = (ushort*)wp;          wp += (size_t)NN * F * 2;     // 25.6 MB

  // CSR-build aliases over the z16/x16/h116 region (89.6 MB), dead before use:
  // part (u16): 27.52 MB @ z16 (inside z16's 38.4 MB);
  // cb (int): 27.52 MB @ z16+28MB (ends 55.5MB < z16+x16 end 64MB; x16 written later);
  // pay: 12 MB @ h116+12MB (region offset 76MB, disjoint from cb's end).
  ushort* part = (ushort*)z16;
  int* cb = (int*)((char*)z16 + ((size_t)28 << 20));
  int2* pay = (int2*)((char*)h116 + ((size_t)12 << 20));

  // CSR build — zero global atomics, XCD-grouped L2 reuse, u16 partials
  hist_part<<<2 * NREL * EC * NRANGE, 256, 0, stream>>>(src, dst, part);
  reduce_rs<<<(NREL * NN + 255) / 256, 256, 0, stream>>>(part, cnt_in, rs_out, rs_in3);
  scan1<<<NREL * NBLK, 256, 0, stream>>>(cnt_in, row_ptr, bsums);
  scan2<<<NREL, 128, 0, stream>>>(bsums);
  scan3_chunk<<<(NREL * NN + 255) / 256, 256, 0, stream>>>(row_ptr, bsums, part, cb);
  make_pay<<<(NREL * NE + 255) / 256, 256, 0, stream>>>(src, rs_out, pay);
  place_part<<<8 * ((NREL * EC + 7) / 8) * NRANGE, 256, 0, stream>>>(dst, pay, cb, ses);

  // weight prep
  prep_small<<<1, 640, 0, stream>>>(b1, b2, bih_f, bhh_f, bih_b, bhh_b, bbar1, bbar2, bselw);
  wt_split<<<192, 256, 0, stream>>>(W1, wt1h, wt1l);
  wt_split<<<192, 256, 0, stream>>>(W2, wt2h, wt2l);
  pack_w_split<<<192, 256, 0, stream>>>(Wih_f, Wih_b, wph, wpl);
  cvt_f16<<<(NN * 32 + 255) / 256, 256, 0, stream>>>(x, x16);

  // layer 1: x16 -> h116 (relu, f16)
  for (int c = 0; c < NCH; ++c) {
    gather3<<<3 * CH / 4, 256, 0, stream>>>(x16, ses, row_ptr, cnt_in, rs_in3, z16, c * CH);
    gemm_mfma1<<<(CH + 63) / 64, 256, 0, stream>>>(z16, wt1h, wt1l, bbar1, h116, c * CH);
  }
  // layer 2 + fused BiLSTM: h116 -> d_out
  for (int c = 0; c < NCH; ++c) {
    gather3<<<3 * CH / 4, 256, 0, stream>>>(h116, ses, row_ptr, cnt_in, rs_in3, z16, c * CH);
    gemm2_lstm<<<(CH + 63) / 64, 512, 0, stream>>>(z16, wt2h, wt2l, wph, wpl,
                                                   bbar2, bselw, out, c * CH);
  }
}